// Round 13
// baseline (207.849 us; speedup 1.0000x reference)
//
#include <hip/hip_runtime.h>
#include <hip/hip_bf16.h>
#include <math.h>

#define TSEQ 2048
#define NB 2
#define DM 1024
#define NH 16
#define DHD 64

typedef __attribute__((ext_vector_type(8))) __bf16 bf16x8;
typedef __attribute__((ext_vector_type(8))) short s16x8;
typedef __attribute__((ext_vector_type(4))) float f32x4;

__device__ __forceinline__ bf16x8 ld_bf16x8(const void* p) {
  s16x8 v = *reinterpret_cast<const s16x8*>(p);
  return __builtin_bit_cast(bf16x8, v);
}

#define GLL16(g, l) __builtin_amdgcn_global_load_lds( \
    (const __attribute__((address_space(1))) void*)(g), \
    (__attribute__((address_space(3))) void*)(l), 16, 0, 0)

#define FENCE asm volatile("" ::: "memory")

// ---------- merged transpose + cast fp32 -> bf16 for Wqkv, Wr, Wo ----------
__global__ __launch_bounds__(256) void k_transpose_all(
    const float* __restrict__ Wqkv, const float* __restrict__ Wr,
    const float* __restrict__ Wo, __hip_bfloat16* __restrict__ wqkvT,
    __hip_bfloat16* __restrict__ wrT, __hip_bfloat16* __restrict__ woT) {
  __shared__ float t[32][33];
  const int tx = threadIdx.x, ty = threadIdx.y;
  const int blk = blockIdx.x;
  const float* in; __hip_bfloat16* out; int C, bx, by;
  if (blk < 3072)      { in = Wqkv; out = wqkvT; C = 3072; bx = blk % 96;  by = blk / 96; }
  else if (blk < 4096) { in = Wr;   out = wrT;   C = 1024; bx = (blk - 3072) % 32; by = (blk - 3072) / 32; }
  else                 { in = Wo;   out = woT;   C = 1024; bx = (blk - 4096) % 32; by = (blk - 4096) / 32; }
  const int R = 1024;
  const int c0 = bx * 32, r0 = by * 32;
#pragma unroll
  for (int j = 0; j < 4; ++j)
    t[ty + j * 8][tx] = in[(size_t)(r0 + ty + j * 8) * C + c0 + tx];
  __syncthreads();
#pragma unroll
  for (int j = 0; j < 4; ++j) {
    const int oc = ty + j * 8;
    out[(size_t)(c0 + oc) * R + r0 + tx] = __float2bfloat16(t[tx][oc]);
  }
}

// ---------- elementwise cast fp32 -> bf16 (exact-multiple sizes) ----------
__global__ __launch_bounds__(256) void k_cast_bf16(
    const float* __restrict__ in, __hip_bfloat16* __restrict__ out) {
  const int i = (blockIdx.x * 256 + threadIdx.x) * 4;
  const float4 v = *reinterpret_cast<const float4*>(in + i);
  struct B4 { __hip_bfloat16 a, b, c, d; } o;
  o.a = __float2bfloat16(v.x); o.b = __float2bfloat16(v.y);
  o.c = __float2bfloat16(v.z); o.d = __float2bfloat16(v.w);
  *reinterpret_cast<B4*>(out + i) = o;
}

// ---------- LayerNorm rows of [4096][1024], fp32 in -> bf16 out ----------
__global__ __launch_bounds__(256) void k_layernorm(
    const float* __restrict__ x, const float* __restrict__ g,
    const float* __restrict__ b, __hip_bfloat16* __restrict__ out) {
  const int row = blockIdx.x, tid = threadIdx.x;
  const float4 v = reinterpret_cast<const float4*>(x + (size_t)row * DM)[tid];
  float s = v.x + v.y + v.z + v.w;
  __shared__ float r1[4], r2[4];
#pragma unroll
  for (int off = 32; off; off >>= 1) s += __shfl_xor(s, off);
  if ((tid & 63) == 0) r1[tid >> 6] = s;
  __syncthreads();
  const float mu = (r1[0] + r1[1] + r1[2] + r1[3]) * (1.f / DM);
  const float dx = v.x - mu, dy = v.y - mu, dz = v.z - mu, dw = v.w - mu;
  float q = dx * dx + dy * dy + dz * dz + dw * dw;
#pragma unroll
  for (int off = 32; off; off >>= 1) q += __shfl_xor(q, off);
  if ((tid & 63) == 0) r2[tid >> 6] = q;
  __syncthreads();
  const float rs = rsqrtf((r2[0] + r2[1] + r2[2] + r2[3]) * (1.f / DM) + 1e-5f);
  const float4 gv = reinterpret_cast<const float4*>(g)[tid];
  const float4 bv = reinterpret_cast<const float4*>(b)[tid];
  struct B4 { __hip_bfloat16 a, b, c, d; } o;
  o.a = __float2bfloat16(dx * rs * gv.x + bv.x);
  o.b = __float2bfloat16(dy * rs * gv.y + bv.y);
  o.c = __float2bfloat16(dz * rs * gv.z + bv.z);
  o.d = __float2bfloat16(dw * rs * gv.w + bv.w);
  reinterpret_cast<B4*>(out + (size_t)row * DM)[tid] = o;
}

// ---------- generic 128x128 bf16 MFMA GEMM, C = A[M][K] * BT[N][K]^T ----------
// MODE 0: QKV epilogue (qr NOT written; attn reconstructs it from bias delta)
// MODE 1: R epilogue  MODE 2: fp32 out epilogue
template <int MODE>
__global__ __launch_bounds__(256) void k_gemm_bt(
    const __hip_bfloat16* __restrict__ A, const __hip_bfloat16* __restrict__ BT,
    int M, int N, int K, float* __restrict__ outF,
    __hip_bfloat16* __restrict__ o_qw,
    __hip_bfloat16* __restrict__ o_k, __hip_bfloat16* __restrict__ o_vT,
    const float* __restrict__ rwb,
    __hip_bfloat16* __restrict__ o_rT) {
  __shared__ __align__(16) __hip_bfloat16 As[128 * 32];
  __shared__ __align__(16) __hip_bfloat16 Bs[128 * 32];
  const int tid = threadIdx.x, lane = tid & 63;
  const int ntn = N >> 7;
  const int m0 = (blockIdx.x / ntn) * 128, n0 = (blockIdx.x % ntn) * 128;
  const int wid = tid >> 6;
  const int wr = (wid >> 1) * 64, wc = (wid & 1) * 64;
  const int fr = lane & 15, fq = lane >> 4;
  const int srow = tid >> 2, scol = (tid & 3) * 8;
  const __hip_bfloat16* aSrc = A + (size_t)(m0 + srow) * K + scol;
  const __hip_bfloat16* bSrc = BT + (size_t)(n0 + srow) * K + scol;
  char* aDst = (char*)As + (tid - lane) * 16;
  char* bDst = (char*)Bs + (tid - lane) * 16;
  f32x4 acc[4][4] = {};
  for (int k0 = 0; k0 < K; k0 += 32) {
    GLL16(aSrc + k0, aDst);
    GLL16(aSrc + (size_t)64 * K + k0, aDst + 4096);
    GLL16(bSrc + k0, bDst);
    GLL16(bSrc + (size_t)64 * K + k0, bDst + 4096);
    __syncthreads();
    bf16x8 af[4], bfr[4];
#pragma unroll
    for (int mi = 0; mi < 4; ++mi)
      af[mi] = ld_bf16x8(As + (wr + mi * 16 + fr) * 32 + fq * 8);
#pragma unroll
    for (int ni = 0; ni < 4; ++ni)
      bfr[ni] = ld_bf16x8(Bs + (wc + ni * 16 + fr) * 32 + fq * 8);
#pragma unroll
    for (int mi = 0; mi < 4; ++mi)
#pragma unroll
      for (int ni = 0; ni < 4; ++ni)
        acc[mi][ni] = __builtin_amdgcn_mfma_f32_16x16x32_bf16(
            af[mi], bfr[ni], acc[mi][ni], 0, 0, 0);
    __syncthreads();
  }
#pragma unroll
  for (int mi = 0; mi < 4; ++mi) {
#pragma unroll
    for (int ni = 0; ni < 4; ++ni) {
#pragma unroll
      for (int j = 0; j < 4; ++j) {
        const int r = m0 + wr + mi * 16 + fq * 4 + j;
        const int c = n0 + wc + ni * 16 + fr;
        const float v = acc[mi][ni][j];
        if (MODE == 2) {
          outF[(size_t)r * N + c] = v;
        } else if (MODE == 1) {
          const int h = c >> 6, d = c & 63;
          o_rT[((size_t)h * TSEQ + r) * DHD + d] = __float2bfloat16(v);
        } else {
          const int t = r >> 1, bb = r & 1;
          if (c < 1024) {
            const int h = c >> 6, d = c & 63;
            const size_t o = (((size_t)(bb * NH + h)) * TSEQ + t) * DHD + d;
            o_qw[o] = __float2bfloat16(v + rwb[c]);
          } else if (c < 2048) {
            const int e = c - 1024, h = e >> 6, d = e & 63;
            o_k[(((size_t)(bb * NH + h)) * TSEQ + t) * DHD + d] = __float2bfloat16(v);
          } else {
            const int e = c - 2048, h = e >> 6, d = e & 63;
            o_vT[(((size_t)(bb * NH + h)) * DHD + d) * TSEQ + t] = __float2bfloat16(v);
          }
        }
      }
    }
  }
}

// ---------- fused causal rel-attention: 52KB single-buffered, 3 blocks/CU ----------
// 1024 blocks (XCD-local heads, LPT big-first), 4 waves = one 64-row qblock.
// Iteration = [bar1: vmcnt(0)+barrier (prev prefetch landed)] ->
//   READ PHASE: K frags (8 b128 -> regs), V frags (8 b128 -> regs),
//   band R (10 b128 + MFMA, braw f32[16][80] per-wave scratch) ->
//   lgkmcnt(0)+sched_barrier+bar2 (shared-buffer reads drained) ->
//   prefetch(kt+1) GLLs into the SAME single buffers (provably safe) ->
//   softmax + P roundtrip + reg-fed PV run under GLL flight.
// LDS: Ksm 8K + Vsm 8K + Rsm[128] circular (slot=row&127) 16K + scratch 20K = 52KB.
__global__ __launch_bounds__(256, 3) void k_attn(
    const __hip_bfloat16* __restrict__ qw,
    const __hip_bfloat16* __restrict__ kb, const __hip_bfloat16* __restrict__ vT,
    const __hip_bfloat16* __restrict__ rT,
    const float* __restrict__ rwb, const float* __restrict__ rrb,
    __hip_bfloat16* __restrict__ av) {
  const int tid = threadIdx.x, lane = tid & 63;
  const int w = __builtin_amdgcn_readfirstlane(tid >> 6);
  const int fr = lane & 15, fq = lane >> 4;
  const int l8 = lane >> 3, lb = lane & 7;
  const int bid = blockIdx.x;
  const int xcd = bid & 7, slot = bid >> 3;    // slot 0..127
  const int bh = xcd * 4 + (slot & 3);         // 4 heads per XCD
  const int p4 = 31 - (slot >> 2);             // LPT: big qblocks dispatch first
  const int bb = bh >> 4, h = bh & 15;
  const int nk = p4 + 1;
  const int iw0 = p4 * 64 + w * 16;
  const char* Kp = (const char*)(kb + (size_t)bh * TSEQ * DHD);   // row t:128B
  const char* Vp = (const char*)(vT + (size_t)bh * DHD * TSEQ);   // row d:4096B
  const char* Rp = (const char*)(rT + (size_t)h * TSEQ * DHD);    // row t:128B

  __shared__ __align__(16) __hip_bfloat16 Ksm[64][64];    // 8 KB single
  __shared__ __align__(16) __hip_bfloat16 Vsm[64][64];    // 8 KB single
  __shared__ __align__(16) __hip_bfloat16 Rsm[128][64];   // 16 KB circular slot=row&127
  __shared__ __align__(16) float scratch[4][1280];        // 20 KB: braw f32[16][80] / plq bf16[16][72] overlay

  // ---- per-lane constant offsets ----
  const int swz = (lb << 4) ^ (l8 << 4);                 // staging src byte
  const int koff0 = (fq << 4) ^ ((fr & 7) << 4);         // swizzled read c=0
  const int koff1 = ((fq << 4) + 64) ^ ((fr & 7) << 4);  // swizzled read c=1
  const int rowA = w * 16 + l8;                          // K/V stage rows
  const int kOff0 = rowA * 128 + swz, kOff1 = (rowA + 8) * 128 + swz;
  const int vOff0 = rowA * 4096 + swz, vOff1 = (rowA + 8) * 4096 + swz;
  char* kDst = (char*)Ksm + w * 2048 + lane * 16;
  char* vDst = (char*)Vsm + w * 2048 + lane * 16;
  char* RsmC = (char*)Rsm;
  float* brawW = scratch[w];                             // [16][80] f32
  __hip_bfloat16* plqW = (__hip_bfloat16*)scratch[w];    // [16][72] bf16 overlay
  const f32x4 zero = {0.f, 0.f, 0.f, 0.f};
  struct B4 { __hip_bfloat16 a, b, c, d; };

  const float* rwbh = rwb + h * 64;
  const float* rrbh = rrb + h * 64;

  const __hip_bfloat16* qwp = qw + ((size_t)bh * TSEQ + iw0 + fr) * DHD + fq * 8;
  const bf16x8 qwf0 = ld_bf16x8(qwp), qwf1 = ld_bf16x8(qwp + 32);
  bf16x8 qrf0, qrf1;   // qr reconstructed from bias delta
#pragma unroll
  for (int e = 0; e < 8; ++e) {
    qrf0[e] = (__bf16)((float)qwf0[e] + rrbh[fq * 8 + e] - rwbh[fq * 8 + e]);
    qrf1[e] = (__bf16)((float)qwf1[e] + rrbh[32 + fq * 8 + e] - rwbh[32 + fq * 8 + e]);
  }
  f32x4 o[4] = {};
  float mrow = -INFINITY, lrow = 0.f;

  const int rbase0 = 1984 - 64 * p4;

  // ---- prologue: K(0),V(0); R rows [rbase0, rbase0+128) (slot = row&127) ----
  GLL16(Kp + kOff0, kDst);
  GLL16(Kp + kOff1, kDst + 1024);
  GLL16(Vp + vOff0, vDst);
  GLL16(Vp + vOff1, vDst + 1024);
#pragma unroll
  for (int s = 0; s < 4; ++s) {
    const int rel = w * 32 + s * 8;                      // 0..120, step 8
    int g = rbase0 + rel + l8;
    g = g > 2047 ? 2047 : g;
    const int dslot = (rbase0 + rel) & 127;              // never wraps within 8
    GLL16(Rp + g * 128 + swz, RsmC + dslot * 128 + (lb << 4));
  }

  int rbase = rbase0;
  int thr = iw0 + fr;
  const char* kTile = Kp + 8192;    // src for K(kt+1)
  const char* vTile = Vp + 128;     // src for V(kt+1)

  for (int kt = 0; kt < nk; ++kt) {
    asm volatile("s_waitcnt vmcnt(0)" ::: "memory");   // prefetch(kt) landed
    __builtin_amdgcn_s_barrier();
    // ================= READ PHASE (shared buffers -> regs) =================
    const char* kls = (const char*)Ksm + fr * 128;
    const char* vls = (const char*)Vsm + fr * 128;
    bf16x8 kk[8], vv[8];
#pragma unroll
    for (int n = 0; n < 4; ++n) {
      kk[n] = ld_bf16x8(kls + n * 2048 + koff0);
      kk[4 + n] = ld_bf16x8(kls + n * 2048 + koff1);
      vv[n] = ld_bf16x8(vls + n * 2048 + koff0);
      vv[4 + n] = ld_bf16x8(vls + n * 2048 + koff1);
    }
    // S^T = mfma(K, Q)
    f32x4 st[4];
    __builtin_amdgcn_s_setprio(1);
#pragma unroll
    for (int n = 0; n < 4; ++n) {
      st[n] = __builtin_amdgcn_mfma_f32_16x16x32_bf16(kk[n], qwf0, zero, 0, 0, 0);
      st[n] = __builtin_amdgcn_mfma_f32_16x16x32_bf16(kk[4 + n], qwf1, st[n], 0, 0, 0);
    }
    __builtin_amdgcn_s_setprio(0);
    // band from circular Rsm: D[m][q=fr] -> b128 write to per-wave scratch
    const int bandRel = 48 - 16 * w + fr;    // 0..63
    __builtin_amdgcn_s_setprio(1);
#pragma unroll
    for (int pp = 0; pp < 5; ++pp) {
      const int rrow = (rbase + bandRel + 16 * pp) & 127;
      const char* rls = RsmC + rrow * 128;
      f32x4 br = __builtin_amdgcn_mfma_f32_16x16x32_bf16(ld_bf16x8(rls + koff0), qrf0, zero, 0, 0, 0);
      br = __builtin_amdgcn_mfma_f32_16x16x32_bf16(ld_bf16x8(rls + koff1), qrf1, br, 0, 0, 0);
      *reinterpret_cast<f32x4*>(&brawW[fr * 80 + pp * 16 + 4 * fq]) = br;
    }
    __builtin_amdgcn_s_setprio(0);
    asm volatile("s_waitcnt lgkmcnt(0)" ::: "memory");
    __builtin_amdgcn_sched_barrier(0);
    __builtin_amdgcn_s_barrier();   // bar2: all shared-buffer reads drained
    // ================= PREFETCH (kt+1) into same buffers ===================
    if (kt + 1 < nk) {
      GLL16(kTile + kOff0, kDst);
      GLL16(kTile + kOff1, kDst + 1024);
      GLL16(vTile + vOff0, vDst);
      GLL16(vTile + vOff1, vDst + 1024);
#pragma unroll
      for (int s = 0; s < 2; ++s) {
        const int rel = w * 16 + s * 8;                  // 0..56
        int g = rbase + 128 + rel + l8;
        g = g > 2047 ? 2047 : g;
        const int dslot = (rbase + 128 + rel) & 127;     // == (rbase&127)+rel
        GLL16(Rp + g * 128 + swz, RsmC + dslot * 128 + (lb << 4));
      }
      kTile += 8192;
      vTile += 128;
    }
    // ================= softmax (q = fr), under GLL flight ==================
    const float* brd = &brawW[fr * 80 + 15 - fr];
    float mx = -INFINITY;
#pragma unroll
    for (int n = 0; n < 4; ++n) {
#pragma unroll
      for (int j = 0; j < 4; ++j) {
        const int koff = 16 * n + 4 * fq + j;
        const float s = (koff > thr) ? -INFINITY : (st[n][j] + brd[koff]) * 0.125f;
        st[n][j] = s;
        mx = fmaxf(mx, s);
      }
    }
    mx = fmaxf(mx, __shfl_xor(mx, 16));
    mx = fmaxf(mx, __shfl_xor(mx, 32));
    const float mn = fmaxf(mrow, mx);
    const float al = __expf(mrow - mn);
    mrow = mn;
    float rsum = 0.f;
#pragma unroll
    for (int n = 0; n < 4; ++n)
#pragma unroll
      for (int j = 0; j < 4; ++j) {
        const float pv = __expf(st[n][j] - mn);
        st[n][j] = pv;
        rsum += pv;
      }
    rsum += __shfl_xor(rsum, 16);
    rsum += __shfl_xor(rsum, 32);
    lrow = lrow * al + rsum;
#pragma unroll
    for (int nd = 0; nd < 4; ++nd) o[nd] *= al;
    // ---- P store (overlay; braw consumed) + pf reload ----
#pragma unroll
    for (int n = 0; n < 4; ++n) {
      B4 pk;
      pk.a = __float2bfloat16(st[n][0]);
      pk.b = __float2bfloat16(st[n][1]);
      pk.c = __float2bfloat16(st[n][2]);
      pk.d = __float2bfloat16(st[n][3]);
      *reinterpret_cast<B4*>(&plqW[fr * 72 + 16 * n + 4 * fq]) = pk;
    }
    const bf16x8 pf0 = ld_bf16x8(&plqW[fr * 72 + 8 * fq]);
    const bf16x8 pf1 = ld_bf16x8(&plqW[fr * 72 + 8 * fq + 32]);
    // ---- O^T += V^T . P^T (all operands in regs) ----
    __builtin_amdgcn_s_setprio(1);
#pragma unroll
    for (int nd = 0; nd < 4; ++nd)
      o[nd] = __builtin_amdgcn_mfma_f32_16x16x32_bf16(vv[nd], pf0, o[nd], 0, 0, 0);
#pragma unroll
    for (int nd = 0; nd < 4; ++nd)
      o[nd] = __builtin_amdgcn_mfma_f32_16x16x32_bf16(vv[4 + nd], pf1, o[nd], 0, 0, 0);
    __builtin_amdgcn_s_setprio(0);
    // ---- advance ----
    rbase += 64;
    thr -= 64;
  }
  // ---- epilogue: per-lane 1/l, packed 8B stores; row i = iw0+fr ----
  const float linv = 1.f / lrow;
  const int i = iw0 + fr;
#pragma unroll
  for (int nd = 0; nd < 4; ++nd) {
    B4 pack;
    pack.a = __float2bfloat16(o[nd][0] * linv);
    pack.b = __float2bfloat16(o[nd][1] * linv);
    pack.c = __float2bfloat16(o[nd][2] * linv);
    pack.d = __float2bfloat16(o[nd][3] * linv);
    *reinterpret_cast<B4*>(av + ((size_t)i * NB + bb) * DM + h * DHD + 16 * nd + 4 * fq) = pack;
  }
}

extern "C" void kernel_launch(void* const* d_in, const int* in_sizes, int n_in,
                              void* d_out, int out_size, void* d_ws, size_t ws_size,
                              hipStream_t stream) {
  (void)in_sizes; (void)n_in; (void)out_size; (void)ws_size;
  const float* x    = (const float*)d_in[0];
  const float* pos  = (const float*)d_in[1];
  const float* ln_g = (const float*)d_in[2];
  const float* ln_b = (const float*)d_in[3];
  const float* Wqkv = (const float*)d_in[4];
  const float* Wr   = (const float*)d_in[5];
  const float* Wo   = (const float*)d_in[6];
  const float* rwb  = (const float*)d_in[7];
  const float* rrb  = (const float*)d_in[8];
  float* out = (float*)d_out;

  char* ws = (char*)d_ws;
  size_t off = 0;
  auto alloc = [&](size_t n) {
    char* p = ws + off; off += (n + 255) & ~(size_t)255; return p;
  };
  __hip_bfloat16* wqkvT = (__hip_bfloat16*)alloc((size_t)3072 * 1024 * 2);
  __hip_bfloat16* wrT   = (__hip_bfloat16*)alloc((size_t)1024 * 1024 * 2);
  __hip_bfloat16* woT   = (__hip_bfloat16*)alloc((size_t)1024 * 1024 * 2);
  __hip_bfloat16* posb  = (__hip_bfloat16*)alloc((size_t)2048 * 1024 * 2);
  __hip_bfloat16* xn    = (__hip_bfloat16*)alloc((size_t)4096 * 1024 * 2);
  __hip_bfloat16* qwb   = (__hip_bfloat16*)alloc((size_t)NB * NH * TSEQ * DHD * 2);
  __hip_bfloat16* kbb   = (__hip_bfloat16*)alloc((size_t)NB * NH * TSEQ * DHD * 2);
  __hip_bfloat16* vTb   = (__hip_bfloat16*)alloc((size_t)NB * NH * TSEQ * DHD * 2);
  __hip_bfloat16* rTb   = (__hip_bfloat16*)alloc((size_t)NH * TSEQ * DHD * 2);
  __hip_bfloat16* avb   = (__hip_bfloat16*)alloc((size_t)4096 * 1024 * 2);
  (void)alloc(64 * 1024);  // guard region

  k_transpose_all<<<5120, dim3(32, 8), 0, stream>>>(Wqkv, Wr, Wo, wqkvT, wrT, woT);
  k_cast_bf16<<<(2048 * 1024) / 1024, 256, 0, stream>>>(pos, posb);
  k_layernorm<<<4096, 256, 0, stream>>>(x, ln_g, ln_b, xn);
  k_gemm_bt<0><<<32 * 24, 256, 0, stream>>>(xn, wqkvT, 4096, 3072, 1024,
      nullptr, qwb, kbb, vTb, rwb, nullptr);
  k_gemm_bt<1><<<16 * 8, 256, 0, stream>>>(posb, wrT, 2048, 1024, 1024,
      nullptr, nullptr, nullptr, nullptr, nullptr, rTb);
  k_attn<<<1024, 256, 0, stream>>>(qwb, kbb, vTb, rTb, rwb, rrb, avb);
  k_gemm_bt<2><<<32 * 8, 256, 0, stream>>>(avb, woT, 4096, 1024, 1024,
      out, nullptr, nullptr, nullptr, nullptr, nullptr);
}

// Round 14
// 192.793 us; speedup vs baseline: 1.0781x; 1.0781x over previous
//
#include <hip/hip_runtime.h>
#include <hip/hip_bf16.h>
#include <math.h>

#define TSEQ 2048
#define NB 2
#define DM 1024
#define NH 16
#define DHD 64

typedef __attribute__((ext_vector_type(8))) __bf16 bf16x8;
typedef __attribute__((ext_vector_type(8))) short s16x8;
typedef __attribute__((ext_vector_type(4))) float f32x4;

__device__ __forceinline__ bf16x8 ld_bf16x8(const void* p) {
  s16x8 v = *reinterpret_cast<const s16x8*>(p);
  return __builtin_bit_cast(bf16x8, v);
}

#define GLL16(g, l) __builtin_amdgcn_global_load_lds( \
    (const __attribute__((address_space(1))) void*)(g), \
    (__attribute__((address_space(3))) void*)(l), 16, 0, 0)

#define FENCE asm volatile("" ::: "memory")

// ---------- fused prep: weight transposes + pos cast + LayerNorm ----------
// blocks [0,5120): transpose+cast Wqkv/Wr/Wo ; [5120,7168): cast pos ;
// [7168,11264): LayerNorm rows.
__global__ __launch_bounds__(256) void k_prep(
    const float* __restrict__ Wqkv, const float* __restrict__ Wr,
    const float* __restrict__ Wo, __hip_bfloat16* __restrict__ wqkvT,
    __hip_bfloat16* __restrict__ wrT, __hip_bfloat16* __restrict__ woT,
    const float* __restrict__ pos, __hip_bfloat16* __restrict__ posb,
    const float* __restrict__ x, const float* __restrict__ g,
    const float* __restrict__ b, __hip_bfloat16* __restrict__ xn) {
  __shared__ float t[32][33];
  __shared__ float r1[4], r2[4];
  const int blk = blockIdx.x, tid = threadIdx.x;
  struct B4 { __hip_bfloat16 a, b, c, d; };
  if (blk < 5120) {
    const int tx = tid & 31, ty = tid >> 5;
    const float* in; __hip_bfloat16* out; int C, bx, by;
    if (blk < 3072)      { in = Wqkv; out = wqkvT; C = 3072; bx = blk % 96;  by = blk / 96; }
    else if (blk < 4096) { in = Wr;   out = wrT;   C = 1024; bx = (blk - 3072) % 32; by = (blk - 3072) / 32; }
    else                 { in = Wo;   out = woT;   C = 1024; bx = (blk - 4096) % 32; by = (blk - 4096) / 32; }
    const int c0 = bx * 32, r0 = by * 32;
#pragma unroll
    for (int j = 0; j < 4; ++j)
      t[ty + j * 8][tx] = in[(size_t)(r0 + ty + j * 8) * C + c0 + tx];
    __syncthreads();
#pragma unroll
    for (int j = 0; j < 4; ++j) {
      const int oc = ty + j * 8;
      out[(size_t)(c0 + oc) * 1024 + r0 + tx] = __float2bfloat16(t[tx][oc]);
    }
  } else if (blk < 7168) {
    const int i = ((blk - 5120) * 256 + tid) * 4;
    const float4 v = *reinterpret_cast<const float4*>(pos + i);
    B4 o;
    o.a = __float2bfloat16(v.x); o.b = __float2bfloat16(v.y);
    o.c = __float2bfloat16(v.z); o.d = __float2bfloat16(v.w);
    *reinterpret_cast<B4*>(posb + i) = o;
  } else {
    const int row = blk - 7168;
    const float4 v = reinterpret_cast<const float4*>(x + (size_t)row * DM)[tid];
    float s = v.x + v.y + v.z + v.w;
#pragma unroll
    for (int off = 32; off; off >>= 1) s += __shfl_xor(s, off);
    if ((tid & 63) == 0) r1[tid >> 6] = s;
    __syncthreads();
    const float mu = (r1[0] + r1[1] + r1[2] + r1[3]) * (1.f / DM);
    const float dx = v.x - mu, dy = v.y - mu, dz = v.z - mu, dw = v.w - mu;
    float q = dx * dx + dy * dy + dz * dz + dw * dw;
#pragma unroll
    for (int off = 32; off; off >>= 1) q += __shfl_xor(q, off);
    if ((tid & 63) == 0) r2[tid >> 6] = q;
    __syncthreads();
    const float rs = rsqrtf((r2[0] + r2[1] + r2[2] + r2[3]) * (1.f / DM) + 1e-5f);
    const float4 gv = reinterpret_cast<const float4*>(g)[tid];
    const float4 bv = reinterpret_cast<const float4*>(b)[tid];
    B4 o;
    o.a = __float2bfloat16(dx * rs * gv.x + bv.x);
    o.b = __float2bfloat16(dy * rs * gv.y + bv.y);
    o.c = __float2bfloat16(dz * rs * gv.z + bv.z);
    o.d = __float2bfloat16(dw * rs * gv.w + bv.w);
    reinterpret_cast<B4*>(xn + (size_t)row * DM)[tid] = o;
  }
}

// ---------- 128x128 bf16 MFMA GEMM, BK=64, XOR-swizzled LDS, XCD remap ----
// C = A[M][K] * BT[N][K]^T.  MODE 0: QKV epilogue (qw+bias, K, V^T; no qr)
// MODE 1: R epilogue  MODE 2: fp32 out epilogue
template <int MODE>
__global__ __launch_bounds__(256) void k_gemm_bt(
    const __hip_bfloat16* __restrict__ A, const __hip_bfloat16* __restrict__ BT,
    int M, int N, int K, float* __restrict__ outF,
    __hip_bfloat16* __restrict__ o_qw,
    __hip_bfloat16* __restrict__ o_k, __hip_bfloat16* __restrict__ o_vT,
    const float* __restrict__ rwb,
    __hip_bfloat16* __restrict__ o_rT) {
  __shared__ __align__(16) __hip_bfloat16 As[128 * 64];   // 16 KB
  __shared__ __align__(16) __hip_bfloat16 Bs[128 * 64];   // 16 KB
  const int tid = threadIdx.x, lane = tid & 63;
  const int ntn = N >> 7;
  // XCD-contiguous tile remap (grid % 8 == 0): each XCD owns contiguous
  // m-rows -> A panels L2-resident.
  const int tpx = gridDim.x >> 3;
  const int tile = (blockIdx.x & 7) * tpx + (blockIdx.x >> 3);
  const int m0 = (tile / ntn) * 128, n0 = (tile % ntn) * 128;
  const int wid = tid >> 6;
  const int wr = (wid >> 1) * 64, wc = (wid & 1) * 64;
  const int fr = lane & 15, fq = lane >> 4;
  // staging: 256 threads cover 32 rows x 128B per GLL round; 4 rounds/matrix
  const int srow8 = tid >> 3;                 // 0..31
  const int ssb = ((tid & 7) << 4) ^ ((srow8 & 7) << 4);  // swizzled src col byte
  const char* aS = (const char*)(A + (size_t)(m0 + srow8) * K) + ssb;
  const char* bS = (const char*)(BT + (size_t)(n0 + srow8) * K) + ssb;
  char* aD = (char*)As + tid * 16;
  char* bD = (char*)Bs + tid * 16;
  // swizzled read offsets (same XOR family as staging)
  const int rk0 = (fq << 4) ^ ((fr & 7) << 4);
  const int rk1 = ((fq << 4) + 64) ^ ((fr & 7) << 4);
  f32x4 acc[4][4] = {};
  for (int k0 = 0; k0 < K; k0 += 64) {
    const size_t kb = (size_t)k0 * 2;
#pragma unroll
    for (int gg = 0; gg < 4; ++gg)
      GLL16(aS + (size_t)(gg * 32) * K * 2 + kb, aD + gg * 4096);
#pragma unroll
    for (int gg = 0; gg < 4; ++gg)
      GLL16(bS + (size_t)(gg * 32) * K * 2 + kb, bD + gg * 4096);
    __syncthreads();
    bf16x8 af[4][2], bfr[4][2];
#pragma unroll
    for (int mi = 0; mi < 4; ++mi) {
      const char* p = (char*)As + (wr + mi * 16 + fr) * 128;
      af[mi][0] = ld_bf16x8(p + rk0);
      af[mi][1] = ld_bf16x8(p + rk1);
    }
#pragma unroll
    for (int ni = 0; ni < 4; ++ni) {
      const char* p = (char*)Bs + (wc + ni * 16 + fr) * 128;
      bfr[ni][0] = ld_bf16x8(p + rk0);
      bfr[ni][1] = ld_bf16x8(p + rk1);
    }
#pragma unroll
    for (int mi = 0; mi < 4; ++mi)
#pragma unroll
      for (int ni = 0; ni < 4; ++ni) {
        acc[mi][ni] = __builtin_amdgcn_mfma_f32_16x16x32_bf16(
            af[mi][0], bfr[ni][0], acc[mi][ni], 0, 0, 0);
        acc[mi][ni] = __builtin_amdgcn_mfma_f32_16x16x32_bf16(
            af[mi][1], bfr[ni][1], acc[mi][ni], 0, 0, 0);
      }
    __syncthreads();
  }
#pragma unroll
  for (int mi = 0; mi < 4; ++mi) {
#pragma unroll
    for (int ni = 0; ni < 4; ++ni) {
#pragma unroll
      for (int j = 0; j < 4; ++j) {
        const int r = m0 + wr + mi * 16 + fq * 4 + j;
        const int c = n0 + wc + ni * 16 + fr;
        const float v = acc[mi][ni][j];
        if (MODE == 2) {
          outF[(size_t)r * N + c] = v;
        } else if (MODE == 1) {
          const int h = c >> 6, d = c & 63;
          o_rT[((size_t)h * TSEQ + r) * DHD + d] = __float2bfloat16(v);
        } else {
          const int t = r >> 1, bb = r & 1;
          if (c < 1024) {
            const int h = c >> 6, d = c & 63;
            o_qw[(((size_t)(bb * NH + h)) * TSEQ + t) * DHD + d] = __float2bfloat16(v + rwb[c]);
          } else if (c < 2048) {
            const int e = c - 1024, h = e >> 6, d = e & 63;
            o_k[(((size_t)(bb * NH + h)) * TSEQ + t) * DHD + d] = __float2bfloat16(v);
          } else {
            const int e = c - 2048, h = e >> 6, d = e & 63;
            o_vT[(((size_t)(bb * NH + h)) * DHD + d) * TSEQ + t] = __float2bfloat16(v);
          }
        }
      }
    }
  }
}

// ---------- fused causal rel-attention: R11 structure (best measured) ----------
// 1 wait + 1 barrier per iter; K/V/R prefetched one tile ahead; circular
// 192-row Rsm; both-sides XOR swizzle; swapped-core math; plq/braw overlay;
// qr reconstructed from bias delta (qr tensor eliminated).
__global__ __launch_bounds__(256, 2) void k_attn(
    const __hip_bfloat16* __restrict__ qw,
    const __hip_bfloat16* __restrict__ kb, const __hip_bfloat16* __restrict__ vT,
    const __hip_bfloat16* __restrict__ rT,
    const float* __restrict__ rwb, const float* __restrict__ rrb,
    __hip_bfloat16* __restrict__ av) {
  const int tid = threadIdx.x, lane = tid & 63;
  const int w = __builtin_amdgcn_readfirstlane(tid >> 6);
  const int fr = lane & 15, fq = lane >> 4;
  const int l8 = lane >> 3, lb = lane & 7;
  const int bid = blockIdx.x;
  const int xcd = bid & 7, idx = bid >> 3;     // idx 0..63
  const int bh = xcd * 4 + (idx & 3);          // 4 heads per XCD
  const int pr = idx >> 2;                     // pair 0..15
  const int bb = bh >> 4, h = bh & 15;
  const char* Kp = (const char*)(kb + (size_t)bh * TSEQ * DHD);   // row t:128B
  const char* Vp = (const char*)(vT + (size_t)bh * DHD * TSEQ);   // row d:4096B
  const char* Rp = (const char*)(rT + (size_t)h * TSEQ * DHD);    // row t:128B

  __shared__ __align__(16) __hip_bfloat16 Ksm[2][64][64];   // 16 KB
  __shared__ __align__(16) __hip_bfloat16 Vsm[2][64][64];   // 16 KB
  __shared__ __align__(16) __hip_bfloat16 Rsm[192][64];     // 24 KB circular
  __shared__ __align__(16) char scratch[4][5632];           // braw/plq overlay

  const int swz = (lb << 4) ^ (l8 << 4);                 // staging src byte
  const int koff0 = (fq << 4) ^ ((fr & 7) << 4);         // swizzled read c=0
  const int koff1 = ((fq << 4) + 64) ^ ((fr & 7) << 4);  // swizzled read c=1
  const int rowA = w * 16 + l8;                          // K/V stage rows
  const int kOff0 = rowA * 128 + swz, kOff1 = (rowA + 8) * 128 + swz;
  const int vOff0 = rowA * 4096 + swz, vOff1 = (rowA + 8) * 4096 + swz;
  char* kDstB = (char*)Ksm + w * 2048 + lane * 16;   // + buf*8192
  char* vDstB = (char*)Vsm + w * 2048 + lane * 16;
  char* RsmC = (char*)Rsm;
  float* brawW = (float*)scratch[w];                       // [16][88] f32
  __hip_bfloat16* plqW = (__hip_bfloat16*)scratch[w];      // [16][72] bf16 overlay
  const f32x4 zero = {0.f, 0.f, 0.f, 0.f};
  struct B4 { __hip_bfloat16 a, b, c, d; };

  const float* rwbh = rwb + h * 64;
  const float* rrbh = rrb + h * 64;

#pragma unroll
  for (int part = 0; part < 2; ++part) {
    const int p4 = part ? 31 - pr : pr;
    const int nk = p4 + 1;
    const int iw0 = p4 * 64 + w * 16;
    const int rbase0 = 1984 - 64 * p4;
    int rm = (((1 - p4) % 3) + 3) % 3 * 64;    // rbase0 mod 192
    const __hip_bfloat16* qwp = qw + ((size_t)bh * TSEQ + iw0 + fr) * DHD + fq * 8;
    const bf16x8 qwf0 = ld_bf16x8(qwp), qwf1 = ld_bf16x8(qwp + 32);
    bf16x8 qrf0, qrf1;   // qr reconstructed from bias delta
#pragma unroll
    for (int e = 0; e < 8; ++e) {
      qrf0[e] = (__bf16)((float)qwf0[e] + rrbh[fq * 8 + e] - rwbh[fq * 8 + e]);
      qrf1[e] = (__bf16)((float)qwf1[e] + rrbh[32 + fq * 8 + e] - rwbh[32 + fq * 8 + e]);
    }
    f32x4 o[4] = {};
    float mrow = -INFINITY, lrow = 0.f;

    __builtin_amdgcn_s_barrier();   // protect previous part's reads

    // ---- prologue: K(0),V(0) -> buf0; R rows [rbase0, rbase0+128) ----
    GLL16(Kp + kOff0, kDstB);
    GLL16(Kp + kOff1, kDstB + 1024);
    GLL16(Vp + vOff0, vDstB);
    GLL16(Vp + vOff1, vDstB + 1024);
#pragma unroll
    for (int s = 0; s < 4; ++s) {
      int pb = rm + w * 32 + s * 8;
      if (pb >= 192) pb -= 192;
      int g = rbase0 + w * 32 + s * 8 + l8;
      g = g > 2047 ? 2047 : g;
      GLL16(Rp + g * 128 + swz, RsmC + pb * 128 + (lb << 4));
    }

    int rbase = rbase0;
    int thr = iw0 + fr;
    const char* kTile = Kp + 8192;    // src for K(kt+1)
    const char* vTile = Vp + 128;     // src for V(kt+1)
    for (int kt = 0; kt < nk; ++kt) {
      asm volatile("s_waitcnt vmcnt(0)" ::: "memory");
      __builtin_amdgcn_s_barrier();
      // ---- prefetch tile kt+1 (skip on last) ----
      if (kt + 1 < nk) {
        const int nxtOff = ((kt + 1) & 1) << 13;
        GLL16(kTile + kOff0, kDstB + nxtOff);
        GLL16(kTile + kOff1, kDstB + nxtOff + 1024);
        GLL16(vTile + vOff0, vDstB + nxtOff);
        GLL16(vTile + vOff1, vDstB + nxtOff + 1024);
        const int rm2 = rm >= 64 ? rm - 64 : rm + 128;   // (rbase+128) mod 192
#pragma unroll
        for (int s = 0; s < 2; ++s) {
          int g = rbase + 128 + w * 16 + s * 8 + l8;
          g = g > 2047 ? 2047 : g;
          GLL16(Rp + g * 128 + swz,
                RsmC + (rm2 + w * 16 + s * 8) * 128 + (lb << 4));
        }
        kTile += 8192;
        vTile += 128;
      }
      // ---- S^T from Ksm[cur] (staged last iter; ready) ----
      const int curOff = (kt & 1) << 13;
      const char* kls = (const char*)Ksm + curOff + fr * 128;
      f32x4 st[4];
      __builtin_amdgcn_s_setprio(1);
#pragma unroll
      for (int n = 0; n < 4; ++n) {
        st[n] = __builtin_amdgcn_mfma_f32_16x16x32_bf16(ld_bf16x8(kls + n * 2048 + koff0), qwf0, zero, 0, 0, 0);
        st[n] = __builtin_amdgcn_mfma_f32_16x16x32_bf16(ld_bf16x8(kls + n * 2048 + koff1), qwf1, st[n], 0, 0, 0);
      }
      __builtin_amdgcn_s_setprio(0);
      // ---- band from circular Rsm: D[m][q=fr] -> b128 braw write ----
      const int base_l = rm + 48 - 16 * w + fr;   // <= 191; == fr (mod 8)
      __builtin_amdgcn_s_setprio(1);
#pragma unroll
      for (int pp = 0; pp < 5; ++pp) {
        int rrow = base_l + 16 * pp;
        if (rrow >= 192) rrow -= 192;
        const char* rls = RsmC + rrow * 128;
        f32x4 br = __builtin_amdgcn_mfma_f32_16x16x32_bf16(ld_bf16x8(rls + koff0), qrf0, zero, 0, 0, 0);
        br = __builtin_amdgcn_mfma_f32_16x16x32_bf16(ld_bf16x8(rls + koff1), qrf1, br, 0, 0, 0);
        *reinterpret_cast<f32x4*>(&brawW[fr * 88 + pp * 16 + 4 * fq]) = br;
      }
      __builtin_amdgcn_s_setprio(0);
      // ---- scores + in-register online softmax (q = fr) ----
      const float* brd = &brawW[fr * 88 + 15 - fr];
      float mx = -INFINITY;
#pragma unroll
      for (int n = 0; n < 4; ++n) {
#pragma unroll
        for (int j = 0; j < 4; ++j) {
          const int koff = 16 * n + 4 * fq + j;
          const float s = (koff > thr) ? -INFINITY : (st[n][j] + brd[koff]) * 0.125f;
          st[n][j] = s;
          mx = fmaxf(mx, s);
        }
      }
      mx = fmaxf(mx, __shfl_xor(mx, 16));
      mx = fmaxf(mx, __shfl_xor(mx, 32));
      const float mn = fmaxf(mrow, mx);
      const float al = __expf(mrow - mn);
      mrow = mn;
      float rsum = 0.f;
#pragma unroll
      for (int n = 0; n < 4; ++n)
#pragma unroll
        for (int j = 0; j < 4; ++j) {
          const float pv = __expf(st[n][j] - mn);
          st[n][j] = pv;
          rsum += pv;
        }
      rsum += __shfl_xor(rsum, 16);
      rsum += __shfl_xor(rsum, 32);
      lrow = lrow * al + rsum;
#pragma unroll
      for (int nd = 0; nd < 4; ++nd) o[nd] *= al;
      // ---- P store (overlay; braw fully consumed) ----
#pragma unroll
      for (int n = 0; n < 4; ++n) {
        B4 pk;
        pk.a = __float2bfloat16(st[n][0]);
        pk.b = __float2bfloat16(st[n][1]);
        pk.c = __float2bfloat16(st[n][2]);
        pk.d = __float2bfloat16(st[n][3]);
        *reinterpret_cast<B4*>(&plqW[fr * 72 + 16 * n + 4 * fq]) = pk;
      }
      // ---- O^T += V^T . P^T from Vsm[cur] ----
      const char* vls = (const char*)Vsm + curOff + fr * 128;
      __builtin_amdgcn_s_setprio(1);
#pragma unroll
      for (int c = 0; c < 2; ++c) {
        const bf16x8 pf = ld_bf16x8(&plqW[fr * 72 + 8 * fq + 32 * c]);
#pragma unroll
        for (int nd = 0; nd < 4; ++nd)
          o[nd] = __builtin_amdgcn_mfma_f32_16x16x32_bf16(
              ld_bf16x8(vls + nd * 2048 + (c ? koff1 : koff0)), pf, o[nd], 0, 0, 0);
      }
      __builtin_amdgcn_s_setprio(0);
      // ---- advance ----
      rbase += 64;
      rm = rm >= 128 ? 0 : rm + 64;
      thr -= 64;
    }
    // ---- epilogue: per-lane 1/l, packed 8B stores; row i = iw0+fr ----
    const float linv = 1.f / lrow;
    const int i = iw0 + fr;
#pragma unroll
    for (int nd = 0; nd < 4; ++nd) {
      B4 pack;
      pack.a = __float2bfloat16(o[nd][0] * linv);
      pack.b = __float2bfloat16(o[nd][1] * linv);
      pack.c = __float2bfloat16(o[nd][2] * linv);
      pack.d = __float2bfloat16(o[nd][3] * linv);
      *reinterpret_cast<B4*>(av + ((size_t)i * NB + bb) * DM + h * DHD + 16 * nd + 4 * fq) = pack;
    }
  }
}

extern "C" void kernel_launch(void* const* d_in, const int* in_sizes, int n_in,
                              void* d_out, int out_size, void* d_ws, size_t ws_size,
                              hipStream_t stream) {
  (void)in_sizes; (void)n_in; (void)out_size; (void)ws_size;
  const float* x    = (const float*)d_in[0];
  const float* pos  = (const float*)d_in[1];
  const float* ln_g = (const float*)d_in[2];
  const float* ln_b = (const float*)d_in[3];
  const float* Wqkv = (const float*)d_in[4];
  const float* Wr   = (const float*)d_in[5];
  const float* Wo   = (const float*)d_in[6];
  const float* rwb  = (const float*)d_in[7];
  const float* rrb  = (const float*)d_in[8];
  float* out = (float*)d_out;

  char* ws = (char*)d_ws;
  size_t off = 0;
  auto alloc = [&](size_t n) {
    char* p = ws + off; off += (n + 255) & ~(size_t)255; return p;
  };
  __hip_bfloat16* wqkvT = (__hip_bfloat16*)alloc((size_t)3072 * 1024 * 2);
  __hip_bfloat16* wrT   = (__hip_bfloat16*)alloc((size_t)1024 * 1024 * 2);
  __hip_bfloat16* woT   = (__hip_bfloat16*)alloc((size_t)1024 * 1024 * 2);
  __hip_bfloat16* posb  = (__hip_bfloat16*)alloc((size_t)2048 * 1024 * 2);
  __hip_bfloat16* xn    = (__hip_bfloat16*)alloc((size_t)4096 * 1024 * 2);
  __hip_bfloat16* qwb   = (__hip_bfloat16*)alloc((size_t)NB * NH * TSEQ * DHD * 2);
  __hip_bfloat16* kbb   = (__hip_bfloat16*)alloc((size_t)NB * NH * TSEQ * DHD * 2);
  __hip_bfloat16* vTb   = (__hip_bfloat16*)alloc((size_t)NB * NH * TSEQ * DHD * 2);
  __hip_bfloat16* rTb   = (__hip_bfloat16*)alloc((size_t)NH * TSEQ * DHD * 2);
  __hip_bfloat16* avb   = (__hip_bfloat16*)alloc((size_t)4096 * 1024 * 2);
  (void)alloc(64 * 1024);  // guard region

  k_prep<<<11264, 256, 0, stream>>>(Wqkv, Wr, Wo, wqkvT, wrT, woT,
                                    pos, posb, x, ln_g, ln_b, xn);
  k_gemm_bt<0><<<32 * 24, 256, 0, stream>>>(xn, wqkvT, 4096, 3072, 1024,
      nullptr, qwb, kbb, vTb, rwb, nullptr);
  k_gemm_bt<1><<<16 * 8, 256, 0, stream>>>(posb, wrT, 2048, 1024, 1024,
      nullptr, nullptr, nullptr, nullptr, nullptr, rTb);
  k_attn<<<512, 256, 0, stream>>>(qwb, kbb, vTb, rTb, rwb, rrb, avb);
  k_gemm_bt<2><<<32 * 8, 256, 0, stream>>>(avb, woT, 4096, 1024, 1024,
      out, nullptr, nullptr, nullptr, nullptr, nullptr);
}

// Round 16
// 182.004 us; speedup vs baseline: 1.1420x; 1.0593x over previous
//
#include <hip/hip_runtime.h>
#include <hip/hip_bf16.h>
#include <math.h>

#define TSEQ 2048
#define NB 2
#define DM 1024
#define NH 16
#define DHD 64

typedef __attribute__((ext_vector_type(8))) __bf16 bf16x8;
typedef __attribute__((ext_vector_type(8))) short s16x8;
typedef __attribute__((ext_vector_type(4))) float f32x4;

__device__ __forceinline__ bf16x8 ld_bf16x8(const void* p) {
  s16x8 v = *reinterpret_cast<const s16x8*>(p);
  return __builtin_bit_cast(bf16x8, v);
}

#define GLL16(g, l) __builtin_amdgcn_global_load_lds( \
    (const __attribute__((address_space(1))) void*)(g), \
    (__attribute__((address_space(3))) void*)(l), 16, 0, 0)

// ---------- fused prep: weight transposes + pos cast + LayerNorm ----------
__global__ __launch_bounds__(256) void k_prep(
    const float* __restrict__ Wqkv, const float* __restrict__ Wr,
    const float* __restrict__ Wo, __hip_bfloat16* __restrict__ wqkvT,
    __hip_bfloat16* __restrict__ wrT, __hip_bfloat16* __restrict__ woT,
    const float* __restrict__ pos, __hip_bfloat16* __restrict__ posb,
    const float* __restrict__ x, const float* __restrict__ g,
    const float* __restrict__ b, __hip_bfloat16* __restrict__ xn) {
  __shared__ float t[32][33];
  __shared__ float r1[4], r2[4];
  const int blk = blockIdx.x, tid = threadIdx.x;
  struct B4 { __hip_bfloat16 a, b, c, d; };
  if (blk < 5120) {
    const int tx = tid & 31, ty = tid >> 5;
    const float* in; __hip_bfloat16* out; int C, bx, by;
    if (blk < 3072)      { in = Wqkv; out = wqkvT; C = 3072; bx = blk % 96;  by = blk / 96; }
    else if (blk < 4096) { in = Wr;   out = wrT;   C = 1024; bx = (blk - 3072) % 32; by = (blk - 3072) / 32; }
    else                 { in = Wo;   out = woT;   C = 1024; bx = (blk - 4096) % 32; by = (blk - 4096) / 32; }
    const int c0 = bx * 32, r0 = by * 32;
#pragma unroll
    for (int j = 0; j < 4; ++j)
      t[ty + j * 8][tx] = in[(size_t)(r0 + ty + j * 8) * C + c0 + tx];
    __syncthreads();
#pragma unroll
    for (int j = 0; j < 4; ++j) {
      const int oc = ty + j * 8;
      out[(size_t)(c0 + oc) * 1024 + r0 + tx] = __float2bfloat16(t[tx][oc]);
    }
  } else if (blk < 7168) {
    const int i = ((blk - 5120) * 256 + tid) * 4;
    const float4 v = *reinterpret_cast<const float4*>(pos + i);
    B4 o;
    o.a = __float2bfloat16(v.x); o.b = __float2bfloat16(v.y);
    o.c = __float2bfloat16(v.z); o.d = __float2bfloat16(v.w);
    *reinterpret_cast<B4*>(posb + i) = o;
  } else {
    const int row = blk - 7168;
    const float4 v = reinterpret_cast<const float4*>(x + (size_t)row * DM)[tid];
    float s = v.x + v.y + v.z + v.w;
#pragma unroll
    for (int off = 32; off; off >>= 1) s += __shfl_xor(s, off);
    if ((tid & 63) == 0) r1[tid >> 6] = s;
    __syncthreads();
    const float mu = (r1[0] + r1[1] + r1[2] + r1[3]) * (1.f / DM);
    const float dx = v.x - mu, dy = v.y - mu, dz = v.z - mu, dw = v.w - mu;
    float q = dx * dx + dy * dy + dz * dz + dw * dw;
#pragma unroll
    for (int off = 32; off; off >>= 1) q += __shfl_xor(q, off);
    if ((tid & 63) == 0) r2[tid >> 6] = q;
    __syncthreads();
    const float rs = rsqrtf((r2[0] + r2[1] + r2[2] + r2[3]) * (1.f / DM) + 1e-5f);
    const float4 gv = reinterpret_cast<const float4*>(g)[tid];
    const float4 bv = reinterpret_cast<const float4*>(b)[tid];
    B4 o;
    o.a = __float2bfloat16(dx * rs * gv.x + bv.x);
    o.b = __float2bfloat16(dy * rs * gv.y + bv.y);
    o.c = __float2bfloat16(dz * rs * gv.z + bv.z);
    o.d = __float2bfloat16(dw * rs * gv.w + bv.w);
    reinterpret_cast<B4*>(xn + (size_t)row * DM)[tid] = o;
  }
}

// ---------- merged QKV + R GEMM: 896 blocks (768 MODE0 + 128 MODE1) ----------
// BM=128, BK=64, XOR-swizzled LDS (both-sides), XCD-contiguous remap (896=8x112).
__global__ __launch_bounds__(256) void k_gemm01(
    const __hip_bfloat16* __restrict__ xn, const __hip_bfloat16* __restrict__ wqkvT,
    const __hip_bfloat16* __restrict__ posb, const __hip_bfloat16* __restrict__ wrT,
    __hip_bfloat16* __restrict__ o_qw, __hip_bfloat16* __restrict__ o_k,
    __hip_bfloat16* __restrict__ o_vT, const float* __restrict__ rwb,
    __hip_bfloat16* __restrict__ o_rT) {
  __shared__ __align__(16) __hip_bfloat16 As[128 * 64];
  __shared__ __align__(16) __hip_bfloat16 Bs[128 * 64];
  const int tid = threadIdx.x, lane = tid & 63;
  const int tile = (blockIdx.x & 7) * 112 + (blockIdx.x >> 3);
  const bool q0 = tile < 768;
  const int t0 = q0 ? tile : tile - 768;
  const int ntn = q0 ? 24 : 8;
  const __hip_bfloat16* A  = q0 ? xn : posb;
  const __hip_bfloat16* BT = q0 ? wqkvT : wrT;
  const int K = 1024;
  const int m0 = (t0 / ntn) * 128, n0 = (t0 % ntn) * 128;
  const int wid = tid >> 6;
  const int wr = (wid >> 1) * 64, wc = (wid & 1) * 64;
  const int fr = lane & 15, fq = lane >> 4;
  const int srow8 = tid >> 3;
  const int ssb = ((tid & 7) << 4) ^ ((srow8 & 7) << 4);
  const char* aS = (const char*)(A + (size_t)(m0 + srow8) * K) + ssb;
  const char* bS = (const char*)(BT + (size_t)(n0 + srow8) * K) + ssb;
  char* aD = (char*)As + tid * 16;
  char* bD = (char*)Bs + tid * 16;
  const int rk0 = (fq << 4) ^ ((fr & 7) << 4);
  const int rk1 = ((fq << 4) + 64) ^ ((fr & 7) << 4);
  f32x4 acc[4][4] = {};
  for (int k0 = 0; k0 < K; k0 += 64) {
    const size_t kb = (size_t)k0 * 2;
#pragma unroll
    for (int gg = 0; gg < 4; ++gg)
      GLL16(aS + (size_t)(gg * 32) * K * 2 + kb, aD + gg * 4096);
#pragma unroll
    for (int gg = 0; gg < 4; ++gg)
      GLL16(bS + (size_t)(gg * 32) * K * 2 + kb, bD + gg * 4096);
    __syncthreads();
    bf16x8 af[4][2], bfr[4][2];
#pragma unroll
    for (int mi = 0; mi < 4; ++mi) {
      const char* p = (char*)As + (wr + mi * 16 + fr) * 128;
      af[mi][0] = ld_bf16x8(p + rk0);
      af[mi][1] = ld_bf16x8(p + rk1);
    }
#pragma unroll
    for (int ni = 0; ni < 4; ++ni) {
      const char* p = (char*)Bs + (wc + ni * 16 + fr) * 128;
      bfr[ni][0] = ld_bf16x8(p + rk0);
      bfr[ni][1] = ld_bf16x8(p + rk1);
    }
#pragma unroll
    for (int mi = 0; mi < 4; ++mi)
#pragma unroll
      for (int ni = 0; ni < 4; ++ni) {
        acc[mi][ni] = __builtin_amdgcn_mfma_f32_16x16x32_bf16(
            af[mi][0], bfr[ni][0], acc[mi][ni], 0, 0, 0);
        acc[mi][ni] = __builtin_amdgcn_mfma_f32_16x16x32_bf16(
            af[mi][1], bfr[ni][1], acc[mi][ni], 0, 0, 0);
      }
    __syncthreads();
  }
#pragma unroll
  for (int mi = 0; mi < 4; ++mi) {
#pragma unroll
    for (int ni = 0; ni < 4; ++ni) {
#pragma unroll
      for (int j = 0; j < 4; ++j) {
        const int r = m0 + wr + mi * 16 + fq * 4 + j;
        const int c = n0 + wc + ni * 16 + fr;
        const float v = acc[mi][ni][j];
        if (q0) {
          const int t = r >> 1, bb = r & 1;
          if (c < 1024) {
            const int h = c >> 6, d = c & 63;
            o_qw[(((size_t)(bb * NH + h)) * TSEQ + t) * DHD + d] = __float2bfloat16(v + rwb[c]);
          } else if (c < 2048) {
            const int e = c - 1024, h = e >> 6, d = e & 63;
            o_k[(((size_t)(bb * NH + h)) * TSEQ + t) * DHD + d] = __float2bfloat16(v);
          } else {
            const int e = c - 2048, h = e >> 6, d = e & 63;
            o_vT[(((size_t)(bb * NH + h)) * DHD + d) * TSEQ + t] = __float2bfloat16(v);
          }
        } else {
          const int h = c >> 6, d = c & 63;
          o_rT[((size_t)h * TSEQ + r) * DHD + d] = __float2bfloat16(v);
        }
      }
    }
  }
}

// ---------- out GEMM: R14-proven BM=128 geometry, 256 blocks, fp32 out ----------
__global__ __launch_bounds__(256) void k_gemm2(
    const __hip_bfloat16* __restrict__ A, const __hip_bfloat16* __restrict__ BT,
    float* __restrict__ outF) {
  __shared__ __align__(16) __hip_bfloat16 As[128 * 64];
  __shared__ __align__(16) __hip_bfloat16 Bs[128 * 64];
  const int tid = threadIdx.x, lane = tid & 63;
  const int K = 1024, N = 1024, ntn = 8;
  const int tile = (blockIdx.x & 7) * 32 + (blockIdx.x >> 3);   // 256 = 8*32
  const int m0 = (tile / ntn) * 128, n0 = (tile % ntn) * 128;
  const int wid = tid >> 6;
  const int wr = (wid >> 1) * 64, wc = (wid & 1) * 64;
  const int fr = lane & 15, fq = lane >> 4;
  const int srow8 = tid >> 3;
  const int ssb = ((tid & 7) << 4) ^ ((srow8 & 7) << 4);
  const char* aS = (const char*)(A + (size_t)(m0 + srow8) * K) + ssb;
  const char* bS = (const char*)(BT + (size_t)(n0 + srow8) * K) + ssb;
  char* aD = (char*)As + tid * 16;
  char* bD = (char*)Bs + tid * 16;
  const int rk0 = (fq << 4) ^ ((fr & 7) << 4);
  const int rk1 = ((fq << 4) + 64) ^ ((fr & 7) << 4);
  f32x4 acc[4][4] = {};
  for (int k0 = 0; k0 < K; k0 += 64) {
    const size_t kb = (size_t)k0 * 2;
#pragma unroll
    for (int gg = 0; gg < 4; ++gg)
      GLL16(aS + (size_t)(gg * 32) * K * 2 + kb, aD + gg * 4096);
#pragma unroll
    for (int gg = 0; gg < 4; ++gg)
      GLL16(bS + (size_t)(gg * 32) * K * 2 + kb, bD + gg * 4096);
    __syncthreads();
    bf16x8 af[4][2], bfr[4][2];
#pragma unroll
    for (int mi = 0; mi < 4; ++mi) {
      const char* p = (char*)As + (wr + mi * 16 + fr) * 128;
      af[mi][0] = ld_bf16x8(p + rk0);
      af[mi][1] = ld_bf16x8(p + rk1);
    }
#pragma unroll
    for (int ni = 0; ni < 4; ++ni) {
      const char* p = (char*)Bs + (wc + ni * 16 + fr) * 128;
      bfr[ni][0] = ld_bf16x8(p + rk0);
      bfr[ni][1] = ld_bf16x8(p + rk1);
    }
#pragma unroll
    for (int mi = 0; mi < 4; ++mi)
#pragma unroll
      for (int ni = 0; ni < 4; ++ni) {
        acc[mi][ni] = __builtin_amdgcn_mfma_f32_16x16x32_bf16(
            af[mi][0], bfr[ni][0], acc[mi][ni], 0, 0, 0);
        acc[mi][ni] = __builtin_amdgcn_mfma_f32_16x16x32_bf16(
            af[mi][1], bfr[ni][1], acc[mi][ni], 0, 0, 0);
      }
    __syncthreads();
  }
#pragma unroll
  for (int mi = 0; mi < 4; ++mi)
#pragma unroll
    for (int ni = 0; ni < 4; ++ni)
#pragma unroll
      for (int j = 0; j < 4; ++j) {
        const int r = m0 + wr + mi * 16 + fq * 4 + j;
        const int c = n0 + wc + ni * 16 + fr;
        outF[(size_t)r * N + c] = acc[mi][ni][j];
      }
}

// ---------- fused causal rel-attention: R11 structure (best measured) ----------
// (R14 verbatim + free lgkmcnt(0) hardening before the part-boundary barrier)
__global__ __launch_bounds__(256, 2) void k_attn(
    const __hip_bfloat16* __restrict__ qw,
    const __hip_bfloat16* __restrict__ kb, const __hip_bfloat16* __restrict__ vT,
    const __hip_bfloat16* __restrict__ rT,
    const float* __restrict__ rwb, const float* __restrict__ rrb,
    __hip_bfloat16* __restrict__ av) {
  const int tid = threadIdx.x, lane = tid & 63;
  const int w = __builtin_amdgcn_readfirstlane(tid >> 6);
  const int fr = lane & 15, fq = lane >> 4;
  const int l8 = lane >> 3, lb = lane & 7;
  const int bid = blockIdx.x;
  const int xcd = bid & 7, idx = bid >> 3;     // idx 0..63
  const int bh = xcd * 4 + (idx & 3);          // 4 heads per XCD
  const int pr = idx >> 2;                     // pair 0..15
  const int bb = bh >> 4, h = bh & 15;
  const char* Kp = (const char*)(kb + (size_t)bh * TSEQ * DHD);   // row t:128B
  const char* Vp = (const char*)(vT + (size_t)bh * DHD * TSEQ);   // row d:4096B
  const char* Rp = (const char*)(rT + (size_t)h * TSEQ * DHD);    // row t:128B

  __shared__ __align__(16) __hip_bfloat16 Ksm[2][64][64];   // 16 KB
  __shared__ __align__(16) __hip_bfloat16 Vsm[2][64][64];   // 16 KB
  __shared__ __align__(16) __hip_bfloat16 Rsm[192][64];     // 24 KB circular
  __shared__ __align__(16) char scratch[4][5632];           // braw/plq overlay

  const int swz = (lb << 4) ^ (l8 << 4);                 // staging src byte
  const int koff0 = (fq << 4) ^ ((fr & 7) << 4);         // swizzled read c=0
  const int koff1 = ((fq << 4) + 64) ^ ((fr & 7) << 4);  // swizzled read c=1
  const int rowA = w * 16 + l8;                          // K/V stage rows
  const int kOff0 = rowA * 128 + swz, kOff1 = (rowA + 8) * 128 + swz;
  const int vOff0 = rowA * 4096 + swz, vOff1 = (rowA + 8) * 4096 + swz;
  char* kDstB = (char*)Ksm + w * 2048 + lane * 16;   // + buf*8192
  char* vDstB = (char*)Vsm + w * 2048 + lane * 16;
  char* RsmC = (char*)Rsm;
  float* brawW = (float*)scratch[w];                       // [16][88] f32
  __hip_bfloat16* plqW = (__hip_bfloat16*)scratch[w];      // [16][72] bf16 overlay
  const f32x4 zero = {0.f, 0.f, 0.f, 0.f};
  struct B4 { __hip_bfloat16 a, b, c, d; };

  const float* rwbh = rwb + h * 64;
  const float* rrbh = rrb + h * 64;

#pragma unroll
  for (int part = 0; part < 2; ++part) {
    const int p4 = part ? 31 - pr : pr;
    const int nk = p4 + 1;
    const int iw0 = p4 * 64 + w * 16;
    const int rbase0 = 1984 - 64 * p4;
    int rm = (((1 - p4) % 3) + 3) % 3 * 64;    // rbase0 mod 192
    const __hip_bfloat16* qwp = qw + ((size_t)bh * TSEQ + iw0 + fr) * DHD + fq * 8;
    const bf16x8 qwf0 = ld_bf16x8(qwp), qwf1 = ld_bf16x8(qwp + 32);
    bf16x8 qrf0, qrf1;   // qr reconstructed from bias delta
#pragma unroll
    for (int e = 0; e < 8; ++e) {
      qrf0[e] = (__bf16)((float)qwf0[e] + rrbh[fq * 8 + e] - rwbh[fq * 8 + e]);
      qrf1[e] = (__bf16)((float)qwf1[e] + rrbh[32 + fq * 8 + e] - rwbh[32 + fq * 8 + e]);
    }
    f32x4 o[4] = {};
    float mrow = -INFINITY, lrow = 0.f;

    asm volatile("s_waitcnt lgkmcnt(0)" ::: "memory");  // harden: all LDS ops done
    __builtin_amdgcn_s_barrier();   // protect previous part's reads

    // ---- prologue: K(0),V(0) -> buf0; R rows [rbase0, rbase0+128) ----
    GLL16(Kp + kOff0, kDstB);
    GLL16(Kp + kOff1, kDstB + 1024);
    GLL16(Vp + vOff0, vDstB);
    GLL16(Vp + vOff1, vDstB + 1024);
#pragma unroll
    for (int s = 0; s < 4; ++s) {
      int pb = rm + w * 32 + s * 8;
      if (pb >= 192) pb -= 192;
      int g = rbase0 + w * 32 + s * 8 + l8;
      g = g > 2047 ? 2047 : g;
      GLL16(Rp + g * 128 + swz, RsmC + pb * 128 + (lb << 4));
    }

    int rbase = rbase0;
    int thr = iw0 + fr;
    const char* kTile = Kp + 8192;    // src for K(kt+1)
    const char* vTile = Vp + 128;     // src for V(kt+1)
    for (int kt = 0; kt < nk; ++kt) {
      asm volatile("s_waitcnt vmcnt(0)" ::: "memory");
      __builtin_amdgcn_s_barrier();
      // ---- prefetch tile kt+1 (skip on last) ----
      if (kt + 1 < nk) {
        const int nxtOff = ((kt + 1) & 1) << 13;
        GLL16(kTile + kOff0, kDstB + nxtOff);
        GLL16(kTile + kOff1, kDstB + nxtOff + 1024);
        GLL16(vTile + vOff0, vDstB + nxtOff);
        GLL16(vTile + vOff1, vDstB + nxtOff + 1024);
        const int rm2 = rm >= 64 ? rm - 64 : rm + 128;   // (rbase+128) mod 192
#pragma unroll
        for (int s = 0; s < 2; ++s) {
          int g = rbase + 128 + w * 16 + s * 8 + l8;
          g = g > 2047 ? 2047 : g;
          GLL16(Rp + g * 128 + swz,
                RsmC + (rm2 + w * 16 + s * 8) * 128 + (lb << 4));
        }
        kTile += 8192;
        vTile += 128;
      }
      // ---- S^T from Ksm[cur] (staged last iter; ready) ----
      const int curOff = (kt & 1) << 13;
      const char* kls = (const char*)Ksm + curOff + fr * 128;
      f32x4 st[4];
      __builtin_amdgcn_s_setprio(1);
#pragma unroll
      for (int n = 0; n < 4; ++n) {
        st[n] = __builtin_amdgcn_mfma_f32_16x16x32_bf16(ld_bf16x8(kls + n * 2048 + koff0), qwf0, zero, 0, 0, 0);
        st[n] = __builtin_amdgcn_mfma_f32_16x16x32_bf16(ld_bf16x8(kls + n * 2048 + koff1), qwf1, st[n], 0, 0, 0);
      }
      __builtin_amdgcn_s_setprio(0);
      // ---- band from circular Rsm: D[m][q=fr] -> b128 braw write ----
      const int base_l = rm + 48 - 16 * w + fr;   // <= 191; == fr (mod 8)
      __builtin_amdgcn_s_setprio(1);
#pragma unroll
      for (int pp = 0; pp < 5; ++pp) {
        int rrow = base_l + 16 * pp;
        if (rrow >= 192) rrow -= 192;
        const char* rls = RsmC + rrow * 128;
        f32x4 br = __builtin_amdgcn_mfma_f32_16x16x32_bf16(ld_bf16x8(rls + koff0), qrf0, zero, 0, 0, 0);
        br = __builtin_amdgcn_mfma_f32_16x16x32_bf16(ld_bf16x8(rls + koff1), qrf1, br, 0, 0, 0);
        *reinterpret_cast<f32x4*>(&brawW[fr * 88 + pp * 16 + 4 * fq]) = br;
      }
      __builtin_amdgcn_s_setprio(0);
      // ---- scores + in-register online softmax (q = fr) ----
      const float* brd = &brawW[fr * 88 + 15 - fr];
      float mx = -INFINITY;
#pragma unroll
      for (int n = 0; n < 4; ++n) {
#pragma unroll
        for (int j = 0; j < 4; ++j) {
          const int koff = 16 * n + 4 * fq + j;
          const float s = (koff > thr) ? -INFINITY : (st[n][j] + brd[koff]) * 0.125f;
          st[n][j] = s;
          mx = fmaxf(mx, s);
        }
      }
      mx = fmaxf(mx, __shfl_xor(mx, 16));
      mx = fmaxf(mx, __shfl_xor(mx, 32));
      const float mn = fmaxf(mrow, mx);
      const float al = __expf(mrow - mn);
      mrow = mn;
      float rsum = 0.f;
#pragma unroll
      for (int n = 0; n < 4; ++n)
#pragma unroll
        for (int j = 0; j < 4; ++j) {
          const float pv = __expf(st[n][j] - mn);
          st[n][j] = pv;
          rsum += pv;
        }
      rsum += __shfl_xor(rsum, 16);
      rsum += __shfl_xor(rsum, 32);
      lrow = lrow * al + rsum;
#pragma unroll
      for (int nd = 0; nd < 4; ++nd) o[nd] *= al;
      // ---- P store (overlay; braw fully consumed) ----
#pragma unroll
      for (int n = 0; n < 4; ++n) {
        B4 pk;
        pk.a = __float2bfloat16(st[n][0]);
        pk.b = __float2bfloat16(st[n][1]);
        pk.c = __float2bfloat16(st[n][2]);
        pk.d = __float2bfloat16(st[n][3]);
        *reinterpret_cast<B4*>(&plqW[fr * 72 + 16 * n + 4 * fq]) = pk;
      }
      // ---- O^T += V^T . P^T from Vsm[cur] ----
      const char* vls = (const char*)Vsm + curOff + fr * 128;
      __builtin_amdgcn_s_setprio(1);
#pragma unroll
      for (int c = 0; c < 2; ++c) {
        const bf16x8 pf = ld_bf16x8(&plqW[fr * 72 + 8 * fq + 32 * c]);
#pragma unroll
        for (int nd = 0; nd < 4; ++nd)
          o[nd] = __builtin_amdgcn_mfma_f32_16x16x32_bf16(
              ld_bf16x8(vls + nd * 2048 + (c ? koff1 : koff0)), pf, o[nd], 0, 0, 0);
      }
      __builtin_amdgcn_s_setprio(0);
      // ---- advance ----
      rbase += 64;
      rm = rm >= 128 ? 0 : rm + 64;
      thr -= 64;
    }
    // ---- epilogue: per-lane 1/l, packed 8B stores; row i = iw0+fr ----
    const float linv = 1.f / lrow;
    const int i = iw0 + fr;
#pragma unroll
    for (int nd = 0; nd < 4; ++nd) {
      B4 pack;
      pack.a = __float2bfloat16(o[nd][0] * linv);
      pack.b = __float2bfloat16(o[nd][1] * linv);
      pack.c = __float2bfloat16(o[nd][2] * linv);
      pack.d = __float2bfloat16(o[nd][3] * linv);
      *reinterpret_cast<B4*>(av + ((size_t)i * NB + bb) * DM + h * DHD + 16 * nd + 4 * fq) = pack;
    }
  }
}

extern "C" void kernel_launch(void* const* d_in, const int* in_sizes, int n_in,
                              void* d_out, int out_size, void* d_ws, size_t ws_size,
                              hipStream_t stream) {
  (void)in_sizes; (void)n_in; (void)out_size; (void)ws_size;
  const float* x    = (const float*)d_in[0];
  const float* pos  = (const float*)d_in[1];
  const float* ln_g = (const float*)d_in[2];
  const float* ln_b = (const float*)d_in[3];
  const float* Wqkv = (const float*)d_in[4];
  const float* Wr   = (const float*)d_in[5];
  const float* Wo   = (const float*)d_in[6];
  const float* rwb  = (const float*)d_in[7];
  const float* rrb  = (const float*)d_in[8];
  float* out = (float*)d_out;

  char* ws = (char*)d_ws;
  size_t off = 0;
  auto alloc = [&](size_t n) {
    char* p = ws + off; off += (n + 255) & ~(size_t)255; return p;
  };
  __hip_bfloat16* wqkvT = (__hip_bfloat16*)alloc((size_t)3072 * 1024 * 2);
  __hip_bfloat16* wrT   = (__hip_bfloat16*)alloc((size_t)1024 * 1024 * 2);
  __hip_bfloat16* woT   = (__hip_bfloat16*)alloc((size_t)1024 * 1024 * 2);
  __hip_bfloat16* posb  = (__hip_bfloat16*)alloc((size_t)2048 * 1024 * 2);
  __hip_bfloat16* xn    = (__hip_bfloat16*)alloc((size_t)4096 * 1024 * 2);
  __hip_bfloat16* qwb   = (__hip_bfloat16*)alloc((size_t)NB * NH * TSEQ * DHD * 2);
  __hip_bfloat16* kbb   = (__hip_bfloat16*)alloc((size_t)NB * NH * TSEQ * DHD * 2);
  __hip_bfloat16* vTb   = (__hip_bfloat16*)alloc((size_t)NB * NH * TSEQ * DHD * 2);
  __hip_bfloat16* rTb   = (__hip_bfloat16*)alloc((size_t)NH * TSEQ * DHD * 2);
  __hip_bfloat16* avb   = (__hip_bfloat16*)alloc((size_t)4096 * 1024 * 2);
  (void)alloc(64 * 1024);  // guard region

  k_prep<<<11264, 256, 0, stream>>>(Wqkv, Wr, Wo, wqkvT, wrT, woT,
                                    pos, posb, x, ln_g, ln_b, xn);
  k_gemm01<<<896, 256, 0, stream>>>(xn, wqkvT, posb, wrT,
                                    qwb, kbb, vTb, rwb, rTb);
  k_attn<<<512, 256, 0, stream>>>(qwb, kbb, vTb, rTb, rwb, rrb, avb);
  k_gemm2<<<256, 256, 0, stream>>>(avb, woT, out);
}

// Round 17
// 176.896 us; speedup vs baseline: 1.1750x; 1.0289x over previous
//
#include <hip/hip_runtime.h>
#include <hip/hip_bf16.h>
#include <math.h>

#define TSEQ 2048
#define NB 2
#define DM 1024
#define NH 16
#define DHD 64

typedef __attribute__((ext_vector_type(8))) __bf16 bf16x8;
typedef __attribute__((ext_vector_type(8))) short s16x8;
typedef __attribute__((ext_vector_type(4))) float f32x4;

__device__ __forceinline__ bf16x8 ld_bf16x8(const void* p) {
  s16x8 v = *reinterpret_cast<const s16x8*>(p);
  return __builtin_bit_cast(bf16x8, v);
}

#define GLL16(g, l) __builtin_amdgcn_global_load_lds( \
    (const __attribute__((address_space(1))) void*)(g), \
    (__attribute__((address_space(3))) void*)(l), 16, 0, 0)

// ---------- fused prep: weight transposes + pos cast + LayerNorm ----------
__global__ __launch_bounds__(256) void k_prep(
    const float* __restrict__ Wqkv, const float* __restrict__ Wr,
    const float* __restrict__ Wo, __hip_bfloat16* __restrict__ wqkvT,
    __hip_bfloat16* __restrict__ wrT, __hip_bfloat16* __restrict__ woT,
    const float* __restrict__ pos, __hip_bfloat16* __restrict__ posb,
    const float* __restrict__ x, const float* __restrict__ g,
    const float* __restrict__ b, __hip_bfloat16* __restrict__ xn) {
  __shared__ float t[32][33];
  __shared__ float r1[4], r2[4];
  const int blk = blockIdx.x, tid = threadIdx.x;
  struct B4 { __hip_bfloat16 a, b, c, d; };
  if (blk < 5120) {
    const int tx = tid & 31, ty = tid >> 5;
    const float* in; __hip_bfloat16* out; int C, bx, by;
    if (blk < 3072)      { in = Wqkv; out = wqkvT; C = 3072; bx = blk % 96;  by = blk / 96; }
    else if (blk < 4096) { in = Wr;   out = wrT;   C = 1024; bx = (blk - 3072) % 32; by = (blk - 3072) / 32; }
    else                 { in = Wo;   out = woT;   C = 1024; bx = (blk - 4096) % 32; by = (blk - 4096) / 32; }
    const int c0 = bx * 32, r0 = by * 32;
#pragma unroll
    for (int j = 0; j < 4; ++j)
      t[ty + j * 8][tx] = in[(size_t)(r0 + ty + j * 8) * C + c0 + tx];
    __syncthreads();
#pragma unroll
    for (int j = 0; j < 4; ++j) {
      const int oc = ty + j * 8;
      out[(size_t)(c0 + oc) * 1024 + r0 + tx] = __float2bfloat16(t[tx][oc]);
    }
  } else if (blk < 7168) {
    const int i = ((blk - 5120) * 256 + tid) * 4;
    const float4 v = *reinterpret_cast<const float4*>(pos + i);
    B4 o;
    o.a = __float2bfloat16(v.x); o.b = __float2bfloat16(v.y);
    o.c = __float2bfloat16(v.z); o.d = __float2bfloat16(v.w);
    *reinterpret_cast<B4*>(posb + i) = o;
  } else {
    const int row = blk - 7168;
    const float4 v = reinterpret_cast<const float4*>(x + (size_t)row * DM)[tid];
    float s = v.x + v.y + v.z + v.w;
#pragma unroll
    for (int off = 32; off; off >>= 1) s += __shfl_xor(s, off);
    if ((tid & 63) == 0) r1[tid >> 6] = s;
    __syncthreads();
    const float mu = (r1[0] + r1[1] + r1[2] + r1[3]) * (1.f / DM);
    const float dx = v.x - mu, dy = v.y - mu, dz = v.z - mu, dw = v.w - mu;
    float q = dx * dx + dy * dy + dz * dz + dw * dw;
#pragma unroll
    for (int off = 32; off; off >>= 1) q += __shfl_xor(q, off);
    if ((tid & 63) == 0) r2[tid >> 6] = q;
    __syncthreads();
    const float rs = rsqrtf((r2[0] + r2[1] + r2[2] + r2[3]) * (1.f / DM) + 1e-5f);
    const float4 gv = reinterpret_cast<const float4*>(g)[tid];
    const float4 bv = reinterpret_cast<const float4*>(b)[tid];
    B4 o;
    o.a = __float2bfloat16(dx * rs * gv.x + bv.x);
    o.b = __float2bfloat16(dy * rs * gv.y + bv.y);
    o.c = __float2bfloat16(dz * rs * gv.z + bv.z);
    o.d = __float2bfloat16(dw * rs * gv.w + bv.w);
    reinterpret_cast<B4*>(xn + (size_t)row * DM)[tid] = o;
  }
}

// ---------- merged QKV + R GEMM: 896 blocks (768 MODE0 + 128 MODE1) ----------
// BM=128, BK=64, XOR-swizzled LDS (both-sides), XCD-contiguous remap (896=8x112).
__global__ __launch_bounds__(256) void k_gemm01(
    const __hip_bfloat16* __restrict__ xn, const __hip_bfloat16* __restrict__ wqkvT,
    const __hip_bfloat16* __restrict__ posb, const __hip_bfloat16* __restrict__ wrT,
    __hip_bfloat16* __restrict__ o_qw, __hip_bfloat16* __restrict__ o_k,
    __hip_bfloat16* __restrict__ o_vT, const float* __restrict__ rwb,
    __hip_bfloat16* __restrict__ o_rT) {
  __shared__ __align__(16) __hip_bfloat16 As[128 * 64];
  __shared__ __align__(16) __hip_bfloat16 Bs[128 * 64];
  const int tid = threadIdx.x, lane = tid & 63;
  const int tile = (blockIdx.x & 7) * 112 + (blockIdx.x >> 3);
  const bool q0 = tile < 768;
  const int t0 = q0 ? tile : tile - 768;
  const int ntn = q0 ? 24 : 8;
  const __hip_bfloat16* A  = q0 ? xn : posb;
  const __hip_bfloat16* BT = q0 ? wqkvT : wrT;
  const int K = 1024;
  const int m0 = (t0 / ntn) * 128, n0 = (t0 % ntn) * 128;
  const int wid = tid >> 6;
  const int wr = (wid >> 1) * 64, wc = (wid & 1) * 64;
  const int fr = lane & 15, fq = lane >> 4;
  const int srow8 = tid >> 3;
  const int ssb = ((tid & 7) << 4) ^ ((srow8 & 7) << 4);
  const char* aS = (const char*)(A + (size_t)(m0 + srow8) * K) + ssb;
  const char* bS = (const char*)(BT + (size_t)(n0 + srow8) * K) + ssb;
  char* aD = (char*)As + tid * 16;
  char* bD = (char*)Bs + tid * 16;
  const int rk0 = (fq << 4) ^ ((fr & 7) << 4);
  const int rk1 = ((fq << 4) + 64) ^ ((fr & 7) << 4);
  f32x4 acc[4][4] = {};
  for (int k0 = 0; k0 < K; k0 += 64) {
    const size_t kb = (size_t)k0 * 2;
#pragma unroll
    for (int gg = 0; gg < 4; ++gg)
      GLL16(aS + (size_t)(gg * 32) * K * 2 + kb, aD + gg * 4096);
#pragma unroll
    for (int gg = 0; gg < 4; ++gg)
      GLL16(bS + (size_t)(gg * 32) * K * 2 + kb, bD + gg * 4096);
    __syncthreads();
    bf16x8 af[4][2], bfr[4][2];
#pragma unroll
    for (int mi = 0; mi < 4; ++mi) {
      const char* p = (char*)As + (wr + mi * 16 + fr) * 128;
      af[mi][0] = ld_bf16x8(p + rk0);
      af[mi][1] = ld_bf16x8(p + rk1);
    }
#pragma unroll
    for (int ni = 0; ni < 4; ++ni) {
      const char* p = (char*)Bs + (wc + ni * 16 + fr) * 128;
      bfr[ni][0] = ld_bf16x8(p + rk0);
      bfr[ni][1] = ld_bf16x8(p + rk1);
    }
#pragma unroll
    for (int mi = 0; mi < 4; ++mi)
#pragma unroll
      for (int ni = 0; ni < 4; ++ni) {
        acc[mi][ni] = __builtin_amdgcn_mfma_f32_16x16x32_bf16(
            af[mi][0], bfr[ni][0], acc[mi][ni], 0, 0, 0);
        acc[mi][ni] = __builtin_amdgcn_mfma_f32_16x16x32_bf16(
            af[mi][1], bfr[ni][1], acc[mi][ni], 0, 0, 0);
      }
    __syncthreads();
  }
#pragma unroll
  for (int mi = 0; mi < 4; ++mi) {
#pragma unroll
    for (int ni = 0; ni < 4; ++ni) {
#pragma unroll
      for (int j = 0; j < 4; ++j) {
        const int r = m0 + wr + mi * 16 + fq * 4 + j;
        const int c = n0 + wc + ni * 16 + fr;
        const float v = acc[mi][ni][j];
        if (q0) {
          const int t = r >> 1, bb = r & 1;
          if (c < 1024) {
            const int h = c >> 6, d = c & 63;
            o_qw[(((size_t)(bb * NH + h)) * TSEQ + t) * DHD + d] = __float2bfloat16(v + rwb[c]);
          } else if (c < 2048) {
            const int e = c - 1024, h = e >> 6, d = e & 63;
            o_k[(((size_t)(bb * NH + h)) * TSEQ + t) * DHD + d] = __float2bfloat16(v);
          } else {
            const int e = c - 2048, h = e >> 6, d = e & 63;
            o_vT[(((size_t)(bb * NH + h)) * DHD + d) * TSEQ + t] = __float2bfloat16(v);
          }
        } else {
          const int h = c >> 6, d = c & 63;
          o_rT[((size_t)h * TSEQ + r) * DHD + d] = __float2bfloat16(v);
        }
      }
    }
  }
}

// ---------- out GEMM: BM=128 x BN=64, 512 blocks (2/CU), fp32 out ----------
// A-path byte-identical to proven BM=128 kernel; only the N-tile is halved:
// Bs 64x64 (2 staging rounds, same row formula), wc=(wid&1)*32, acc[4][2].
__global__ __launch_bounds__(256) void k_gemm2(
    const __hip_bfloat16* __restrict__ A, const __hip_bfloat16* __restrict__ BT,
    float* __restrict__ outF) {
  __shared__ __align__(16) __hip_bfloat16 As[128 * 64];   // 16 KB
  __shared__ __align__(16) __hip_bfloat16 Bs[64 * 64];    // 8 KB
  const int tid = threadIdx.x, lane = tid & 63;
  const int K = 1024, N = 1024, ntn = 16;
  const int tile = (blockIdx.x & 7) * 64 + (blockIdx.x >> 3);   // 512 = 8*64
  const int m0 = (tile / ntn) * 128, n0 = (tile % ntn) * 64;
  const int wid = tid >> 6;
  const int wr = (wid >> 1) * 64, wc = (wid & 1) * 32;
  const int fr = lane & 15, fq = lane >> 4;
  const int srow8 = tid >> 3;
  const int ssb = ((tid & 7) << 4) ^ ((srow8 & 7) << 4);
  const char* aS = (const char*)(A + (size_t)(m0 + srow8) * K) + ssb;
  const char* bS = (const char*)(BT + (size_t)(n0 + srow8) * K) + ssb;
  char* aD = (char*)As + tid * 16;
  char* bD = (char*)Bs + tid * 16;
  const int rk0 = (fq << 4) ^ ((fr & 7) << 4);
  const int rk1 = ((fq << 4) + 64) ^ ((fr & 7) << 4);
  f32x4 acc[4][2] = {};
  for (int k0 = 0; k0 < K; k0 += 64) {
    const size_t kb = (size_t)k0 * 2;
#pragma unroll
    for (int gg = 0; gg < 4; ++gg)
      GLL16(aS + (size_t)(gg * 32) * K * 2 + kb, aD + gg * 4096);
#pragma unroll
    for (int gg = 0; gg < 2; ++gg)
      GLL16(bS + (size_t)(gg * 32) * K * 2 + kb, bD + gg * 4096);
    __syncthreads();
    bf16x8 af[4][2], bfr[2][2];
#pragma unroll
    for (int mi = 0; mi < 4; ++mi) {
      const char* p = (char*)As + (wr + mi * 16 + fr) * 128;
      af[mi][0] = ld_bf16x8(p + rk0);
      af[mi][1] = ld_bf16x8(p + rk1);
    }
#pragma unroll
    for (int ni = 0; ni < 2; ++ni) {
      const char* p = (char*)Bs + (wc + ni * 16 + fr) * 128;
      bfr[ni][0] = ld_bf16x8(p + rk0);
      bfr[ni][1] = ld_bf16x8(p + rk1);
    }
#pragma unroll
    for (int mi = 0; mi < 4; ++mi)
#pragma unroll
      for (int ni = 0; ni < 2; ++ni) {
        acc[mi][ni] = __builtin_amdgcn_mfma_f32_16x16x32_bf16(
            af[mi][0], bfr[ni][0], acc[mi][ni], 0, 0, 0);
        acc[mi][ni] = __builtin_amdgcn_mfma_f32_16x16x32_bf16(
            af[mi][1], bfr[ni][1], acc[mi][ni], 0, 0, 0);
      }
    __syncthreads();
  }
#pragma unroll
  for (int mi = 0; mi < 4; ++mi)
#pragma unroll
    for (int ni = 0; ni < 2; ++ni)
#pragma unroll
      for (int j = 0; j < 4; ++j) {
        const int r = m0 + wr + mi * 16 + fq * 4 + j;
        const int c = n0 + wc + ni * 16 + fr;
        outF[(size_t)r * N + c] = acc[mi][ni][j];
      }
}

// ---------- fused causal rel-attention: R11 structure (best measured) ----------
__global__ __launch_bounds__(256, 2) void k_attn(
    const __hip_bfloat16* __restrict__ qw,
    const __hip_bfloat16* __restrict__ kb, const __hip_bfloat16* __restrict__ vT,
    const __hip_bfloat16* __restrict__ rT,
    const float* __restrict__ rwb, const float* __restrict__ rrb,
    __hip_bfloat16* __restrict__ av) {
  const int tid = threadIdx.x, lane = tid & 63;
  const int w = __builtin_amdgcn_readfirstlane(tid >> 6);
  const int fr = lane & 15, fq = lane >> 4;
  const int l8 = lane >> 3, lb = lane & 7;
  const int bid = blockIdx.x;
  const int xcd = bid & 7, idx = bid >> 3;     // idx 0..63
  const int bh = xcd * 4 + (idx & 3);          // 4 heads per XCD
  const int pr = idx >> 2;                     // pair 0..15
  const int bb = bh >> 4, h = bh & 15;
  const char* Kp = (const char*)(kb + (size_t)bh * TSEQ * DHD);   // row t:128B
  const char* Vp = (const char*)(vT + (size_t)bh * DHD * TSEQ);   // row d:4096B
  const char* Rp = (const char*)(rT + (size_t)h * TSEQ * DHD);    // row t:128B

  __shared__ __align__(16) __hip_bfloat16 Ksm[2][64][64];   // 16 KB
  __shared__ __align__(16) __hip_bfloat16 Vsm[2][64][64];   // 16 KB
  __shared__ __align__(16) __hip_bfloat16 Rsm[192][64];     // 24 KB circular
  __shared__ __align__(16) char scratch[4][5632];           // braw/plq overlay

  const int swz = (lb << 4) ^ (l8 << 4);                 // staging src byte
  const int koff0 = (fq << 4) ^ ((fr & 7) << 4);         // swizzled read c=0
  const int koff1 = ((fq << 4) + 64) ^ ((fr & 7) << 4);  // swizzled read c=1
  const int rowA = w * 16 + l8;                          // K/V stage rows
  const int kOff0 = rowA * 128 + swz, kOff1 = (rowA + 8) * 128 + swz;
  const int vOff0 = rowA * 4096 + swz, vOff1 = (rowA + 8) * 4096 + swz;
  char* kDstB = (char*)Ksm + w * 2048 + lane * 16;   // + buf*8192
  char* vDstB = (char*)Vsm + w * 2048 + lane * 16;
  char* RsmC = (char*)Rsm;
  float* brawW = (float*)scratch[w];                       // [16][88] f32
  __hip_bfloat16* plqW = (__hip_bfloat16*)scratch[w];      // [16][72] bf16 overlay
  const f32x4 zero = {0.f, 0.f, 0.f, 0.f};
  struct B4 { __hip_bfloat16 a, b, c, d; };

  const float* rwbh = rwb + h * 64;
  const float* rrbh = rrb + h * 64;

#pragma unroll
  for (int part = 0; part < 2; ++part) {
    const int p4 = part ? 31 - pr : pr;
    const int nk = p4 + 1;
    const int iw0 = p4 * 64 + w * 16;
    const int rbase0 = 1984 - 64 * p4;
    int rm = (((1 - p4) % 3) + 3) % 3 * 64;    // rbase0 mod 192
    const __hip_bfloat16* qwp = qw + ((size_t)bh * TSEQ + iw0 + fr) * DHD + fq * 8;
    const bf16x8 qwf0 = ld_bf16x8(qwp), qwf1 = ld_bf16x8(qwp + 32);
    bf16x8 qrf0, qrf1;   // qr reconstructed from bias delta
#pragma unroll
    for (int e = 0; e < 8; ++e) {
      qrf0[e] = (__bf16)((float)qwf0[e] + rrbh[fq * 8 + e] - rwbh[fq * 8 + e]);
      qrf1[e] = (__bf16)((float)qwf1[e] + rrbh[32 + fq * 8 + e] - rwbh[32 + fq * 8 + e]);
    }
    f32x4 o[4] = {};
    float mrow = -INFINITY, lrow = 0.f;

    asm volatile("s_waitcnt lgkmcnt(0)" ::: "memory");  // harden: all LDS ops done
    __builtin_amdgcn_s_barrier();   // protect previous part's reads

    // ---- prologue: K(0),V(0) -> buf0; R rows [rbase0, rbase0+128) ----
    GLL16(Kp + kOff0, kDstB);
    GLL16(Kp + kOff1, kDstB + 1024);
    GLL16(Vp + vOff0, vDstB);
    GLL16(Vp + vOff1, vDstB + 1024);
#pragma unroll
    for (int s = 0; s < 4; ++s) {
      int pb = rm + w * 32 + s * 8;
      if (pb >= 192) pb -= 192;
      int g = rbase0 + w * 32 + s * 8 + l8;
      g = g > 2047 ? 2047 : g;
      GLL16(Rp + g * 128 + swz, RsmC + pb * 128 + (lb << 4));
    }

    int rbase = rbase0;
    int thr = iw0 + fr;
    const char* kTile = Kp + 8192;    // src for K(kt+1)
    const char* vTile = Vp + 128;     // src for V(kt+1)
    for (int kt = 0; kt < nk; ++kt) {
      asm volatile("s_waitcnt vmcnt(0)" ::: "memory");
      __builtin_amdgcn_s_barrier();
      // ---- prefetch tile kt+1 (skip on last) ----
      if (kt + 1 < nk) {
        const int nxtOff = ((kt + 1) & 1) << 13;
        GLL16(kTile + kOff0, kDstB + nxtOff);
        GLL16(kTile + kOff1, kDstB + nxtOff + 1024);
        GLL16(vTile + vOff0, vDstB + nxtOff);
        GLL16(vTile + vOff1, vDstB + nxtOff + 1024);
        const int rm2 = rm >= 64 ? rm - 64 : rm + 128;   // (rbase+128) mod 192
#pragma unroll
        for (int s = 0; s < 2; ++s) {
          int g = rbase + 128 + w * 16 + s * 8 + l8;
          g = g > 2047 ? 2047 : g;
          GLL16(Rp + g * 128 + swz,
                RsmC + (rm2 + w * 16 + s * 8) * 128 + (lb << 4));
        }
        kTile += 8192;
        vTile += 128;
      }
      // ---- S^T from Ksm[cur] (staged last iter; ready) ----
      const int curOff = (kt & 1) << 13;
      const char* kls = (const char*)Ksm + curOff + fr * 128;
      f32x4 st[4];
      __builtin_amdgcn_s_setprio(1);
#pragma unroll
      for (int n = 0; n < 4; ++n) {
        st[n] = __builtin_amdgcn_mfma_f32_16x16x32_bf16(ld_bf16x8(kls + n * 2048 + koff0), qwf0, zero, 0, 0, 0);
        st[n] = __builtin_amdgcn_mfma_f32_16x16x32_bf16(ld_bf16x8(kls + n * 2048 + koff1), qwf1, st[n], 0, 0, 0);
      }
      __builtin_amdgcn_s_setprio(0);
      // ---- band from circular Rsm: D[m][q=fr] -> b128 braw write ----
      const int base_l = rm + 48 - 16 * w + fr;   // <= 191; == fr (mod 8)
      __builtin_amdgcn_s_setprio(1);
#pragma unroll
      for (int pp = 0; pp < 5; ++pp) {
        int rrow = base_l + 16 * pp;
        if (rrow >= 192) rrow -= 192;
        const char* rls = RsmC + rrow * 128;
        f32x4 br = __builtin_amdgcn_mfma_f32_16x16x32_bf16(ld_bf16x8(rls + koff0), qrf0, zero, 0, 0, 0);
        br = __builtin_amdgcn_mfma_f32_16x16x32_bf16(ld_bf16x8(rls + koff1), qrf1, br, 0, 0, 0);
        *reinterpret_cast<f32x4*>(&brawW[fr * 88 + pp * 16 + 4 * fq]) = br;
      }
      __builtin_amdgcn_s_setprio(0);
      // ---- scores + in-register online softmax (q = fr) ----
      const float* brd = &brawW[fr * 88 + 15 - fr];
      float mx = -INFINITY;
#pragma unroll
      for (int n = 0; n < 4; ++n) {
#pragma unroll
        for (int j = 0; j < 4; ++j) {
          const int koff = 16 * n + 4 * fq + j;
          const float s = (koff > thr) ? -INFINITY : (st[n][j] + brd[koff]) * 0.125f;
          st[n][j] = s;
          mx = fmaxf(mx, s);
        }
      }
      mx = fmaxf(mx, __shfl_xor(mx, 16));
      mx = fmaxf(mx, __shfl_xor(mx, 32));
      const float mn = fmaxf(mrow, mx);
      const float al = __expf(mrow - mn);
      mrow = mn;
      float rsum = 0.f;
#pragma unroll
      for (int n = 0; n < 4; ++n)
#pragma unroll
        for (int j = 0; j < 4; ++j) {
          const float pv = __expf(st[n][j] - mn);
          st[n][j] = pv;
          rsum += pv;
        }
      rsum += __shfl_xor(rsum, 16);
      rsum += __shfl_xor(rsum, 32);
      lrow = lrow * al + rsum;
#pragma unroll
      for (int nd = 0; nd < 4; ++nd) o[nd] *= al;
      // ---- P store (overlay; braw fully consumed) ----
#pragma unroll
      for (int n = 0; n < 4; ++n) {
        B4 pk;
        pk.a = __float2bfloat16(st[n][0]);
        pk.b = __float2bfloat16(st[n][1]);
        pk.c = __float2bfloat16(st[n][2]);
        pk.d = __float2bfloat16(st[n][3]);
        *reinterpret_cast<B4*>(&plqW[fr * 72 + 16 * n + 4 * fq]) = pk;
      }
      // ---- O^T += V^T . P^T from Vsm[cur] ----
      const char* vls = (const char*)Vsm + curOff + fr * 128;
      __builtin_amdgcn_s_setprio(1);
#pragma unroll
      for (int c = 0; c < 2; ++c) {
        const bf16x8 pf = ld_bf16x8(&plqW[fr * 72 + 8 * fq + 32 * c]);
#pragma unroll
        for (int nd = 0; nd < 4; ++nd)
          o[nd] = __builtin_amdgcn_mfma_f32_16x16x32_bf16(
              ld_bf16x8(vls + nd * 2048 + (c ? koff1 : koff0)), pf, o[nd], 0, 0, 0);
      }
      __builtin_amdgcn_s_setprio(0);
      // ---- advance ----
      rbase += 64;
      rm = rm >= 128 ? 0 : rm + 64;
      thr -= 64;
    }
    // ---- epilogue: per-lane 1/l, packed 8B stores; row i = iw0+fr ----
    const float linv = 1.f / lrow;
    const int i = iw0 + fr;
#pragma unroll
    for (int nd = 0; nd < 4; ++nd) {
      B4 pack;
      pack.a = __float2bfloat16(o[nd][0] * linv);
      pack.b = __float2bfloat16(o[nd][1] * linv);
      pack.c = __float2bfloat16(o[nd][2] * linv);
      pack.d = __float2bfloat16(o[nd][3] * linv);
      *reinterpret_cast<B4*>(av + ((size_t)i * NB + bb) * DM + h * DHD + 16 * nd + 4 * fq) = pack;
    }
  }
}

extern "C" void kernel_launch(void* const* d_in, const int* in_sizes, int n_in,
                              void* d_out, int out_size, void* d_ws, size_t ws_size,
                              hipStream_t stream) {
  (void)in_sizes; (void)n_in; (void)out_size; (void)ws_size;
  const float* x    = (const float*)d_in[0];
  const float* pos  = (const float*)d_in[1];
  const float* ln_g = (const float*)d_in[2];
  const float* ln_b = (const float*)d_in[3];
  const float* Wqkv = (const float*)d_in[4];
  const float* Wr   = (const float*)d_in[5];
  const float* Wo   = (const float*)d_in[6];
  const float* rwb  = (const float*)d_in[7];
  const float* rrb  = (const float*)d_in[8];
  float* out = (float*)d_out;

  char* ws = (char*)d_ws;
  size_t off = 0;
  auto alloc = [&](size_t n) {
    char* p = ws + off; off += (n + 255) & ~(size_t)255; return p;
  };
  __hip_bfloat16* wqkvT = (__hip_bfloat16*)alloc((size_t)3072 * 1024 * 2);
  __hip_bfloat16* wrT   = (__hip_bfloat16*)alloc((size_t)1024 * 1024 * 2);
  __hip_bfloat16* woT   = (__hip_bfloat16*)alloc((size_t)1024 * 1024 * 2);
  __hip_bfloat16* posb  = (__hip_bfloat16*)alloc((size_t)2048 * 1024 * 2);
  __hip_bfloat16* xn    = (__hip_bfloat16*)alloc((size_t)4096 * 1024 * 2);
  __hip_bfloat16* qwb   = (__hip_bfloat16*)alloc((size_t)NB * NH * TSEQ * DHD * 2);
  __hip_bfloat16* kbb   = (__hip_bfloat16*)alloc((size_t)NB * NH * TSEQ * DHD * 2);
  __hip_bfloat16* vTb   = (__hip_bfloat16*)alloc((size_t)NB * NH * TSEQ * DHD * 2);
  __hip_bfloat16* rTb   = (__hip_bfloat16*)alloc((size_t)NH * TSEQ * DHD * 2);
  __hip_bfloat16* avb   = (__hip_bfloat16*)alloc((size_t)4096 * 1024 * 2);
  (void)alloc(64 * 1024);  // guard region

  k_prep<<<11264, 256, 0, stream>>>(Wqkv, Wr, Wo, wqkvT, wrT, woT,
                                    pos, posb, x, ln_g, ln_b, xn);
  k_gemm01<<<896, 256, 0, stream>>>(xn, wqkvT, posb, wrT,
                                    qwb, kbb, vTb, rwb, rTb);
  k_attn<<<512, 256, 0, stream>>>(qwb, kbb, vTb, rTb, rwb, rrb, avb);
  k_gemm2<<<512, 256, 0, stream>>>(avb, woT, out);
}

// Round 18
// 166.019 us; speedup vs baseline: 1.2520x; 1.0655x over previous
//
#include <hip/hip_runtime.h>
#include <hip/hip_bf16.h>
#include <math.h>

#define TSEQ 2048
#define NB 2
#define DM 1024
#define NH 16
#define DHD 64

typedef __attribute__((ext_vector_type(8))) __bf16 bf16x8;
typedef __attribute__((ext_vector_type(8))) short s16x8;
typedef __attribute__((ext_vector_type(4))) float f32x4;

__device__ __forceinline__ bf16x8 ld_bf16x8(const void* p) {
  s16x8 v = *reinterpret_cast<const s16x8*>(p);
  return __builtin_bit_cast(bf16x8, v);
}

#define GLL16(g, l) __builtin_amdgcn_global_load_lds( \
    (const __attribute__((address_space(1))) void*)(g), \
    (__attribute__((address_space(3))) void*)(l), 16, 0, 0)

// ---------- fused prep: weight transposes + pos cast + LayerNorm ----------
__global__ __launch_bounds__(256) void k_prep(
    const float* __restrict__ Wqkv, const float* __restrict__ Wr,
    const float* __restrict__ Wo, __hip_bfloat16* __restrict__ wqkvT,
    __hip_bfloat16* __restrict__ wrT, __hip_bfloat16* __restrict__ woT,
    const float* __restrict__ pos, __hip_bfloat16* __restrict__ posb,
    const float* __restrict__ x, const float* __restrict__ g,
    const float* __restrict__ b, __hip_bfloat16* __restrict__ xn) {
  __shared__ float t[32][33];
  __shared__ float r1[4], r2[4];
  const int blk = blockIdx.x, tid = threadIdx.x;
  struct B4 { __hip_bfloat16 a, b, c, d; };
  if (blk < 5120) {
    const int tx = tid & 31, ty = tid >> 5;
    const float* in; __hip_bfloat16* out; int C, bx, by;
    if (blk < 3072)      { in = Wqkv; out = wqkvT; C = 3072; bx = blk % 96;  by = blk / 96; }
    else if (blk < 4096) { in = Wr;   out = wrT;   C = 1024; bx = (blk - 3072) % 32; by = (blk - 3072) / 32; }
    else                 { in = Wo;   out = woT;   C = 1024; bx = (blk - 4096) % 32; by = (blk - 4096) / 32; }
    const int c0 = bx * 32, r0 = by * 32;
#pragma unroll
    for (int j = 0; j < 4; ++j)
      t[ty + j * 8][tx] = in[(size_t)(r0 + ty + j * 8) * C + c0 + tx];
    __syncthreads();
#pragma unroll
    for (int j = 0; j < 4; ++j) {
      const int oc = ty + j * 8;
      out[(size_t)(c0 + oc) * 1024 + r0 + tx] = __float2bfloat16(t[tx][oc]);
    }
  } else if (blk < 7168) {
    const int i = ((blk - 5120) * 256 + tid) * 4;
    const float4 v = *reinterpret_cast<const float4*>(pos + i);
    B4 o;
    o.a = __float2bfloat16(v.x); o.b = __float2bfloat16(v.y);
    o.c = __float2bfloat16(v.z); o.d = __float2bfloat16(v.w);
    *reinterpret_cast<B4*>(posb + i) = o;
  } else {
    const int row = blk - 7168;
    const float4 v = reinterpret_cast<const float4*>(x + (size_t)row * DM)[tid];
    float s = v.x + v.y + v.z + v.w;
#pragma unroll
    for (int off = 32; off; off >>= 1) s += __shfl_xor(s, off);
    if ((tid & 63) == 0) r1[tid >> 6] = s;
    __syncthreads();
    const float mu = (r1[0] + r1[1] + r1[2] + r1[3]) * (1.f / DM);
    const float dx = v.x - mu, dy = v.y - mu, dz = v.z - mu, dw = v.w - mu;
    float q = dx * dx + dy * dy + dz * dz + dw * dw;
#pragma unroll
    for (int off = 32; off; off >>= 1) q += __shfl_xor(q, off);
    if ((tid & 63) == 0) r2[tid >> 6] = q;
    __syncthreads();
    const float rs = rsqrtf((r2[0] + r2[1] + r2[2] + r2[3]) * (1.f / DM) + 1e-5f);
    const float4 gv = reinterpret_cast<const float4*>(g)[tid];
    const float4 bv = reinterpret_cast<const float4*>(b)[tid];
    B4 o;
    o.a = __float2bfloat16(dx * rs * gv.x + bv.x);
    o.b = __float2bfloat16(dy * rs * gv.y + bv.y);
    o.c = __float2bfloat16(dz * rs * gv.z + bv.z);
    o.d = __float2bfloat16(dw * rs * gv.w + bv.w);
    reinterpret_cast<B4*>(xn + (size_t)row * DM)[tid] = o;
  }
}

// ---------- merged QKV + R GEMM, split-phase pipelined (R13-style) ----------
// 896 blocks (768 QKV + 128 R), BM=128, BK=64, XOR-swizzled LDS, XCD remap.
// Per K-step: [vmcnt(0)+bar: prefetch landed] -> ds_read all frags to regs ->
// lgkmcnt(0)+sched_barrier+bar (reads drained) -> issue next tile's GLLs into
// SAME buffers -> 32 reg-fed MFMAs run under the GLL flight.
__global__ __launch_bounds__(256) void k_gemm01(
    const __hip_bfloat16* __restrict__ xn, const __hip_bfloat16* __restrict__ wqkvT,
    const __hip_bfloat16* __restrict__ posb, const __hip_bfloat16* __restrict__ wrT,
    __hip_bfloat16* __restrict__ o_qw, __hip_bfloat16* __restrict__ o_k,
    __hip_bfloat16* __restrict__ o_vT, const float* __restrict__ rwb,
    __hip_bfloat16* __restrict__ o_rT) {
  __shared__ __align__(16) __hip_bfloat16 As[128 * 64];
  __shared__ __align__(16) __hip_bfloat16 Bs[128 * 64];
  const int tid = threadIdx.x, lane = tid & 63;
  const int tile = (blockIdx.x & 7) * 112 + (blockIdx.x >> 3);
  const bool q0 = tile < 768;
  const int t0 = q0 ? tile : tile - 768;
  const int ntn = q0 ? 24 : 8;
  const __hip_bfloat16* A  = q0 ? xn : posb;
  const __hip_bfloat16* BT = q0 ? wqkvT : wrT;
  const int K = 1024;
  const int m0 = (t0 / ntn) * 128, n0 = (t0 % ntn) * 128;
  const int wid = tid >> 6;
  const int wr = (wid >> 1) * 64, wc = (wid & 1) * 64;
  const int fr = lane & 15, fq = lane >> 4;
  const int srow8 = tid >> 3;
  const int ssb = ((tid & 7) << 4) ^ ((srow8 & 7) << 4);
  const char* aS = (const char*)(A + (size_t)(m0 + srow8) * K) + ssb;
  const char* bS = (const char*)(BT + (size_t)(n0 + srow8) * K) + ssb;
  char* aD = (char*)As + tid * 16;
  char* bD = (char*)Bs + tid * 16;
  const int rk0 = (fq << 4) ^ ((fr & 7) << 4);
  const int rk1 = ((fq << 4) + 64) ^ ((fr & 7) << 4);
  f32x4 acc[4][4] = {};

  // prologue: stage tile 0 (drained by first iteration's vmcnt+barrier)
#pragma unroll
  for (int gg = 0; gg < 4; ++gg)
    GLL16(aS + (size_t)(gg * 32) * K * 2, aD + gg * 4096);
#pragma unroll
  for (int gg = 0; gg < 4; ++gg)
    GLL16(bS + (size_t)(gg * 32) * K * 2, bD + gg * 4096);

  for (int k0 = 0; k0 < K; k0 += 64) {
    asm volatile("s_waitcnt vmcnt(0)" ::: "memory");   // prefetched tile landed
    __builtin_amdgcn_s_barrier();
    // ---- read phase: all fragments -> regs ----
    bf16x8 af[4][2], bfr[4][2];
#pragma unroll
    for (int mi = 0; mi < 4; ++mi) {
      const char* p = (char*)As + (wr + mi * 16 + fr) * 128;
      af[mi][0] = ld_bf16x8(p + rk0);
      af[mi][1] = ld_bf16x8(p + rk1);
    }
#pragma unroll
    for (int ni = 0; ni < 4; ++ni) {
      const char* p = (char*)Bs + (wc + ni * 16 + fr) * 128;
      bfr[ni][0] = ld_bf16x8(p + rk0);
      bfr[ni][1] = ld_bf16x8(p + rk1);
    }
    asm volatile("s_waitcnt lgkmcnt(0)" ::: "memory");
    __builtin_amdgcn_sched_barrier(0);
    __builtin_amdgcn_s_barrier();   // all waves' LDS reads drained
    // ---- prefetch next tile into the same buffers ----
    if (k0 + 64 < K) {
      const size_t kb = (size_t)(k0 + 64) * 2;
#pragma unroll
      for (int gg = 0; gg < 4; ++gg)
        GLL16(aS + (size_t)(gg * 32) * K * 2 + kb, aD + gg * 4096);
#pragma unroll
      for (int gg = 0; gg < 4; ++gg)
        GLL16(bS + (size_t)(gg * 32) * K * 2 + kb, bD + gg * 4096);
    }
    // ---- compute (reg-fed) under GLL flight ----
    __builtin_amdgcn_s_setprio(1);
#pragma unroll
    for (int mi = 0; mi < 4; ++mi)
#pragma unroll
      for (int ni = 0; ni < 4; ++ni) {
        acc[mi][ni] = __builtin_amdgcn_mfma_f32_16x16x32_bf16(
            af[mi][0], bfr[ni][0], acc[mi][ni], 0, 0, 0);
        acc[mi][ni] = __builtin_amdgcn_mfma_f32_16x16x32_bf16(
            af[mi][1], bfr[ni][1], acc[mi][ni], 0, 0, 0);
      }
    __builtin_amdgcn_s_setprio(0);
  }
#pragma unroll
  for (int mi = 0; mi < 4; ++mi) {
#pragma unroll
    for (int ni = 0; ni < 4; ++ni) {
#pragma unroll
      for (int j = 0; j < 4; ++j) {
        const int r = m0 + wr + mi * 16 + fq * 4 + j;
        const int c = n0 + wc + ni * 16 + fr;
        const float v = acc[mi][ni][j];
        if (q0) {
          const int t = r >> 1, bb = r & 1;
          if (c < 1024) {
            const int h = c >> 6, d = c & 63;
            o_qw[(((size_t)(bb * NH + h)) * TSEQ + t) * DHD + d] = __float2bfloat16(v + rwb[c]);
          } else if (c < 2048) {
            const int e = c - 1024, h = e >> 6, d = e & 63;
            o_k[(((size_t)(bb * NH + h)) * TSEQ + t) * DHD + d] = __float2bfloat16(v);
          } else {
            const int e = c - 2048, h = e >> 6, d = e & 63;
            o_vT[(((size_t)(bb * NH + h)) * DHD + d) * TSEQ + t] = __float2bfloat16(v);
          }
        } else {
          const int h = c >> 6, d = c & 63;
          o_rT[((size_t)h * TSEQ + r) * DHD + d] = __float2bfloat16(v);
        }
      }
    }
  }
}

// ---------- out GEMM: BM=128 x BN=64, 512 blocks (2/CU), fp32 out ----------
__global__ __launch_bounds__(256) void k_gemm2(
    const __hip_bfloat16* __restrict__ A, const __hip_bfloat16* __restrict__ BT,
    float* __restrict__ outF) {
  __shared__ __align__(16) __hip_bfloat16 As[128 * 64];   // 16 KB
  __shared__ __align__(16) __hip_bfloat16 Bs[64 * 64];    // 8 KB
  const int tid = threadIdx.x, lane = tid & 63;
  const int K = 1024, N = 1024, ntn = 16;
  const int tile = (blockIdx.x & 7) * 64 + (blockIdx.x >> 3);   // 512 = 8*64
  const int m0 = (tile / ntn) * 128, n0 = (tile % ntn) * 64;
  const int wid = tid >> 6;
  const int wr = (wid >> 1) * 64, wc = (wid & 1) * 32;
  const int fr = lane & 15, fq = lane >> 4;
  const int srow8 = tid >> 3;
  const int ssb = ((tid & 7) << 4) ^ ((srow8 & 7) << 4);
  const char* aS = (const char*)(A + (size_t)(m0 + srow8) * K) + ssb;
  const char* bS = (const char*)(BT + (size_t)(n0 + srow8) * K) + ssb;
  char* aD = (char*)As + tid * 16;
  char* bD = (char*)Bs + tid * 16;
  const int rk0 = (fq << 4) ^ ((fr & 7) << 4);
  const int rk1 = ((fq << 4) + 64) ^ ((fr & 7) << 4);
  f32x4 acc[4][2] = {};
  for (int k0 = 0; k0 < K; k0 += 64) {
    const size_t kb = (size_t)k0 * 2;
#pragma unroll
    for (int gg = 0; gg < 4; ++gg)
      GLL16(aS + (size_t)(gg * 32) * K * 2 + kb, aD + gg * 4096);
#pragma unroll
    for (int gg = 0; gg < 2; ++gg)
      GLL16(bS + (size_t)(gg * 32) * K * 2 + kb, bD + gg * 4096);
    __syncthreads();
    bf16x8 af[4][2], bfr[2][2];
#pragma unroll
    for (int mi = 0; mi < 4; ++mi) {
      const char* p = (char*)As + (wr + mi * 16 + fr) * 128;
      af[mi][0] = ld_bf16x8(p + rk0);
      af[mi][1] = ld_bf16x8(p + rk1);
    }
#pragma unroll
    for (int ni = 0; ni < 2; ++ni) {
      const char* p = (char*)Bs + (wc + ni * 16 + fr) * 128;
      bfr[ni][0] = ld_bf16x8(p + rk0);
      bfr[ni][1] = ld_bf16x8(p + rk1);
    }
#pragma unroll
    for (int mi = 0; mi < 4; ++mi)
#pragma unroll
      for (int ni = 0; ni < 2; ++ni) {
        acc[mi][ni] = __builtin_amdgcn_mfma_f32_16x16x32_bf16(
            af[mi][0], bfr[ni][0], acc[mi][ni], 0, 0, 0);
        acc[mi][ni] = __builtin_amdgcn_mfma_f32_16x16x32_bf16(
            af[mi][1], bfr[ni][1], acc[mi][ni], 0, 0, 0);
      }
    __syncthreads();
  }
#pragma unroll
  for (int mi = 0; mi < 4; ++mi)
#pragma unroll
    for (int ni = 0; ni < 2; ++ni)
#pragma unroll
      for (int j = 0; j < 4; ++j) {
        const int r = m0 + wr + mi * 16 + fq * 4 + j;
        const int c = n0 + wc + ni * 16 + fr;
        outF[(size_t)r * N + c] = acc[mi][ni][j];
      }
}

// ---------- fused causal rel-attention: R11 structure (best measured) ----------
__global__ __launch_bounds__(256, 2) void k_attn(
    const __hip_bfloat16* __restrict__ qw,
    const __hip_bfloat16* __restrict__ kb, const __hip_bfloat16* __restrict__ vT,
    const __hip_bfloat16* __restrict__ rT,
    const float* __restrict__ rwb, const float* __restrict__ rrb,
    __hip_bfloat16* __restrict__ av) {
  const int tid = threadIdx.x, lane = tid & 63;
  const int w = __builtin_amdgcn_readfirstlane(tid >> 6);
  const int fr = lane & 15, fq = lane >> 4;
  const int l8 = lane >> 3, lb = lane & 7;
  const int bid = blockIdx.x;
  const int xcd = bid & 7, idx = bid >> 3;     // idx 0..63
  const int bh = xcd * 4 + (idx & 3);          // 4 heads per XCD
  const int pr = idx >> 2;                     // pair 0..15
  const int bb = bh >> 4, h = bh & 15;
  const char* Kp = (const char*)(kb + (size_t)bh * TSEQ * DHD);   // row t:128B
  const char* Vp = (const char*)(vT + (size_t)bh * DHD * TSEQ);   // row d:4096B
  const char* Rp = (const char*)(rT + (size_t)h * TSEQ * DHD);    // row t:128B

  __shared__ __align__(16) __hip_bfloat16 Ksm[2][64][64];   // 16 KB
  __shared__ __align__(16) __hip_bfloat16 Vsm[2][64][64];   // 16 KB
  __shared__ __align__(16) __hip_bfloat16 Rsm[192][64];     // 24 KB circular
  __shared__ __align__(16) char scratch[4][5632];           // braw/plq overlay

  const int swz = (lb << 4) ^ (l8 << 4);                 // staging src byte
  const int koff0 = (fq << 4) ^ ((fr & 7) << 4);         // swizzled read c=0
  const int koff1 = ((fq << 4) + 64) ^ ((fr & 7) << 4);  // swizzled read c=1
  const int rowA = w * 16 + l8;                          // K/V stage rows
  const int kOff0 = rowA * 128 + swz, kOff1 = (rowA + 8) * 128 + swz;
  const int vOff0 = rowA * 4096 + swz, vOff1 = (rowA + 8) * 4096 + swz;
  char* kDstB = (char*)Ksm + w * 2048 + lane * 16;   // + buf*8192
  char* vDstB = (char*)Vsm + w * 2048 + lane * 16;
  char* RsmC = (char*)Rsm;
  float* brawW = (float*)scratch[w];                       // [16][88] f32
  __hip_bfloat16* plqW = (__hip_bfloat16*)scratch[w];      // [16][72] bf16 overlay
  const f32x4 zero = {0.f, 0.f, 0.f, 0.f};
  struct B4 { __hip_bfloat16 a, b, c, d; };

  const float* rwbh = rwb + h * 64;
  const float* rrbh = rrb + h * 64;

#pragma unroll
  for (int part = 0; part < 2; ++part) {
    const int p4 = part ? 31 - pr : pr;
    const int nk = p4 + 1;
    const int iw0 = p4 * 64 + w * 16;
    const int rbase0 = 1984 - 64 * p4;
    int rm = (((1 - p4) % 3) + 3) % 3 * 64;    // rbase0 mod 192
    const __hip_bfloat16* qwp = qw + ((size_t)bh * TSEQ + iw0 + fr) * DHD + fq * 8;
    const bf16x8 qwf0 = ld_bf16x8(qwp), qwf1 = ld_bf16x8(qwp + 32);
    bf16x8 qrf0, qrf1;   // qr reconstructed from bias delta
#pragma unroll
    for (int e = 0; e < 8; ++e) {
      qrf0[e] = (__bf16)((float)qwf0[e] + rrbh[fq * 8 + e] - rwbh[fq * 8 + e]);
      qrf1[e] = (__bf16)((float)qwf1[e] + rrbh[32 + fq * 8 + e] - rwbh[32 + fq * 8 + e]);
    }
    f32x4 o[4] = {};
    float mrow = -INFINITY, lrow = 0.f;

    asm volatile("s_waitcnt lgkmcnt(0)" ::: "memory");  // harden: all LDS ops done
    __builtin_amdgcn_s_barrier();   // protect previous part's reads

    // ---- prologue: K(0),V(0) -> buf0; R rows [rbase0, rbase0+128) ----
    GLL16(Kp + kOff0, kDstB);
    GLL16(Kp + kOff1, kDstB + 1024);
    GLL16(Vp + vOff0, vDstB);
    GLL16(Vp + vOff1, vDstB + 1024);
#pragma unroll
    for (int s = 0; s < 4; ++s) {
      int pb = rm + w * 32 + s * 8;
      if (pb >= 192) pb -= 192;
      int g = rbase0 + w * 32 + s * 8 + l8;
      g = g > 2047 ? 2047 : g;
      GLL16(Rp + g * 128 + swz, RsmC + pb * 128 + (lb << 4));
    }

    int rbase = rbase0;
    int thr = iw0 + fr;
    const char* kTile = Kp + 8192;    // src for K(kt+1)
    const char* vTile = Vp + 128;     // src for V(kt+1)
    for (int kt = 0; kt < nk; ++kt) {
      asm volatile("s_waitcnt vmcnt(0)" ::: "memory");
      __builtin_amdgcn_s_barrier();
      // ---- prefetch tile kt+1 (skip on last) ----
      if (kt + 1 < nk) {
        const int nxtOff = ((kt + 1) & 1) << 13;
        GLL16(kTile + kOff0, kDstB + nxtOff);
        GLL16(kTile + kOff1, kDstB + nxtOff + 1024);
        GLL16(vTile + vOff0, vDstB + nxtOff);
        GLL16(vTile + vOff1, vDstB + nxtOff + 1024);
        const int rm2 = rm >= 64 ? rm - 64 : rm + 128;   // (rbase+128) mod 192
#pragma unroll
        for (int s = 0; s < 2; ++s) {
          int g = rbase + 128 + w * 16 + s * 8 + l8;
          g = g > 2047 ? 2047 : g;
          GLL16(Rp + g * 128 + swz,
                RsmC + (rm2 + w * 16 + s * 8) * 128 + (lb << 4));
        }
        kTile += 8192;
        vTile += 128;
      }
      // ---- S^T from Ksm[cur] (staged last iter; ready) ----
      const int curOff = (kt & 1) << 13;
      const char* kls = (const char*)Ksm + curOff + fr * 128;
      f32x4 st[4];
      __builtin_amdgcn_s_setprio(1);
#pragma unroll
      for (int n = 0; n < 4; ++n) {
        st[n] = __builtin_amdgcn_mfma_f32_16x16x32_bf16(ld_bf16x8(kls + n * 2048 + koff0), qwf0, zero, 0, 0, 0);
        st[n] = __builtin_amdgcn_mfma_f32_16x16x32_bf16(ld_bf16x8(kls + n * 2048 + koff1), qwf1, st[n], 0, 0, 0);
      }
      __builtin_amdgcn_s_setprio(0);
      // ---- band from circular Rsm: D[m][q=fr] -> b128 braw write ----
      const int base_l = rm + 48 - 16 * w + fr;   // <= 191; == fr (mod 8)
      __builtin_amdgcn_s_setprio(1);
#pragma unroll
      for (int pp = 0; pp < 5; ++pp) {
        int rrow = base_l + 16 * pp;
        if (rrow >= 192) rrow -= 192;
        const char* rls = RsmC + rrow * 128;
        f32x4 br = __builtin_amdgcn_mfma_f32_16x16x32_bf16(ld_bf16x8(rls + koff0), qrf0, zero, 0, 0, 0);
        br = __builtin_amdgcn_mfma_f32_16x16x32_bf16(ld_bf16x8(rls + koff1), qrf1, br, 0, 0, 0);
        *reinterpret_cast<f32x4*>(&brawW[fr * 88 + pp * 16 + 4 * fq]) = br;
      }
      __builtin_amdgcn_s_setprio(0);
      // ---- scores + in-register online softmax (q = fr) ----
      const float* brd = &brawW[fr * 88 + 15 - fr];
      float mx = -INFINITY;
#pragma unroll
      for (int n = 0; n < 4; ++n) {
#pragma unroll
        for (int j = 0; j < 4; ++j) {
          const int koff = 16 * n + 4 * fq + j;
          const float s = (koff > thr) ? -INFINITY : (st[n][j] + brd[koff]) * 0.125f;
          st[n][j] = s;
          mx = fmaxf(mx, s);
        }
      }
      mx = fmaxf(mx, __shfl_xor(mx, 16));
      mx = fmaxf(mx, __shfl_xor(mx, 32));
      const float mn = fmaxf(mrow, mx);
      const float al = __expf(mrow - mn);
      mrow = mn;
      float rsum = 0.f;
#pragma unroll
      for (int n = 0; n < 4; ++n)
#pragma unroll
        for (int j = 0; j < 4; ++j) {
          const float pv = __expf(st[n][j] - mn);
          st[n][j] = pv;
          rsum += pv;
        }
      rsum += __shfl_xor(rsum, 16);
      rsum += __shfl_xor(rsum, 32);
      lrow = lrow * al + rsum;
#pragma unroll
      for (int nd = 0; nd < 4; ++nd) o[nd] *= al;
      // ---- P store (overlay; braw fully consumed) ----
#pragma unroll
      for (int n = 0; n < 4; ++n) {
        B4 pk;
        pk.a = __float2bfloat16(st[n][0]);
        pk.b = __float2bfloat16(st[n][1]);
        pk.c = __float2bfloat16(st[n][2]);
        pk.d = __float2bfloat16(st[n][3]);
        *reinterpret_cast<B4*>(&plqW[fr * 72 + 16 * n + 4 * fq]) = pk;
      }
      // ---- O^T += V^T . P^T from Vsm[cur] ----
      const char* vls = (const char*)Vsm + curOff + fr * 128;
      __builtin_amdgcn_s_setprio(1);
#pragma unroll
      for (int c = 0; c < 2; ++c) {
        const bf16x8 pf = ld_bf16x8(&plqW[fr * 72 + 8 * fq + 32 * c]);
#pragma unroll
        for (int nd = 0; nd < 4; ++nd)
          o[nd] = __builtin_amdgcn_mfma_f32_16x16x32_bf16(
              ld_bf16x8(vls + nd * 2048 + (c ? koff1 : koff0)), pf, o[nd], 0, 0, 0);
      }
      __builtin_amdgcn_s_setprio(0);
      // ---- advance ----
      rbase += 64;
      rm = rm >= 128 ? 0 : rm + 64;
      thr -= 64;
    }
    // ---- epilogue: per-lane 1/l, packed 8B stores; row i = iw0+fr ----
    const float linv = 1.f / lrow;
    const int i = iw0 + fr;
#pragma unroll
    for (int nd = 0; nd < 4; ++nd) {
      B4 pack;
      pack.a = __float2bfloat16(o[nd][0] * linv);
      pack.b = __float2bfloat16(o[nd][1] * linv);
      pack.c = __float2bfloat16(o[nd][2] * linv);
      pack.d = __float2bfloat16(o[nd][3] * linv);
      *reinterpret_cast<B4*>(av + ((size_t)i * NB + bb) * DM + h * DHD + 16 * nd + 4 * fq) = pack;
    }
  }
}

extern "C" void kernel_launch(void* const* d_in, const int* in_sizes, int n_in,
                              void* d_out, int out_size, void* d_ws, size_t ws_size,
                              hipStream_t stream) {
  (void)in_sizes; (void)n_in; (void)out_size; (void)ws_size;
  const float* x    = (const float*)d_in[0];
  const float* pos  = (const float*)d_in[1];
  const float* ln_g = (const float*)d_in[2];
  const float* ln_b = (const float*)d_in[3];
  const float* Wqkv = (const float*)d_in[4];
  const float* Wr   = (const float*)d_in[5];
  const float* Wo   = (const float*)d_in[6];
  const float* rwb  = (const float*)d_in[7];
  const float* rrb  = (const float*)d_in[8];
  float* out = (float*)d_out;

  char* ws = (char*)d_ws;
  size_t off = 0;
  auto alloc = [&](size_t n) {
    char* p = ws + off; off += (n + 255) & ~(size_t)255; return p;
  };
  __hip_bfloat16* wqkvT = (__hip_bfloat16*)alloc((size_t)3072 * 1024 * 2);
  __hip_bfloat16* wrT   = (__hip_bfloat16*)alloc((size_t)1024 * 1024 * 2);
  __hip_bfloat16* woT   = (__hip_bfloat16*)alloc((size_t)1024 * 1024 * 2);
  __hip_bfloat16* posb  = (__hip_bfloat16*)alloc((size_t)2048 * 1024 * 2);
  __hip_bfloat16* xn    = (__hip_bfloat16*)alloc((size_t)4096 * 1024 * 2);
  __hip_bfloat16* qwb   = (__hip_bfloat16*)alloc((size_t)NB * NH * TSEQ * DHD * 2);
  __hip_bfloat16* kbb   = (__hip_bfloat16*)alloc((size_t)NB * NH * TSEQ * DHD * 2);
  __hip_bfloat16* vTb   = (__hip_bfloat16*)alloc((size_t)NB * NH * TSEQ * DHD * 2);
  __hip_bfloat16* rTb   = (__hip_bfloat16*)alloc((size_t)NH * TSEQ * DHD * 2);
  __hip_bfloat16* avb   = (__hip_bfloat16*)alloc((size_t)4096 * 1024 * 2);
  (void)alloc(64 * 1024);  // guard region

  k_prep<<<11264, 256, 0, stream>>>(Wqkv, Wr, Wo, wqkvT, wrT, woT,
                                    pos, posb, x, ln_g, ln_b, xn);
  k_gemm01<<<896, 256, 0, stream>>>(xn, wqkvT, posb, wrT,
                                    qwb, kbb, vTb, rwb, rTb);
  k_attn<<<512, 256, 0, stream>>>(qwb, kbb, vTb, rTb, rwb, rrb, avb);
  k_gemm2<<<512, 256, 0, stream>>>(avb, woT, out);
}

// Round 19
// 165.332 us; speedup vs baseline: 1.2572x; 1.0042x over previous
//
#include <hip/hip_runtime.h>
#include <hip/hip_bf16.h>
#include <math.h>

#define TSEQ 2048
#define NB 2
#define DM 1024
#define NH 16
#define DHD 64

typedef __attribute__((ext_vector_type(8))) __bf16 bf16x8;
typedef __attribute__((ext_vector_type(8))) short s16x8;
typedef __attribute__((ext_vector_type(4))) float f32x4;

__device__ __forceinline__ bf16x8 ld_bf16x8(const void* p) {
  s16x8 v = *reinterpret_cast<const s16x8*>(p);
  return __builtin_bit_cast(bf16x8, v);
}

#define GLL16(g, l) __builtin_amdgcn_global_load_lds( \
    (const __attribute__((address_space(1))) void*)(g), \
    (__attribute__((address_space(3))) void*)(l), 16, 0, 0)

// ---------- fused prep: weight transposes + pos cast + LayerNorm ----------
__global__ __launch_bounds__(256) void k_prep(
    const float* __restrict__ Wqkv, const float* __restrict__ Wr,
    const float* __restrict__ Wo, __hip_bfloat16* __restrict__ wqkvT,
    __hip_bfloat16* __restrict__ wrT, __hip_bfloat16* __restrict__ woT,
    const float* __restrict__ pos, __hip_bfloat16* __restrict__ posb,
    const float* __restrict__ x, const float* __restrict__ g,
    const float* __restrict__ b, __hip_bfloat16* __restrict__ xn) {
  __shared__ float t[32][33];
  __shared__ float r1[4], r2[4];
  const int blk = blockIdx.x, tid = threadIdx.x;
  struct B4 { __hip_bfloat16 a, b, c, d; };
  if (blk < 5120) {
    const int tx = tid & 31, ty = tid >> 5;
    const float* in; __hip_bfloat16* out; int C, bx, by;
    if (blk < 3072)      { in = Wqkv; out = wqkvT; C = 3072; bx = blk % 96;  by = blk / 96; }
    else if (blk < 4096) { in = Wr;   out = wrT;   C = 1024; bx = (blk - 3072) % 32; by = (blk - 3072) / 32; }
    else                 { in = Wo;   out = woT;   C = 1024; bx = (blk - 4096) % 32; by = (blk - 4096) / 32; }
    const int c0 = bx * 32, r0 = by * 32;
#pragma unroll
    for (int j = 0; j < 4; ++j)
      t[ty + j * 8][tx] = in[(size_t)(r0 + ty + j * 8) * C + c0 + tx];
    __syncthreads();
#pragma unroll
    for (int j = 0; j < 4; ++j) {
      const int oc = ty + j * 8;
      out[(size_t)(c0 + oc) * 1024 + r0 + tx] = __float2bfloat16(t[tx][oc]);
    }
  } else if (blk < 7168) {
    const int i = ((blk - 5120) * 256 + tid) * 4;
    const float4 v = *reinterpret_cast<const float4*>(pos + i);
    B4 o;
    o.a = __float2bfloat16(v.x); o.b = __float2bfloat16(v.y);
    o.c = __float2bfloat16(v.z); o.d = __float2bfloat16(v.w);
    *reinterpret_cast<B4*>(posb + i) = o;
  } else {
    const int row = blk - 7168;
    const float4 v = reinterpret_cast<const float4*>(x + (size_t)row * DM)[tid];
    float s = v.x + v.y + v.z + v.w;
#pragma unroll
    for (int off = 32; off; off >>= 1) s += __shfl_xor(s, off);
    if ((tid & 63) == 0) r1[tid >> 6] = s;
    __syncthreads();
    const float mu = (r1[0] + r1[1] + r1[2] + r1[3]) * (1.f / DM);
    const float dx = v.x - mu, dy = v.y - mu, dz = v.z - mu, dw = v.w - mu;
    float q = dx * dx + dy * dy + dz * dz + dw * dw;
#pragma unroll
    for (int off = 32; off; off >>= 1) q += __shfl_xor(q, off);
    if ((tid & 63) == 0) r2[tid >> 6] = q;
    __syncthreads();
    const float rs = rsqrtf((r2[0] + r2[1] + r2[2] + r2[3]) * (1.f / DM) + 1e-5f);
    const float4 gv = reinterpret_cast<const float4*>(g)[tid];
    const float4 bv = reinterpret_cast<const float4*>(b)[tid];
    B4 o;
    o.a = __float2bfloat16(dx * rs * gv.x + bv.x);
    o.b = __float2bfloat16(dy * rs * gv.y + bv.y);
    o.c = __float2bfloat16(dz * rs * gv.z + bv.z);
    o.d = __float2bfloat16(dw * rs * gv.w + bv.w);
    reinterpret_cast<B4*>(xn + (size_t)row * DM)[tid] = o;
  }
}

// ---------- merged QKV + R GEMM, split-phase pipelined (R18-proven) ----------
__global__ __launch_bounds__(256) void k_gemm01(
    const __hip_bfloat16* __restrict__ xn, const __hip_bfloat16* __restrict__ wqkvT,
    const __hip_bfloat16* __restrict__ posb, const __hip_bfloat16* __restrict__ wrT,
    __hip_bfloat16* __restrict__ o_qw, __hip_bfloat16* __restrict__ o_k,
    __hip_bfloat16* __restrict__ o_vT, const float* __restrict__ rwb,
    __hip_bfloat16* __restrict__ o_rT) {
  __shared__ __align__(16) __hip_bfloat16 As[128 * 64];
  __shared__ __align__(16) __hip_bfloat16 Bs[128 * 64];
  const int tid = threadIdx.x, lane = tid & 63;
  const int tile = (blockIdx.x & 7) * 112 + (blockIdx.x >> 3);
  const bool q0 = tile < 768;
  const int t0 = q0 ? tile : tile - 768;
  const int ntn = q0 ? 24 : 8;
  const __hip_bfloat16* A  = q0 ? xn : posb;
  const __hip_bfloat16* BT = q0 ? wqkvT : wrT;
  const int K = 1024;
  const int m0 = (t0 / ntn) * 128, n0 = (t0 % ntn) * 128;
  const int wid = tid >> 6;
  const int wr = (wid >> 1) * 64, wc = (wid & 1) * 64;
  const int fr = lane & 15, fq = lane >> 4;
  const int srow8 = tid >> 3;
  const int ssb = ((tid & 7) << 4) ^ ((srow8 & 7) << 4);
  const char* aS = (const char*)(A + (size_t)(m0 + srow8) * K) + ssb;
  const char* bS = (const char*)(BT + (size_t)(n0 + srow8) * K) + ssb;
  char* aD = (char*)As + tid * 16;
  char* bD = (char*)Bs + tid * 16;
  const int rk0 = (fq << 4) ^ ((fr & 7) << 4);
  const int rk1 = ((fq << 4) + 64) ^ ((fr & 7) << 4);
  f32x4 acc[4][4] = {};

  // prologue: stage tile 0
#pragma unroll
  for (int gg = 0; gg < 4; ++gg)
    GLL16(aS + (size_t)(gg * 32) * K * 2, aD + gg * 4096);
#pragma unroll
  for (int gg = 0; gg < 4; ++gg)
    GLL16(bS + (size_t)(gg * 32) * K * 2, bD + gg * 4096);

  for (int k0 = 0; k0 < K; k0 += 64) {
    asm volatile("s_waitcnt vmcnt(0)" ::: "memory");   // prefetched tile landed
    __builtin_amdgcn_s_barrier();
    // ---- read phase: all fragments -> regs ----
    bf16x8 af[4][2], bfr[4][2];
#pragma unroll
    for (int mi = 0; mi < 4; ++mi) {
      const char* p = (char*)As + (wr + mi * 16 + fr) * 128;
      af[mi][0] = ld_bf16x8(p + rk0);
      af[mi][1] = ld_bf16x8(p + rk1);
    }
#pragma unroll
    for (int ni = 0; ni < 4; ++ni) {
      const char* p = (char*)Bs + (wc + ni * 16 + fr) * 128;
      bfr[ni][0] = ld_bf16x8(p + rk0);
      bfr[ni][1] = ld_bf16x8(p + rk1);
    }
    asm volatile("s_waitcnt lgkmcnt(0)" ::: "memory");
    __builtin_amdgcn_sched_barrier(0);
    __builtin_amdgcn_s_barrier();   // all waves' LDS reads drained
    // ---- prefetch next tile into the same buffers ----
    if (k0 + 64 < K) {
      const size_t kb = (size_t)(k0 + 64) * 2;
#pragma unroll
      for (int gg = 0; gg < 4; ++gg)
        GLL16(aS + (size_t)(gg * 32) * K * 2 + kb, aD + gg * 4096);
#pragma unroll
      for (int gg = 0; gg < 4; ++gg)
        GLL16(bS + (size_t)(gg * 32) * K * 2 + kb, bD + gg * 4096);
    }
    // ---- compute (reg-fed) under GLL flight ----
    __builtin_amdgcn_s_setprio(1);
#pragma unroll
    for (int mi = 0; mi < 4; ++mi)
#pragma unroll
      for (int ni = 0; ni < 4; ++ni) {
        acc[mi][ni] = __builtin_amdgcn_mfma_f32_16x16x32_bf16(
            af[mi][0], bfr[ni][0], acc[mi][ni], 0, 0, 0);
        acc[mi][ni] = __builtin_amdgcn_mfma_f32_16x16x32_bf16(
            af[mi][1], bfr[ni][1], acc[mi][ni], 0, 0, 0);
      }
    __builtin_amdgcn_s_setprio(0);
  }
#pragma unroll
  for (int mi = 0; mi < 4; ++mi) {
#pragma unroll
    for (int ni = 0; ni < 4; ++ni) {
#pragma unroll
      for (int j = 0; j < 4; ++j) {
        const int r = m0 + wr + mi * 16 + fq * 4 + j;
        const int c = n0 + wc + ni * 16 + fr;
        const float v = acc[mi][ni][j];
        if (q0) {
          const int t = r >> 1, bb = r & 1;
          if (c < 1024) {
            const int h = c >> 6, d = c & 63;
            o_qw[(((size_t)(bb * NH + h)) * TSEQ + t) * DHD + d] = __float2bfloat16(v + rwb[c]);
          } else if (c < 2048) {
            const int e = c - 1024, h = e >> 6, d = e & 63;
            o_k[(((size_t)(bb * NH + h)) * TSEQ + t) * DHD + d] = __float2bfloat16(v);
          } else {
            const int e = c - 2048, h = e >> 6, d = e & 63;
            o_vT[(((size_t)(bb * NH + h)) * DHD + d) * TSEQ + t] = __float2bfloat16(v);
          }
        } else {
          const int h = c >> 6, d = c & 63;
          o_rT[((size_t)h * TSEQ + r) * DHD + d] = __float2bfloat16(v);
        }
      }
    }
  }
}

// ---------- out GEMM: BM=128 x BN=64, 512 blocks, split-phase pipelined ----------
// Identical geometry to R17-proven kernel; loop restructured with the
// R18-proven split-phase transform (read->regs, bar, prefetch same buffers).
__global__ __launch_bounds__(256) void k_gemm2(
    const __hip_bfloat16* __restrict__ A, const __hip_bfloat16* __restrict__ BT,
    float* __restrict__ outF) {
  __shared__ __align__(16) __hip_bfloat16 As[128 * 64];   // 16 KB
  __shared__ __align__(16) __hip_bfloat16 Bs[64 * 64];    // 8 KB
  const int tid = threadIdx.x, lane = tid & 63;
  const int K = 1024, N = 1024, ntn = 16;
  const int tile = (blockIdx.x & 7) * 64 + (blockIdx.x >> 3);   // 512 = 8*64
  const int m0 = (tile / ntn) * 128, n0 = (tile % ntn) * 64;
  const int wid = tid >> 6;
  const int wr = (wid >> 1) * 64, wc = (wid & 1) * 32;
  const int fr = lane & 15, fq = lane >> 4;
  const int srow8 = tid >> 3;
  const int ssb = ((tid & 7) << 4) ^ ((srow8 & 7) << 4);
  const char* aS = (const char*)(A + (size_t)(m0 + srow8) * K) + ssb;
  const char* bS = (const char*)(BT + (size_t)(n0 + srow8) * K) + ssb;
  char* aD = (char*)As + tid * 16;
  char* bD = (char*)Bs + tid * 16;
  const int rk0 = (fq << 4) ^ ((fr & 7) << 4);
  const int rk1 = ((fq << 4) + 64) ^ ((fr & 7) << 4);
  f32x4 acc[4][2] = {};

  // prologue: stage tile 0
#pragma unroll
  for (int gg = 0; gg < 4; ++gg)
    GLL16(aS + (size_t)(gg * 32) * K * 2, aD + gg * 4096);
#pragma unroll
  for (int gg = 0; gg < 2; ++gg)
    GLL16(bS + (size_t)(gg * 32) * K * 2, bD + gg * 4096);

  for (int k0 = 0; k0 < K; k0 += 64) {
    asm volatile("s_waitcnt vmcnt(0)" ::: "memory");
    __builtin_amdgcn_s_barrier();
    // ---- read phase ----
    bf16x8 af[4][2], bfr[2][2];
#pragma unroll
    for (int mi = 0; mi < 4; ++mi) {
      const char* p = (char*)As + (wr + mi * 16 + fr) * 128;
      af[mi][0] = ld_bf16x8(p + rk0);
      af[mi][1] = ld_bf16x8(p + rk1);
    }
#pragma unroll
    for (int ni = 0; ni < 2; ++ni) {
      const char* p = (char*)Bs + (wc + ni * 16 + fr) * 128;
      bfr[ni][0] = ld_bf16x8(p + rk0);
      bfr[ni][1] = ld_bf16x8(p + rk1);
    }
    asm volatile("s_waitcnt lgkmcnt(0)" ::: "memory");
    __builtin_amdgcn_sched_barrier(0);
    __builtin_amdgcn_s_barrier();
    // ---- prefetch next tile ----
    if (k0 + 64 < K) {
      const size_t kb = (size_t)(k0 + 64) * 2;
#pragma unroll
      for (int gg = 0; gg < 4; ++gg)
        GLL16(aS + (size_t)(gg * 32) * K * 2 + kb, aD + gg * 4096);
#pragma unroll
      for (int gg = 0; gg < 2; ++gg)
        GLL16(bS + (size_t)(gg * 32) * K * 2 + kb, bD + gg * 4096);
    }
    // ---- compute ----
    __builtin_amdgcn_s_setprio(1);
#pragma unroll
    for (int mi = 0; mi < 4; ++mi)
#pragma unroll
      for (int ni = 0; ni < 2; ++ni) {
        acc[mi][ni] = __builtin_amdgcn_mfma_f32_16x16x32_bf16(
            af[mi][0], bfr[ni][0], acc[mi][ni], 0, 0, 0);
        acc[mi][ni] = __builtin_amdgcn_mfma_f32_16x16x32_bf16(
            af[mi][1], bfr[ni][1], acc[mi][ni], 0, 0, 0);
      }
    __builtin_amdgcn_s_setprio(0);
  }
#pragma unroll
  for (int mi = 0; mi < 4; ++mi)
#pragma unroll
    for (int ni = 0; ni < 2; ++ni)
#pragma unroll
      for (int j = 0; j < 4; ++j) {
        const int r = m0 + wr + mi * 16 + fq * 4 + j;
        const int c = n0 + wc + ni * 16 + fr;
        outF[(size_t)r * N + c] = acc[mi][ni][j];
      }
}

// ---------- fused causal rel-attention: R11 structure (best measured) ----------
__global__ __launch_bounds__(256, 2) void k_attn(
    const __hip_bfloat16* __restrict__ qw,
    const __hip_bfloat16* __restrict__ kb, const __hip_bfloat16* __restrict__ vT,
    const __hip_bfloat16* __restrict__ rT,
    const float* __restrict__ rwb, const float* __restrict__ rrb,
    __hip_bfloat16* __restrict__ av) {
  const int tid = threadIdx.x, lane = tid & 63;
  const int w = __builtin_amdgcn_readfirstlane(tid >> 6);
  const int fr = lane & 15, fq = lane >> 4;
  const int l8 = lane >> 3, lb = lane & 7;
  const int bid = blockIdx.x;
  const int xcd = bid & 7, idx = bid >> 3;     // idx 0..63
  const int bh = xcd * 4 + (idx & 3);          // 4 heads per XCD
  const int pr = idx >> 2;                     // pair 0..15
  const int bb = bh >> 4, h = bh & 15;
  const char* Kp = (const char*)(kb + (size_t)bh * TSEQ * DHD);   // row t:128B
  const char* Vp = (const char*)(vT + (size_t)bh * DHD * TSEQ);   // row d:4096B
  const char* Rp = (const char*)(rT + (size_t)h * TSEQ * DHD);    // row t:128B

  __shared__ __align__(16) __hip_bfloat16 Ksm[2][64][64];   // 16 KB
  __shared__ __align__(16) __hip_bfloat16 Vsm[2][64][64];   // 16 KB
  __shared__ __align__(16) __hip_bfloat16 Rsm[192][64];     // 24 KB circular
  __shared__ __align__(16) char scratch[4][5632];           // braw/plq overlay

  const int swz = (lb << 4) ^ (l8 << 4);                 // staging src byte
  const int koff0 = (fq << 4) ^ ((fr & 7) << 4);         // swizzled read c=0
  const int koff1 = ((fq << 4) + 64) ^ ((fr & 7) << 4);  // swizzled read c=1
  const int rowA = w * 16 + l8;                          // K/V stage rows
  const int kOff0 = rowA * 128 + swz, kOff1 = (rowA + 8) * 128 + swz;
  const int vOff0 = rowA * 4096 + swz, vOff1 = (rowA + 8) * 4096 + swz;
  char* kDstB = (char*)Ksm + w * 2048 + lane * 16;   // + buf*8192
  char* vDstB = (char*)Vsm + w * 2048 + lane * 16;
  char* RsmC = (char*)Rsm;
  float* brawW = (float*)scratch[w];                       // [16][88] f32
  __hip_bfloat16* plqW = (__hip_bfloat16*)scratch[w];      // [16][72] bf16 overlay
  const f32x4 zero = {0.f, 0.f, 0.f, 0.f};
  struct B4 { __hip_bfloat16 a, b, c, d; };

  const float* rwbh = rwb + h * 64;
  const float* rrbh = rrb + h * 64;

#pragma unroll
  for (int part = 0; part < 2; ++part) {
    const int p4 = part ? 31 - pr : pr;
    const int nk = p4 + 1;
    const int iw0 = p4 * 64 + w * 16;
    const int rbase0 = 1984 - 64 * p4;
    int rm = (((1 - p4) % 3) + 3) % 3 * 64;    // rbase0 mod 192
    const __hip_bfloat16* qwp = qw + ((size_t)bh * TSEQ + iw0 + fr) * DHD + fq * 8;
    const bf16x8 qwf0 = ld_bf16x8(qwp), qwf1 = ld_bf16x8(qwp + 32);
    bf16x8 qrf0, qrf1;   // qr reconstructed from bias delta
#pragma unroll
    for (int e = 0; e < 8; ++e) {
      qrf0[e] = (__bf16)((float)qwf0[e] + rrbh[fq * 8 + e] - rwbh[fq * 8 + e]);
      qrf1[e] = (__bf16)((float)qwf1[e] + rrbh[32 + fq * 8 + e] - rwbh[32 + fq * 8 + e]);
    }
    f32x4 o[4] = {};
    float mrow = -INFINITY, lrow = 0.f;

    asm volatile("s_waitcnt lgkmcnt(0)" ::: "memory");  // harden: all LDS ops done
    __builtin_amdgcn_s_barrier();   // protect previous part's reads

    // ---- prologue: K(0),V(0) -> buf0; R rows [rbase0, rbase0+128) ----
    GLL16(Kp + kOff0, kDstB);
    GLL16(Kp + kOff1, kDstB + 1024);
    GLL16(Vp + vOff0, vDstB);
    GLL16(Vp + vOff1, vDstB + 1024);
#pragma unroll
    for (int s = 0; s < 4; ++s) {
      int pb = rm + w * 32 + s * 8;
      if (pb >= 192) pb -= 192;
      int g = rbase0 + w * 32 + s * 8 + l8;
      g = g > 2047 ? 2047 : g;
      GLL16(Rp + g * 128 + swz, RsmC + pb * 128 + (lb << 4));
    }

    int rbase = rbase0;
    int thr = iw0 + fr;
    const char* kTile = Kp + 8192;    // src for K(kt+1)
    const char* vTile = Vp + 128;     // src for V(kt+1)
    for (int kt = 0; kt < nk; ++kt) {
      asm volatile("s_waitcnt vmcnt(0)" ::: "memory");
      __builtin_amdgcn_s_barrier();
      // ---- prefetch tile kt+1 (skip on last) ----
      if (kt + 1 < nk) {
        const int nxtOff = ((kt + 1) & 1) << 13;
        GLL16(kTile + kOff0, kDstB + nxtOff);
        GLL16(kTile + kOff1, kDstB + nxtOff + 1024);
        GLL16(vTile + vOff0, vDstB + nxtOff);
        GLL16(vTile + vOff1, vDstB + nxtOff + 1024);
        const int rm2 = rm >= 64 ? rm - 64 : rm + 128;   // (rbase+128) mod 192
#pragma unroll
        for (int s = 0; s < 2; ++s) {
          int g = rbase + 128 + w * 16 + s * 8 + l8;
          g = g > 2047 ? 2047 : g;
          GLL16(Rp + g * 128 + swz,
                RsmC + (rm2 + w * 16 + s * 8) * 128 + (lb << 4));
        }
        kTile += 8192;
        vTile += 128;
      }
      // ---- S^T from Ksm[cur] (staged last iter; ready) ----
      const int curOff = (kt & 1) << 13;
      const char* kls = (const char*)Ksm + curOff + fr * 128;
      f32x4 st[4];
      __builtin_amdgcn_s_setprio(1);
#pragma unroll
      for (int n = 0; n < 4; ++n) {
        st[n] = __builtin_amdgcn_mfma_f32_16x16x32_bf16(ld_bf16x8(kls + n * 2048 + koff0), qwf0, zero, 0, 0, 0);
        st[n] = __builtin_amdgcn_mfma_f32_16x16x32_bf16(ld_bf16x8(kls + n * 2048 + koff1), qwf1, st[n], 0, 0, 0);
      }
      __builtin_amdgcn_s_setprio(0);
      // ---- band from circular Rsm: D[m][q=fr] -> b128 braw write ----
      const int base_l = rm + 48 - 16 * w + fr;   // <= 191; == fr (mod 8)
      __builtin_amdgcn_s_setprio(1);
#pragma unroll
      for (int pp = 0; pp < 5; ++pp) {
        int rrow = base_l + 16 * pp;
        if (rrow >= 192) rrow -= 192;
        const char* rls = RsmC + rrow * 128;
        f32x4 br = __builtin_amdgcn_mfma_f32_16x16x32_bf16(ld_bf16x8(rls + koff0), qrf0, zero, 0, 0, 0);
        br = __builtin_amdgcn_mfma_f32_16x16x32_bf16(ld_bf16x8(rls + koff1), qrf1, br, 0, 0, 0);
        *reinterpret_cast<f32x4*>(&brawW[fr * 88 + pp * 16 + 4 * fq]) = br;
      }
      __builtin_amdgcn_s_setprio(0);
      // ---- scores + in-register online softmax (q = fr) ----
      const float* brd = &brawW[fr * 88 + 15 - fr];
      float mx = -INFINITY;
#pragma unroll
      for (int n = 0; n < 4; ++n) {
#pragma unroll
        for (int j = 0; j < 4; ++j) {
          const int koff = 16 * n + 4 * fq + j;
          const float s = (koff > thr) ? -INFINITY : (st[n][j] + brd[koff]) * 0.125f;
          st[n][j] = s;
          mx = fmaxf(mx, s);
        }
      }
      mx = fmaxf(mx, __shfl_xor(mx, 16));
      mx = fmaxf(mx, __shfl_xor(mx, 32));
      const float mn = fmaxf(mrow, mx);
      const float al = __expf(mrow - mn);
      mrow = mn;
      float rsum = 0.f;
#pragma unroll
      for (int n = 0; n < 4; ++n)
#pragma unroll
        for (int j = 0; j < 4; ++j) {
          const float pv = __expf(st[n][j] - mn);
          st[n][j] = pv;
          rsum += pv;
        }
      rsum += __shfl_xor(rsum, 16);
      rsum += __shfl_xor(rsum, 32);
      lrow = lrow * al + rsum;
#pragma unroll
      for (int nd = 0; nd < 4; ++nd) o[nd] *= al;
      // ---- P store (overlay; braw fully consumed) ----
#pragma unroll
      for (int n = 0; n < 4; ++n) {
        B4 pk;
        pk.a = __float2bfloat16(st[n][0]);
        pk.b = __float2bfloat16(st[n][1]);
        pk.c = __float2bfloat16(st[n][2]);
        pk.d = __float2bfloat16(st[n][3]);
        *reinterpret_cast<B4*>(&plqW[fr * 72 + 16 * n + 4 * fq]) = pk;
      }
      // ---- O^T += V^T . P^T from Vsm[cur] ----
      const char* vls = (const char*)Vsm + curOff + fr * 128;
      __builtin_amdgcn_s_setprio(1);
#pragma unroll
      for (int c = 0; c < 2; ++c) {
        const bf16x8 pf = ld_bf16x8(&plqW[fr * 72 + 8 * fq + 32 * c]);
#pragma unroll
        for (int nd = 0; nd < 4; ++nd)
          o[nd] = __builtin_amdgcn_mfma_f32_16x16x32_bf16(
              ld_bf16x8(vls + nd * 2048 + (c ? koff1 : koff0)), pf, o[nd], 0, 0, 0);
      }
      __builtin_amdgcn_s_setprio(0);
      // ---- advance ----
      rbase += 64;
      rm = rm >= 128 ? 0 : rm + 64;
      thr -= 64;
    }
    // ---- epilogue: per-lane 1/l, packed 8B stores; row i = iw0+fr ----
    const float linv = 1.f / lrow;
    const int i = iw0 + fr;
#pragma unroll
    for (int nd = 0; nd < 4; ++nd) {
      B4 pack;
      pack.a = __float2bfloat16(o[nd][0] * linv);
      pack.b = __float2bfloat16(o[nd][1] * linv);
      pack.c = __float2bfloat16(o[nd][2] * linv);
      pack.d = __float2bfloat16(o[nd][3] * linv);
      *reinterpret_cast<B4*>(av + ((size_t)i * NB + bb) * DM + h * DHD + 16 * nd + 4 * fq) = pack;
    }
  }
}

extern "C" void kernel_launch(void* const* d_in, const int* in_sizes, int n_in,
                              void* d_out, int out_size, void* d_ws, size_t ws_size,
                              hipStream_t stream) {
  (void)in_sizes; (void)n_in; (void)out_size; (void)ws_size;
  const float* x    = (const float*)d_in[0];
  const float* pos  = (const float*)d_in[1];
  const float* ln_g = (const float*)d_in[2];
  const float* ln_b = (const float*)d_in[3];
  const float* Wqkv = (const float*)d_in[4];
  const float* Wr   = (const float*)d_in[5];
  const float* Wo   = (const float*)d_in[6];
  const float* rwb  = (const float*)d_in[7];
  const float* rrb  = (const float*)d_in[8];
  float* out = (float*)d_out;

  char* ws = (char*)d_ws;
  size_t off = 0;
  auto alloc = [&](size_t n) {
    char* p = ws + off; off += (n + 255) & ~(size_t)255; return p;
  };
  __hip_bfloat16* wqkvT = (__hip_bfloat16*)alloc((size_t)3072 * 1024 * 2);
  __hip_bfloat16* wrT   = (__hip_bfloat16*)alloc((size_t)1024 * 1024 * 2);
  __hip_bfloat16* woT   = (__hip_bfloat16*)alloc((size_t)1024 * 1024 * 2);
  __hip_bfloat16* posb  = (__hip_bfloat16*)alloc((size_t)2048 * 1024 * 2);
  __hip_bfloat16* xn    = (__hip_bfloat16*)alloc((size_t)4096 * 1024 * 2);
  __hip_bfloat16* qwb   = (__hip_bfloat16*)alloc((size_t)NB * NH * TSEQ * DHD * 2);
  __hip_bfloat16* kbb   = (__hip_bfloat16*)alloc((size_t)NB * NH * TSEQ * DHD * 2);
  __hip_bfloat16* vTb   = (__hip_bfloat16*)alloc((size_t)NB * NH * TSEQ * DHD * 2);
  __hip_bfloat16* rTb   = (__hip_bfloat16*)alloc((size_t)NH * TSEQ * DHD * 2);
  __hip_bfloat16* avb   = (__hip_bfloat16*)alloc((size_t)4096 * 1024 * 2);
  (void)alloc(64 * 1024);  // guard region

  k_prep<<<11264, 256, 0, stream>>>(Wqkv, Wr, Wo, wqkvT, wrT, woT,
                                    pos, posb, x, ln_g, ln_b, xn);
  k_gemm01<<<896, 256, 0, stream>>>(xn, wqkvT, posb, wrT,
                                    qwb, kbb, vTb, rwb, rTb);
  k_attn<<<512, 256, 0, stream>>>(qwb, kbb, vTb, rTb, rwb, rrb, avb);
  k_gemm2<<<512, 256, 0, stream>>>(avb, woT, out);
}

// Round 20
// 162.762 us; speedup vs baseline: 1.2770x; 1.0158x over previous
//
#include <hip/hip_runtime.h>
#include <hip/hip_bf16.h>
#include <math.h>

#define TSEQ 2048
#define NB 2
#define DM 1024
#define NH 16
#define DHD 64

typedef __attribute__((ext_vector_type(8))) __bf16 bf16x8;
typedef __attribute__((ext_vector_type(8))) short s16x8;
typedef __attribute__((ext_vector_type(4))) float f32x4;

__device__ __forceinline__ bf16x8 ld_bf16x8(const void* p) {
  s16x8 v = *reinterpret_cast<const s16x8*>(p);
  return __builtin_bit_cast(bf16x8, v);
}

#define GLL16(g, l) __builtin_amdgcn_global_load_lds( \
    (const __attribute__((address_space(1))) void*)(g), \
    (__attribute__((address_space(3))) void*)(l), 16, 0, 0)

// ---------- fused prep: weight transposes + pos cast + LayerNorm ----------
__global__ __launch_bounds__(256) void k_prep(
    const float* __restrict__ Wqkv, const float* __restrict__ Wr,
    const float* __restrict__ Wo, __hip_bfloat16* __restrict__ wqkvT,
    __hip_bfloat16* __restrict__ wrT, __hip_bfloat16* __restrict__ woT,
    const float* __restrict__ pos, __hip_bfloat16* __restrict__ posb,
    const float* __restrict__ x, const float* __restrict__ g,
    const float* __restrict__ b, __hip_bfloat16* __restrict__ xn) {
  __shared__ float t[32][33];
  __shared__ float r1[4], r2[4];
  const int blk = blockIdx.x, tid = threadIdx.x;
  struct B4 { __hip_bfloat16 a, b, c, d; };
  if (blk < 5120) {
    const int tx = tid & 31, ty = tid >> 5;
    const float* in; __hip_bfloat16* out; int C, bx, by;
    if (blk < 3072)      { in = Wqkv; out = wqkvT; C = 3072; bx = blk % 96;  by = blk / 96; }
    else if (blk < 4096) { in = Wr;   out = wrT;   C = 1024; bx = (blk - 3072) % 32; by = (blk - 3072) / 32; }
    else                 { in = Wo;   out = woT;   C = 1024; bx = (blk - 4096) % 32; by = (blk - 4096) / 32; }
    const int c0 = bx * 32, r0 = by * 32;
#pragma unroll
    for (int j = 0; j < 4; ++j)
      t[ty + j * 8][tx] = in[(size_t)(r0 + ty + j * 8) * C + c0 + tx];
    __syncthreads();
#pragma unroll
    for (int j = 0; j < 4; ++j) {
      const int oc = ty + j * 8;
      out[(size_t)(c0 + oc) * 1024 + r0 + tx] = __float2bfloat16(t[tx][oc]);
    }
  } else if (blk < 7168) {
    const int i = ((blk - 5120) * 256 + tid) * 4;
    const float4 v = *reinterpret_cast<const float4*>(pos + i);
    B4 o;
    o.a = __float2bfloat16(v.x); o.b = __float2bfloat16(v.y);
    o.c = __float2bfloat16(v.z); o.d = __float2bfloat16(v.w);
    *reinterpret_cast<B4*>(posb + i) = o;
  } else {
    const int row = blk - 7168;
    const float4 v = reinterpret_cast<const float4*>(x + (size_t)row * DM)[tid];
    float s = v.x + v.y + v.z + v.w;
#pragma unroll
    for (int off = 32; off; off >>= 1) s += __shfl_xor(s, off);
    if ((tid & 63) == 0) r1[tid >> 6] = s;
    __syncthreads();
    const float mu = (r1[0] + r1[1] + r1[2] + r1[3]) * (1.f / DM);
    const float dx = v.x - mu, dy = v.y - mu, dz = v.z - mu, dw = v.w - mu;
    float q = dx * dx + dy * dy + dz * dz + dw * dw;
#pragma unroll
    for (int off = 32; off; off >>= 1) q += __shfl_xor(q, off);
    if ((tid & 63) == 0) r2[tid >> 6] = q;
    __syncthreads();
    const float rs = rsqrtf((r2[0] + r2[1] + r2[2] + r2[3]) * (1.f / DM) + 1e-5f);
    const float4 gv = reinterpret_cast<const float4*>(g)[tid];
    const float4 bv = reinterpret_cast<const float4*>(b)[tid];
    B4 o;
    o.a = __float2bfloat16(dx * rs * gv.x + bv.x);
    o.b = __float2bfloat16(dy * rs * gv.y + bv.y);
    o.c = __float2bfloat16(dz * rs * gv.z + bv.z);
    o.d = __float2bfloat16(dw * rs * gv.w + bv.w);
    reinterpret_cast<B4*>(xn + (size_t)row * DM)[tid] = o;
  }
}

// ---------- merged QKV + R GEMM, split-phase pipelined (R18-proven) ----------
__global__ __launch_bounds__(256) void k_gemm01(
    const __hip_bfloat16* __restrict__ xn, const __hip_bfloat16* __restrict__ wqkvT,
    const __hip_bfloat16* __restrict__ posb, const __hip_bfloat16* __restrict__ wrT,
    __hip_bfloat16* __restrict__ o_qw, __hip_bfloat16* __restrict__ o_k,
    __hip_bfloat16* __restrict__ o_vT, const float* __restrict__ rwb,
    __hip_bfloat16* __restrict__ o_rT) {
  __shared__ __align__(16) __hip_bfloat16 As[128 * 64];
  __shared__ __align__(16) __hip_bfloat16 Bs[128 * 64];
  const int tid = threadIdx.x, lane = tid & 63;
  const int tile = (blockIdx.x & 7) * 112 + (blockIdx.x >> 3);
  const bool q0 = tile < 768;
  const int t0 = q0 ? tile : tile - 768;
  const int ntn = q0 ? 24 : 8;
  const __hip_bfloat16* A  = q0 ? xn : posb;
  const __hip_bfloat16* BT = q0 ? wqkvT : wrT;
  const int K = 1024;
  const int m0 = (t0 / ntn) * 128, n0 = (t0 % ntn) * 128;
  const int wid = tid >> 6;
  const int wr = (wid >> 1) * 64, wc = (wid & 1) * 64;
  const int fr = lane & 15, fq = lane >> 4;
  const int srow8 = tid >> 3;
  const int ssb = ((tid & 7) << 4) ^ ((srow8 & 7) << 4);
  const char* aS = (const char*)(A + (size_t)(m0 + srow8) * K) + ssb;
  const char* bS = (const char*)(BT + (size_t)(n0 + srow8) * K) + ssb;
  char* aD = (char*)As + tid * 16;
  char* bD = (char*)Bs + tid * 16;
  const int rk0 = (fq << 4) ^ ((fr & 7) << 4);
  const int rk1 = ((fq << 4) + 64) ^ ((fr & 7) << 4);
  f32x4 acc[4][4] = {};

  // prologue: stage tile 0
#pragma unroll
  for (int gg = 0; gg < 4; ++gg)
    GLL16(aS + (size_t)(gg * 32) * K * 2, aD + gg * 4096);
#pragma unroll
  for (int gg = 0; gg < 4; ++gg)
    GLL16(bS + (size_t)(gg * 32) * K * 2, bD + gg * 4096);

  for (int k0 = 0; k0 < K; k0 += 64) {
    asm volatile("s_waitcnt vmcnt(0)" ::: "memory");   // prefetched tile landed
    __builtin_amdgcn_s_barrier();
    // ---- read phase: all fragments -> regs ----
    bf16x8 af[4][2], bfr[4][2];
#pragma unroll
    for (int mi = 0; mi < 4; ++mi) {
      const char* p = (char*)As + (wr + mi * 16 + fr) * 128;
      af[mi][0] = ld_bf16x8(p + rk0);
      af[mi][1] = ld_bf16x8(p + rk1);
    }
#pragma unroll
    for (int ni = 0; ni < 4; ++ni) {
      const char* p = (char*)Bs + (wc + ni * 16 + fr) * 128;
      bfr[ni][0] = ld_bf16x8(p + rk0);
      bfr[ni][1] = ld_bf16x8(p + rk1);
    }
    asm volatile("s_waitcnt lgkmcnt(0)" ::: "memory");
    __builtin_amdgcn_sched_barrier(0);
    __builtin_amdgcn_s_barrier();   // all waves' LDS reads drained
    // ---- prefetch next tile into the same buffers ----
    if (k0 + 64 < K) {
      const size_t kb = (size_t)(k0 + 64) * 2;
#pragma unroll
      for (int gg = 0; gg < 4; ++gg)
        GLL16(aS + (size_t)(gg * 32) * K * 2 + kb, aD + gg * 4096);
#pragma unroll
      for (int gg = 0; gg < 4; ++gg)
        GLL16(bS + (size_t)(gg * 32) * K * 2 + kb, bD + gg * 4096);
    }
    // ---- compute (reg-fed) under GLL flight ----
    __builtin_amdgcn_s_setprio(1);
#pragma unroll
    for (int mi = 0; mi < 4; ++mi)
#pragma unroll
      for (int ni = 0; ni < 4; ++ni) {
        acc[mi][ni] = __builtin_amdgcn_mfma_f32_16x16x32_bf16(
            af[mi][0], bfr[ni][0], acc[mi][ni], 0, 0, 0);
        acc[mi][ni] = __builtin_amdgcn_mfma_f32_16x16x32_bf16(
            af[mi][1], bfr[ni][1], acc[mi][ni], 0, 0, 0);
      }
    __builtin_amdgcn_s_setprio(0);
  }
#pragma unroll
  for (int mi = 0; mi < 4; ++mi) {
#pragma unroll
    for (int ni = 0; ni < 4; ++ni) {
#pragma unroll
      for (int j = 0; j < 4; ++j) {
        const int r = m0 + wr + mi * 16 + fq * 4 + j;
        const int c = n0 + wc + ni * 16 + fr;
        const float v = acc[mi][ni][j];
        if (q0) {
          const int t = r >> 1, bb = r & 1;
          if (c < 1024) {
            const int h = c >> 6, d = c & 63;
            o_qw[(((size_t)(bb * NH + h)) * TSEQ + t) * DHD + d] = __float2bfloat16(v + rwb[c]);
          } else if (c < 2048) {
            const int e = c - 1024, h = e >> 6, d = e & 63;
            o_k[(((size_t)(bb * NH + h)) * TSEQ + t) * DHD + d] = __float2bfloat16(v);
          } else {
            const int e = c - 2048, h = e >> 6, d = e & 63;
            o_vT[(((size_t)(bb * NH + h)) * DHD + d) * TSEQ + t] = __float2bfloat16(v);
          }
        } else {
          const int h = c >> 6, d = c & 63;
          o_rT[((size_t)h * TSEQ + r) * DHD + d] = __float2bfloat16(v);
        }
      }
    }
  }
}

// ---------- out GEMM: BM=128 x BN=64, 512 blocks, split-phase pipelined ----------
__global__ __launch_bounds__(256) void k_gemm2(
    const __hip_bfloat16* __restrict__ A, const __hip_bfloat16* __restrict__ BT,
    float* __restrict__ outF) {
  __shared__ __align__(16) __hip_bfloat16 As[128 * 64];   // 16 KB
  __shared__ __align__(16) __hip_bfloat16 Bs[64 * 64];    // 8 KB
  const int tid = threadIdx.x, lane = tid & 63;
  const int K = 1024, N = 1024, ntn = 16;
  const int tile = (blockIdx.x & 7) * 64 + (blockIdx.x >> 3);   // 512 = 8*64
  const int m0 = (tile / ntn) * 128, n0 = (tile % ntn) * 64;
  const int wid = tid >> 6;
  const int wr = (wid >> 1) * 64, wc = (wid & 1) * 32;
  const int fr = lane & 15, fq = lane >> 4;
  const int srow8 = tid >> 3;
  const int ssb = ((tid & 7) << 4) ^ ((srow8 & 7) << 4);
  const char* aS = (const char*)(A + (size_t)(m0 + srow8) * K) + ssb;
  const char* bS = (const char*)(BT + (size_t)(n0 + srow8) * K) + ssb;
  char* aD = (char*)As + tid * 16;
  char* bD = (char*)Bs + tid * 16;
  const int rk0 = (fq << 4) ^ ((fr & 7) << 4);
  const int rk1 = ((fq << 4) + 64) ^ ((fr & 7) << 4);
  f32x4 acc[4][2] = {};

  // prologue: stage tile 0
#pragma unroll
  for (int gg = 0; gg < 4; ++gg)
    GLL16(aS + (size_t)(gg * 32) * K * 2, aD + gg * 4096);
#pragma unroll
  for (int gg = 0; gg < 2; ++gg)
    GLL16(bS + (size_t)(gg * 32) * K * 2, bD + gg * 4096);

  for (int k0 = 0; k0 < K; k0 += 64) {
    asm volatile("s_waitcnt vmcnt(0)" ::: "memory");
    __builtin_amdgcn_s_barrier();
    // ---- read phase ----
    bf16x8 af[4][2], bfr[2][2];
#pragma unroll
    for (int mi = 0; mi < 4; ++mi) {
      const char* p = (char*)As + (wr + mi * 16 + fr) * 128;
      af[mi][0] = ld_bf16x8(p + rk0);
      af[mi][1] = ld_bf16x8(p + rk1);
    }
#pragma unroll
    for (int ni = 0; ni < 2; ++ni) {
      const char* p = (char*)Bs + (wc + ni * 16 + fr) * 128;
      bfr[ni][0] = ld_bf16x8(p + rk0);
      bfr[ni][1] = ld_bf16x8(p + rk1);
    }
    asm volatile("s_waitcnt lgkmcnt(0)" ::: "memory");
    __builtin_amdgcn_sched_barrier(0);
    __builtin_amdgcn_s_barrier();
    // ---- prefetch next tile ----
    if (k0 + 64 < K) {
      const size_t kb = (size_t)(k0 + 64) * 2;
#pragma unroll
      for (int gg = 0; gg < 4; ++gg)
        GLL16(aS + (size_t)(gg * 32) * K * 2 + kb, aD + gg * 4096);
#pragma unroll
      for (int gg = 0; gg < 2; ++gg)
        GLL16(bS + (size_t)(gg * 32) * K * 2 + kb, bD + gg * 4096);
    }
    // ---- compute ----
    __builtin_amdgcn_s_setprio(1);
#pragma unroll
    for (int mi = 0; mi < 4; ++mi)
#pragma unroll
      for (int ni = 0; ni < 2; ++ni) {
        acc[mi][ni] = __builtin_amdgcn_mfma_f32_16x16x32_bf16(
            af[mi][0], bfr[ni][0], acc[mi][ni], 0, 0, 0);
        acc[mi][ni] = __builtin_amdgcn_mfma_f32_16x16x32_bf16(
            af[mi][1], bfr[ni][1], acc[mi][ni], 0, 0, 0);
      }
    __builtin_amdgcn_s_setprio(0);
  }
#pragma unroll
  for (int mi = 0; mi < 4; ++mi)
#pragma unroll
    for (int ni = 0; ni < 2; ++ni)
#pragma unroll
      for (int j = 0; j < 4; ++j) {
        const int r = m0 + wr + mi * 16 + fq * 4 + j;
        const int c = n0 + wc + ni * 16 + fr;
        outF[(size_t)r * N + c] = acc[mi][ni][j];
      }
}

// ---------- fused causal rel-attention: R11 structure, de-conflicted strides ----------
// Only change vs R19: plq stride 72 -> 88 bf16 (176B: read bank (12fr+4fq)%32,
// ~2-way vs prior 8-way); braw stride 88 -> 84 f32 (336B: write bank
// (20fr+4fq)%32, ~2-way). Both 16B-aligned; fit the 5632B/wave scratch.
__global__ __launch_bounds__(256, 2) void k_attn(
    const __hip_bfloat16* __restrict__ qw,
    const __hip_bfloat16* __restrict__ kb, const __hip_bfloat16* __restrict__ vT,
    const __hip_bfloat16* __restrict__ rT,
    const float* __restrict__ rwb, const float* __restrict__ rrb,
    __hip_bfloat16* __restrict__ av) {
  const int tid = threadIdx.x, lane = tid & 63;
  const int w = __builtin_amdgcn_readfirstlane(tid >> 6);
  const int fr = lane & 15, fq = lane >> 4;
  const int l8 = lane >> 3, lb = lane & 7;
  const int bid = blockIdx.x;
  const int xcd = bid & 7, idx = bid >> 3;     // idx 0..63
  const int bh = xcd * 4 + (idx & 3);          // 4 heads per XCD
  const int pr = idx >> 2;                     // pair 0..15
  const int bb = bh >> 4, h = bh & 15;
  const char* Kp = (const char*)(kb + (size_t)bh * TSEQ * DHD);   // row t:128B
  const char* Vp = (const char*)(vT + (size_t)bh * DHD * TSEQ);   // row d:4096B
  const char* Rp = (const char*)(rT + (size_t)h * TSEQ * DHD);    // row t:128B

  __shared__ __align__(16) __hip_bfloat16 Ksm[2][64][64];   // 16 KB
  __shared__ __align__(16) __hip_bfloat16 Vsm[2][64][64];   // 16 KB
  __shared__ __align__(16) __hip_bfloat16 Rsm[192][64];     // 24 KB circular
  __shared__ __align__(16) char scratch[4][5632];           // braw/plq overlay

  const int swz = (lb << 4) ^ (l8 << 4);                 // staging src byte
  const int koff0 = (fq << 4) ^ ((fr & 7) << 4);         // swizzled read c=0
  const int koff1 = ((fq << 4) + 64) ^ ((fr & 7) << 4);  // swizzled read c=1
  const int rowA = w * 16 + l8;                          // K/V stage rows
  const int kOff0 = rowA * 128 + swz, kOff1 = (rowA + 8) * 128 + swz;
  const int vOff0 = rowA * 4096 + swz, vOff1 = (rowA + 8) * 4096 + swz;
  char* kDstB = (char*)Ksm + w * 2048 + lane * 16;   // + buf*8192
  char* vDstB = (char*)Vsm + w * 2048 + lane * 16;
  char* RsmC = (char*)Rsm;
  float* brawW = (float*)scratch[w];                       // [16][84] f32
  __hip_bfloat16* plqW = (__hip_bfloat16*)scratch[w];      // [16][88] bf16 overlay
  const f32x4 zero = {0.f, 0.f, 0.f, 0.f};
  struct B4 { __hip_bfloat16 a, b, c, d; };

  const float* rwbh = rwb + h * 64;
  const float* rrbh = rrb + h * 64;

#pragma unroll
  for (int part = 0; part < 2; ++part) {
    const int p4 = part ? 31 - pr : pr;
    const int nk = p4 + 1;
    const int iw0 = p4 * 64 + w * 16;
    const int rbase0 = 1984 - 64 * p4;
    int rm = (((1 - p4) % 3) + 3) % 3 * 64;    // rbase0 mod 192
    const __hip_bfloat16* qwp = qw + ((size_t)bh * TSEQ + iw0 + fr) * DHD + fq * 8;
    const bf16x8 qwf0 = ld_bf16x8(qwp), qwf1 = ld_bf16x8(qwp + 32);
    bf16x8 qrf0, qrf1;   // qr reconstructed from bias delta
#pragma unroll
    for (int e = 0; e < 8; ++e) {
      qrf0[e] = (__bf16)((float)qwf0[e] + rrbh[fq * 8 + e] - rwbh[fq * 8 + e]);
      qrf1[e] = (__bf16)((float)qwf1[e] + rrbh[32 + fq * 8 + e] - rwbh[32 + fq * 8 + e]);
    }
    f32x4 o[4] = {};
    float mrow = -INFINITY, lrow = 0.f;

    asm volatile("s_waitcnt lgkmcnt(0)" ::: "memory");  // harden: all LDS ops done
    __builtin_amdgcn_s_barrier();   // protect previous part's reads

    // ---- prologue: K(0),V(0) -> buf0; R rows [rbase0, rbase0+128) ----
    GLL16(Kp + kOff0, kDstB);
    GLL16(Kp + kOff1, kDstB + 1024);
    GLL16(Vp + vOff0, vDstB);
    GLL16(Vp + vOff1, vDstB + 1024);
#pragma unroll
    for (int s = 0; s < 4; ++s) {
      int pb = rm + w * 32 + s * 8;
      if (pb >= 192) pb -= 192;
      int g = rbase0 + w * 32 + s * 8 + l8;
      g = g > 2047 ? 2047 : g;
      GLL16(Rp + g * 128 + swz, RsmC + pb * 128 + (lb << 4));
    }

    int rbase = rbase0;
    int thr = iw0 + fr;
    const char* kTile = Kp + 8192;    // src for K(kt+1)
    const char* vTile = Vp + 128;     // src for V(kt+1)
    for (int kt = 0; kt < nk; ++kt) {
      asm volatile("s_waitcnt vmcnt(0)" ::: "memory");
      __builtin_amdgcn_s_barrier();
      // ---- prefetch tile kt+1 (skip on last) ----
      if (kt + 1 < nk) {
        const int nxtOff = ((kt + 1) & 1) << 13;
        GLL16(kTile + kOff0, kDstB + nxtOff);
        GLL16(kTile + kOff1, kDstB + nxtOff + 1024);
        GLL16(vTile + vOff0, vDstB + nxtOff);
        GLL16(vTile + vOff1, vDstB + nxtOff + 1024);
        const int rm2 = rm >= 64 ? rm - 64 : rm + 128;   // (rbase+128) mod 192
#pragma unroll
        for (int s = 0; s < 2; ++s) {
          int g = rbase + 128 + w * 16 + s * 8 + l8;
          g = g > 2047 ? 2047 : g;
          GLL16(Rp + g * 128 + swz,
                RsmC + (rm2 + w * 16 + s * 8) * 128 + (lb << 4));
        }
        kTile += 8192;
        vTile += 128;
      }
      // ---- S^T from Ksm[cur] (staged last iter; ready) ----
      const int curOff = (kt & 1) << 13;
      const char* kls = (const char*)Ksm + curOff + fr * 128;
      f32x4 st[4];
      __builtin_amdgcn_s_setprio(1);
#pragma unroll
      for (int n = 0; n < 4; ++n) {
        st[n] = __builtin_amdgcn_mfma_f32_16x16x32_bf16(ld_bf16x8(kls + n * 2048 + koff0), qwf0, zero, 0, 0, 0);
        st[n] = __builtin_amdgcn_mfma_f32_16x16x32_bf16(ld_bf16x8(kls + n * 2048 + koff1), qwf1, st[n], 0, 0, 0);
      }
      __builtin_amdgcn_s_setprio(0);
      // ---- band from circular Rsm: D[m][q=fr] -> b128 braw write ----
      const int base_l = rm + 48 - 16 * w + fr;   // <= 191; == fr (mod 8)
      __builtin_amdgcn_s_setprio(1);
#pragma unroll
      for (int pp = 0; pp < 5; ++pp) {
        int rrow = base_l + 16 * pp;
        if (rrow >= 192) rrow -= 192;
        const char* rls = RsmC + rrow * 128;
        f32x4 br = __builtin_amdgcn_mfma_f32_16x16x32_bf16(ld_bf16x8(rls + koff0), qrf0, zero, 0, 0, 0);
        br = __builtin_amdgcn_mfma_f32_16x16x32_bf16(ld_bf16x8(rls + koff1), qrf1, br, 0, 0, 0);
        *reinterpret_cast<f32x4*>(&brawW[fr * 84 + pp * 16 + 4 * fq]) = br;
      }
      __builtin_amdgcn_s_setprio(0);
      // ---- scores + in-register online softmax (q = fr) ----
      const float* brd = &brawW[fr * 84 + 15 - fr];
      float mx = -INFINITY;
#pragma unroll
      for (int n = 0; n < 4; ++n) {
#pragma unroll
        for (int j = 0; j < 4; ++j) {
          const int koff = 16 * n + 4 * fq + j;
          const float s = (koff > thr) ? -INFINITY : (st[n][j] + brd[koff]) * 0.125f;
          st[n][j] = s;
          mx = fmaxf(mx, s);
        }
      }
      mx = fmaxf(mx, __shfl_xor(mx, 16));
      mx = fmaxf(mx, __shfl_xor(mx, 32));
      const float mn = fmaxf(mrow, mx);
      const float al = __expf(mrow - mn);
      mrow = mn;
      float rsum = 0.f;
#pragma unroll
      for (int n = 0; n < 4; ++n)
#pragma unroll
        for (int j = 0; j < 4; ++j) {
          const float pv = __expf(st[n][j] - mn);
          st[n][j] = pv;
          rsum += pv;
        }
      rsum += __shfl_xor(rsum, 16);
      rsum += __shfl_xor(rsum, 32);
      lrow = lrow * al + rsum;
#pragma unroll
      for (int nd = 0; nd < 4; ++nd) o[nd] *= al;
      // ---- P store (overlay; braw fully consumed) ----
#pragma unroll
      for (int n = 0; n < 4; ++n) {
        B4 pk;
        pk.a = __float2bfloat16(st[n][0]);
        pk.b = __float2bfloat16(st[n][1]);
        pk.c = __float2bfloat16(st[n][2]);
        pk.d = __float2bfloat16(st[n][3]);
        *reinterpret_cast<B4*>(&plqW[fr * 88 + 16 * n + 4 * fq]) = pk;
      }
      // ---- O^T += V^T . P^T from Vsm[cur] ----
      const char* vls = (const char*)Vsm + curOff + fr * 128;
      __builtin_amdgcn_s_setprio(1);
#pragma unroll
      for (int c = 0; c < 2; ++c) {
        const bf16x8 pf = ld_bf16x8(&plqW[fr * 88 + 8 * fq + 32 * c]);
#pragma unroll
        for (int nd = 0; nd < 4; ++nd)
          o[nd] = __builtin_amdgcn_mfma_f32_16x16x32_bf16(
              ld_bf16x8(vls + nd * 2048 + (c ? koff1 : koff0)), pf, o[nd], 0, 0, 0);
      }
      __builtin_amdgcn_s_setprio(0);
      // ---- advance ----
      rbase += 64;
      rm = rm >= 128 ? 0 : rm + 64;
      thr -= 64;
    }
    // ---- epilogue: per-lane 1/l, packed 8B stores; row i = iw0+fr ----
    const float linv = 1.f / lrow;
    const int i = iw0 + fr;
#pragma unroll
    for (int nd = 0; nd < 4; ++nd) {
      B4 pack;
      pack.a = __float2bfloat16(o[nd][0] * linv);
      pack.b = __float2bfloat16(o[nd][1] * linv);
      pack.c = __float2bfloat16(o[nd][2] * linv);
      pack.d = __float2bfloat16(o[nd][3] * linv);
      *reinterpret_cast<B4*>(av + ((size_t)i * NB + bb) * DM + h * DHD + 16 * nd + 4 * fq) = pack;
    }
  }
}

extern "C" void kernel_launch(void* const* d_in, const int* in_sizes, int n_in,
                              void* d_out, int out_size, void* d_ws, size_t ws_size,
                              hipStream_t stream) {
  (void)in_sizes; (void)n_in; (void)out_size; (void)ws_size;
  const float* x    = (const float*)d_in[0];
  const float* pos  = (const float*)d_in[1];
  const float* ln_g = (const float*)d_in[2];
  const float* ln_b = (const float*)d_in[3];
  const float* Wqkv = (const float*)d_in[4];
  const float* Wr   = (const float*)d_in[5];
  const float* Wo   = (const float*)d_in[6];
  const float* rwb  = (const float*)d_in[7];
  const float* rrb  = (const float*)d_in[8];
  float* out = (float*)d_out;

  char* ws = (char*)d_ws;
  size_t off = 0;
  auto alloc = [&](size_t n) {
    char* p = ws + off; off += (n + 255) & ~(size_t)255; return p;
  };
  __hip_bfloat16* wqkvT = (__hip_bfloat16*)alloc((size_t)3072 * 1024 * 2);
  __hip_bfloat16* wrT   = (__hip_bfloat16*)alloc((size_t)1024 * 1024 * 2);
  __hip_bfloat16* woT   = (__hip_bfloat16*)alloc((size_t)1024 * 1024 * 2);
  __hip_bfloat16* posb  = (__hip_bfloat16*)alloc((size_t)2048 * 1024 * 2);
  __hip_bfloat16* xn    = (__hip_bfloat16*)alloc((size_t)4096 * 1024 * 2);
  __hip_bfloat16* qwb   = (__hip_bfloat16*)alloc((size_t)NB * NH * TSEQ * DHD * 2);
  __hip_bfloat16* kbb   = (__hip_bfloat16*)alloc((size_t)NB * NH * TSEQ * DHD * 2);
  __hip_bfloat16* vTb   = (__hip_bfloat16*)alloc((size_t)NB * NH * TSEQ * DHD * 2);
  __hip_bfloat16* rTb   = (__hip_bfloat16*)alloc((size_t)NH * TSEQ * DHD * 2);
  __hip_bfloat16* avb   = (__hip_bfloat16*)alloc((size_t)4096 * 1024 * 2);
  (void)alloc(64 * 1024);  // guard region

  k_prep<<<11264, 256, 0, stream>>>(Wqkv, Wr, Wo, wqkvT, wrT, woT,
                                    pos, posb, x, ln_g, ln_b, xn);
  k_gemm01<<<896, 256, 0, stream>>>(xn, wqkvT, posb, wrT,
                                    qwb, kbb, vTb, rwb, rTb);
  k_attn<<<512, 256, 0, stream>>>(qwb, kbb, vTb, rTb, rwb, rrb, avb);
  k_gemm2<<<512, 256, 0, stream>>>(avb, woT, out);
}

// Round 21
// 151.991 us; speedup vs baseline: 1.3675x; 1.0709x over previous
//
#include <hip/hip_runtime.h>
#include <hip/hip_bf16.h>
#include <math.h>

#define TSEQ 2048
#define NB 2
#define DM 1024
#define NH 16
#define DHD 64

typedef __attribute__((ext_vector_type(8))) __bf16 bf16x8;
typedef __attribute__((ext_vector_type(8))) short s16x8;
typedef __attribute__((ext_vector_type(4))) float f32x4;

__device__ __forceinline__ bf16x8 ld_bf16x8(const void* p) {
  s16x8 v = *reinterpret_cast<const s16x8*>(p);
  return __builtin_bit_cast(bf16x8, v);
}

#define GLL16(g, l) __builtin_amdgcn_global_load_lds( \
    (const __attribute__((address_space(1))) void*)(g), \
    (__attribute__((address_space(3))) void*)(l), 16, 0, 0)

// ---------- fused prep: weight transposes + pos cast + LayerNorm ----------
__global__ __launch_bounds__(256) void k_prep(
    const float* __restrict__ Wqkv, const float* __restrict__ Wr,
    const float* __restrict__ Wo, __hip_bfloat16* __restrict__ wqkvT,
    __hip_bfloat16* __restrict__ wrT, __hip_bfloat16* __restrict__ woT,
    const float* __restrict__ pos, __hip_bfloat16* __restrict__ posb,
    const float* __restrict__ x, const float* __restrict__ g,
    const float* __restrict__ b, __hip_bfloat16* __restrict__ xn) {
  __shared__ float t[32][33];
  __shared__ float r1[4], r2[4];
  const int blk = blockIdx.x, tid = threadIdx.x;
  struct B4 { __hip_bfloat16 a, b, c, d; };
  if (blk < 5120) {
    const int tx = tid & 31, ty = tid >> 5;
    const float* in; __hip_bfloat16* out; int C, bx, by;
    if (blk < 3072)      { in = Wqkv; out = wqkvT; C = 3072; bx = blk % 96;  by = blk / 96; }
    else if (blk < 4096) { in = Wr;   out = wrT;   C = 1024; bx = (blk - 3072) % 32; by = (blk - 3072) / 32; }
    else                 { in = Wo;   out = woT;   C = 1024; bx = (blk - 4096) % 32; by = (blk - 4096) / 32; }
    const int c0 = bx * 32, r0 = by * 32;
#pragma unroll
    for (int j = 0; j < 4; ++j)
      t[ty + j * 8][tx] = in[(size_t)(r0 + ty + j * 8) * C + c0 + tx];
    __syncthreads();
#pragma unroll
    for (int j = 0; j < 4; ++j) {
      const int oc = ty + j * 8;
      out[(size_t)(c0 + oc) * 1024 + r0 + tx] = __float2bfloat16(t[tx][oc]);
    }
  } else if (blk < 7168) {
    const int i = ((blk - 5120) * 256 + tid) * 4;
    const float4 v = *reinterpret_cast<const float4*>(pos + i);
    B4 o;
    o.a = __float2bfloat16(v.x); o.b = __float2bfloat16(v.y);
    o.c = __float2bfloat16(v.z); o.d = __float2bfloat16(v.w);
    *reinterpret_cast<B4*>(posb + i) = o;
  } else {
    const int row = blk - 7168;
    const float4 v = reinterpret_cast<const float4*>(x + (size_t)row * DM)[tid];
    float s = v.x + v.y + v.z + v.w;
#pragma unroll
    for (int off = 32; off; off >>= 1) s += __shfl_xor(s, off);
    if ((tid & 63) == 0) r1[tid >> 6] = s;
    __syncthreads();
    const float mu = (r1[0] + r1[1] + r1[2] + r1[3]) * (1.f / DM);
    const float dx = v.x - mu, dy = v.y - mu, dz = v.z - mu, dw = v.w - mu;
    float q = dx * dx + dy * dy + dz * dz + dw * dw;
#pragma unroll
    for (int off = 32; off; off >>= 1) q += __shfl_xor(q, off);
    if ((tid & 63) == 0) r2[tid >> 6] = q;
    __syncthreads();
    const float rs = rsqrtf((r2[0] + r2[1] + r2[2] + r2[3]) * (1.f / DM) + 1e-5f);
    const float4 gv = reinterpret_cast<const float4*>(g)[tid];
    const float4 bv = reinterpret_cast<const float4*>(b)[tid];
    B4 o;
    o.a = __float2bfloat16(dx * rs * gv.x + bv.x);
    o.b = __float2bfloat16(dy * rs * gv.y + bv.y);
    o.c = __float2bfloat16(dz * rs * gv.z + bv.z);
    o.d = __float2bfloat16(dw * rs * gv.w + bv.w);
    reinterpret_cast<B4*>(xn + (size_t)row * DM)[tid] = o;
  }
}

// ---------- merged QKV + R GEMM, split-phase pipelined (R18-proven) ----------
__global__ __launch_bounds__(256) void k_gemm01(
    const __hip_bfloat16* __restrict__ xn, const __hip_bfloat16* __restrict__ wqkvT,
    const __hip_bfloat16* __restrict__ posb, const __hip_bfloat16* __restrict__ wrT,
    __hip_bfloat16* __restrict__ o_qw, __hip_bfloat16* __restrict__ o_k,
    __hip_bfloat16* __restrict__ o_vT, const float* __restrict__ rwb,
    __hip_bfloat16* __restrict__ o_rT) {
  __shared__ __align__(16) __hip_bfloat16 As[128 * 64];
  __shared__ __align__(16) __hip_bfloat16 Bs[128 * 64];
  const int tid = threadIdx.x, lane = tid & 63;
  const int tile = (blockIdx.x & 7) * 112 + (blockIdx.x >> 3);
  const bool q0 = tile < 768;
  const int t0 = q0 ? tile : tile - 768;
  const int ntn = q0 ? 24 : 8;
  const __hip_bfloat16* A  = q0 ? xn : posb;
  const __hip_bfloat16* BT = q0 ? wqkvT : wrT;
  const int K = 1024;
  const int m0 = (t0 / ntn) * 128, n0 = (t0 % ntn) * 128;
  const int wid = tid >> 6;
  const int wr = (wid >> 1) * 64, wc = (wid & 1) * 64;
  const int fr = lane & 15, fq = lane >> 4;
  const int srow8 = tid >> 3;
  const int ssb = ((tid & 7) << 4) ^ ((srow8 & 7) << 4);
  const char* aS = (const char*)(A + (size_t)(m0 + srow8) * K) + ssb;
  const char* bS = (const char*)(BT + (size_t)(n0 + srow8) * K) + ssb;
  char* aD = (char*)As + tid * 16;
  char* bD = (char*)Bs + tid * 16;
  const int rk0 = (fq << 4) ^ ((fr & 7) << 4);
  const int rk1 = ((fq << 4) + 64) ^ ((fr & 7) << 4);
  f32x4 acc[4][4] = {};

  // prologue: stage tile 0
#pragma unroll
  for (int gg = 0; gg < 4; ++gg)
    GLL16(aS + (size_t)(gg * 32) * K * 2, aD + gg * 4096);
#pragma unroll
  for (int gg = 0; gg < 4; ++gg)
    GLL16(bS + (size_t)(gg * 32) * K * 2, bD + gg * 4096);

  for (int k0 = 0; k0 < K; k0 += 64) {
    asm volatile("s_waitcnt vmcnt(0)" ::: "memory");   // prefetched tile landed
    __builtin_amdgcn_s_barrier();
    // ---- read phase: all fragments -> regs ----
    bf16x8 af[4][2], bfr[4][2];
#pragma unroll
    for (int mi = 0; mi < 4; ++mi) {
      const char* p = (char*)As + (wr + mi * 16 + fr) * 128;
      af[mi][0] = ld_bf16x8(p + rk0);
      af[mi][1] = ld_bf16x8(p + rk1);
    }
#pragma unroll
    for (int ni = 0; ni < 4; ++ni) {
      const char* p = (char*)Bs + (wc + ni * 16 + fr) * 128;
      bfr[ni][0] = ld_bf16x8(p + rk0);
      bfr[ni][1] = ld_bf16x8(p + rk1);
    }
    asm volatile("s_waitcnt lgkmcnt(0)" ::: "memory");
    __builtin_amdgcn_sched_barrier(0);
    __builtin_amdgcn_s_barrier();   // all waves' LDS reads drained
    // ---- prefetch next tile into the same buffers ----
    if (k0 + 64 < K) {
      const size_t kb = (size_t)(k0 + 64) * 2;
#pragma unroll
      for (int gg = 0; gg < 4; ++gg)
        GLL16(aS + (size_t)(gg * 32) * K * 2 + kb, aD + gg * 4096);
#pragma unroll
      for (int gg = 0; gg < 4; ++gg)
        GLL16(bS + (size_t)(gg * 32) * K * 2 + kb, bD + gg * 4096);
    }
    // ---- compute (reg-fed) under GLL flight ----
    __builtin_amdgcn_s_setprio(1);
#pragma unroll
    for (int mi = 0; mi < 4; ++mi)
#pragma unroll
      for (int ni = 0; ni < 4; ++ni) {
        acc[mi][ni] = __builtin_amdgcn_mfma_f32_16x16x32_bf16(
            af[mi][0], bfr[ni][0], acc[mi][ni], 0, 0, 0);
        acc[mi][ni] = __builtin_amdgcn_mfma_f32_16x16x32_bf16(
            af[mi][1], bfr[ni][1], acc[mi][ni], 0, 0, 0);
      }
    __builtin_amdgcn_s_setprio(0);
  }
#pragma unroll
  for (int mi = 0; mi < 4; ++mi) {
#pragma unroll
    for (int ni = 0; ni < 4; ++ni) {
#pragma unroll
      for (int j = 0; j < 4; ++j) {
        const int r = m0 + wr + mi * 16 + fq * 4 + j;
        const int c = n0 + wc + ni * 16 + fr;
        const float v = acc[mi][ni][j];
        if (q0) {
          const int t = r >> 1, bb = r & 1;
          if (c < 1024) {
            const int h = c >> 6, d = c & 63;
            o_qw[(((size_t)(bb * NH + h)) * TSEQ + t) * DHD + d] = __float2bfloat16(v + rwb[c]);
          } else if (c < 2048) {
            const int e = c - 1024, h = e >> 6, d = e & 63;
            o_k[(((size_t)(bb * NH + h)) * TSEQ + t) * DHD + d] = __float2bfloat16(v);
          } else {
            const int e = c - 2048, h = e >> 6, d = e & 63;
            o_vT[(((size_t)(bb * NH + h)) * DHD + d) * TSEQ + t] = __float2bfloat16(v);
          }
        } else {
          const int h = c >> 6, d = c & 63;
          o_rT[((size_t)h * TSEQ + r) * DHD + d] = __float2bfloat16(v);
        }
      }
    }
  }
}

// ---------- out GEMM: BM=128 x BN=64, 512 blocks, split-phase pipelined ----------
__global__ __launch_bounds__(256) void k_gemm2(
    const __hip_bfloat16* __restrict__ A, const __hip_bfloat16* __restrict__ BT,
    float* __restrict__ outF) {
  __shared__ __align__(16) __hip_bfloat16 As[128 * 64];   // 16 KB
  __shared__ __align__(16) __hip_bfloat16 Bs[64 * 64];    // 8 KB
  const int tid = threadIdx.x, lane = tid & 63;
  const int K = 1024, N = 1024, ntn = 16;
  const int tile = (blockIdx.x & 7) * 64 + (blockIdx.x >> 3);   // 512 = 8*64
  const int m0 = (tile / ntn) * 128, n0 = (tile % ntn) * 64;
  const int wid = tid >> 6;
  const int wr = (wid >> 1) * 64, wc = (wid & 1) * 32;
  const int fr = lane & 15, fq = lane >> 4;
  const int srow8 = tid >> 3;
  const int ssb = ((tid & 7) << 4) ^ ((srow8 & 7) << 4);
  const char* aS = (const char*)(A + (size_t)(m0 + srow8) * K) + ssb;
  const char* bS = (const char*)(BT + (size_t)(n0 + srow8) * K) + ssb;
  char* aD = (char*)As + tid * 16;
  char* bD = (char*)Bs + tid * 16;
  const int rk0 = (fq << 4) ^ ((fr & 7) << 4);
  const int rk1 = ((fq << 4) + 64) ^ ((fr & 7) << 4);
  f32x4 acc[4][2] = {};

  // prologue: stage tile 0
#pragma unroll
  for (int gg = 0; gg < 4; ++gg)
    GLL16(aS + (size_t)(gg * 32) * K * 2, aD + gg * 4096);
#pragma unroll
  for (int gg = 0; gg < 2; ++gg)
    GLL16(bS + (size_t)(gg * 32) * K * 2, bD + gg * 4096);

  for (int k0 = 0; k0 < K; k0 += 64) {
    asm volatile("s_waitcnt vmcnt(0)" ::: "memory");
    __builtin_amdgcn_s_barrier();
    // ---- read phase ----
    bf16x8 af[4][2], bfr[2][2];
#pragma unroll
    for (int mi = 0; mi < 4; ++mi) {
      const char* p = (char*)As + (wr + mi * 16 + fr) * 128;
      af[mi][0] = ld_bf16x8(p + rk0);
      af[mi][1] = ld_bf16x8(p + rk1);
    }
#pragma unroll
    for (int ni = 0; ni < 2; ++ni) {
      const char* p = (char*)Bs + (wc + ni * 16 + fr) * 128;
      bfr[ni][0] = ld_bf16x8(p + rk0);
      bfr[ni][1] = ld_bf16x8(p + rk1);
    }
    asm volatile("s_waitcnt lgkmcnt(0)" ::: "memory");
    __builtin_amdgcn_sched_barrier(0);
    __builtin_amdgcn_s_barrier();
    // ---- prefetch next tile ----
    if (k0 + 64 < K) {
      const size_t kb = (size_t)(k0 + 64) * 2;
#pragma unroll
      for (int gg = 0; gg < 4; ++gg)
        GLL16(aS + (size_t)(gg * 32) * K * 2 + kb, aD + gg * 4096);
#pragma unroll
      for (int gg = 0; gg < 2; ++gg)
        GLL16(bS + (size_t)(gg * 32) * K * 2 + kb, bD + gg * 4096);
    }
    // ---- compute ----
    __builtin_amdgcn_s_setprio(1);
#pragma unroll
    for (int mi = 0; mi < 4; ++mi)
#pragma unroll
      for (int ni = 0; ni < 2; ++ni) {
        acc[mi][ni] = __builtin_amdgcn_mfma_f32_16x16x32_bf16(
            af[mi][0], bfr[ni][0], acc[mi][ni], 0, 0, 0);
        acc[mi][ni] = __builtin_amdgcn_mfma_f32_16x16x32_bf16(
            af[mi][1], bfr[ni][1], acc[mi][ni], 0, 0, 0);
      }
    __builtin_amdgcn_s_setprio(0);
  }
#pragma unroll
  for (int mi = 0; mi < 4; ++mi)
#pragma unroll
    for (int ni = 0; ni < 2; ++ni)
#pragma unroll
      for (int j = 0; j < 4; ++j) {
        const int r = m0 + wr + mi * 16 + fq * 4 + j;
        const int c = n0 + wc + ni * 16 + fr;
        outF[(size_t)r * N + c] = acc[mi][ni][j];
      }
}

// ---------- fused causal rel-attention: R20 + mask-hoisted score loop ----------
// Only change vs R20: causal mask evaluated ONLY on the last k-tile
// (provably mask-free for kt < nk-1: thr >= 64 > koff_max). Saves 32 VALU
// insts per non-last iteration via a wave-uniform branch.
__global__ __launch_bounds__(256, 2) void k_attn(
    const __hip_bfloat16* __restrict__ qw,
    const __hip_bfloat16* __restrict__ kb, const __hip_bfloat16* __restrict__ vT,
    const __hip_bfloat16* __restrict__ rT,
    const float* __restrict__ rwb, const float* __restrict__ rrb,
    __hip_bfloat16* __restrict__ av) {
  const int tid = threadIdx.x, lane = tid & 63;
  const int w = __builtin_amdgcn_readfirstlane(tid >> 6);
  const int fr = lane & 15, fq = lane >> 4;
  const int l8 = lane >> 3, lb = lane & 7;
  const int bid = blockIdx.x;
  const int xcd = bid & 7, idx = bid >> 3;     // idx 0..63
  const int bh = xcd * 4 + (idx & 3);          // 4 heads per XCD
  const int pr = idx >> 2;                     // pair 0..15
  const int bb = bh >> 4, h = bh & 15;
  const char* Kp = (const char*)(kb + (size_t)bh * TSEQ * DHD);   // row t:128B
  const char* Vp = (const char*)(vT + (size_t)bh * DHD * TSEQ);   // row d:4096B
  const char* Rp = (const char*)(rT + (size_t)h * TSEQ * DHD);    // row t:128B

  __shared__ __align__(16) __hip_bfloat16 Ksm[2][64][64];   // 16 KB
  __shared__ __align__(16) __hip_bfloat16 Vsm[2][64][64];   // 16 KB
  __shared__ __align__(16) __hip_bfloat16 Rsm[192][64];     // 24 KB circular
  __shared__ __align__(16) char scratch[4][5632];           // braw/plq overlay

  const int swz = (lb << 4) ^ (l8 << 4);                 // staging src byte
  const int koff0 = (fq << 4) ^ ((fr & 7) << 4);         // swizzled read c=0
  const int koff1 = ((fq << 4) + 64) ^ ((fr & 7) << 4);  // swizzled read c=1
  const int rowA = w * 16 + l8;                          // K/V stage rows
  const int kOff0 = rowA * 128 + swz, kOff1 = (rowA + 8) * 128 + swz;
  const int vOff0 = rowA * 4096 + swz, vOff1 = (rowA + 8) * 4096 + swz;
  char* kDstB = (char*)Ksm + w * 2048 + lane * 16;   // + buf*8192
  char* vDstB = (char*)Vsm + w * 2048 + lane * 16;
  char* RsmC = (char*)Rsm;
  float* brawW = (float*)scratch[w];                       // [16][84] f32
  __hip_bfloat16* plqW = (__hip_bfloat16*)scratch[w];      // [16][88] bf16 overlay
  const f32x4 zero = {0.f, 0.f, 0.f, 0.f};
  struct B4 { __hip_bfloat16 a, b, c, d; };

  const float* rwbh = rwb + h * 64;
  const float* rrbh = rrb + h * 64;

#pragma unroll
  for (int part = 0; part < 2; ++part) {
    const int p4 = part ? 31 - pr : pr;
    const int nk = p4 + 1;
    const int iw0 = p4 * 64 + w * 16;
    const int rbase0 = 1984 - 64 * p4;
    int rm = (((1 - p4) % 3) + 3) % 3 * 64;    // rbase0 mod 192
    const __hip_bfloat16* qwp = qw + ((size_t)bh * TSEQ + iw0 + fr) * DHD + fq * 8;
    const bf16x8 qwf0 = ld_bf16x8(qwp), qwf1 = ld_bf16x8(qwp + 32);
    bf16x8 qrf0, qrf1;   // qr reconstructed from bias delta
#pragma unroll
    for (int e = 0; e < 8; ++e) {
      qrf0[e] = (__bf16)((float)qwf0[e] + rrbh[fq * 8 + e] - rwbh[fq * 8 + e]);
      qrf1[e] = (__bf16)((float)qwf1[e] + rrbh[32 + fq * 8 + e] - rwbh[32 + fq * 8 + e]);
    }
    f32x4 o[4] = {};
    float mrow = -INFINITY, lrow = 0.f;

    asm volatile("s_waitcnt lgkmcnt(0)" ::: "memory");  // harden: all LDS ops done
    __builtin_amdgcn_s_barrier();   // protect previous part's reads

    // ---- prologue: K(0),V(0) -> buf0; R rows [rbase0, rbase0+128) ----
    GLL16(Kp + kOff0, kDstB);
    GLL16(Kp + kOff1, kDstB + 1024);
    GLL16(Vp + vOff0, vDstB);
    GLL16(Vp + vOff1, vDstB + 1024);
#pragma unroll
    for (int s = 0; s < 4; ++s) {
      int pb = rm + w * 32 + s * 8;
      if (pb >= 192) pb -= 192;
      int g = rbase0 + w * 32 + s * 8 + l8;
      g = g > 2047 ? 2047 : g;
      GLL16(Rp + g * 128 + swz, RsmC + pb * 128 + (lb << 4));
    }

    int rbase = rbase0;
    int thr = iw0 + fr;
    const char* kTile = Kp + 8192;    // src for K(kt+1)
    const char* vTile = Vp + 128;     // src for V(kt+1)
    for (int kt = 0; kt < nk; ++kt) {
      asm volatile("s_waitcnt vmcnt(0)" ::: "memory");
      __builtin_amdgcn_s_barrier();
      // ---- prefetch tile kt+1 (skip on last) ----
      if (kt + 1 < nk) {
        const int nxtOff = ((kt + 1) & 1) << 13;
        GLL16(kTile + kOff0, kDstB + nxtOff);
        GLL16(kTile + kOff1, kDstB + nxtOff + 1024);
        GLL16(vTile + vOff0, vDstB + nxtOff);
        GLL16(vTile + vOff1, vDstB + nxtOff + 1024);
        const int rm2 = rm >= 64 ? rm - 64 : rm + 128;   // (rbase+128) mod 192
#pragma unroll
        for (int s = 0; s < 2; ++s) {
          int g = rbase + 128 + w * 16 + s * 8 + l8;
          g = g > 2047 ? 2047 : g;
          GLL16(Rp + g * 128 + swz,
                RsmC + (rm2 + w * 16 + s * 8) * 128 + (lb << 4));
        }
        kTile += 8192;
        vTile += 128;
      }
      // ---- S^T from Ksm[cur] (staged last iter; ready) ----
      const int curOff = (kt & 1) << 13;
      const char* kls = (const char*)Ksm + curOff + fr * 128;
      f32x4 st[4];
      __builtin_amdgcn_s_setprio(1);
#pragma unroll
      for (int n = 0; n < 4; ++n) {
        st[n] = __builtin_amdgcn_mfma_f32_16x16x32_bf16(ld_bf16x8(kls + n * 2048 + koff0), qwf0, zero, 0, 0, 0);
        st[n] = __builtin_amdgcn_mfma_f32_16x16x32_bf16(ld_bf16x8(kls + n * 2048 + koff1), qwf1, st[n], 0, 0, 0);
      }
      __builtin_amdgcn_s_setprio(0);
      // ---- band from circular Rsm: D[m][q=fr] -> b128 braw write ----
      const int base_l = rm + 48 - 16 * w + fr;   // <= 191; == fr (mod 8)
      __builtin_amdgcn_s_setprio(1);
#pragma unroll
      for (int pp = 0; pp < 5; ++pp) {
        int rrow = base_l + 16 * pp;
        if (rrow >= 192) rrow -= 192;
        const char* rls = RsmC + rrow * 128;
        f32x4 br = __builtin_amdgcn_mfma_f32_16x16x32_bf16(ld_bf16x8(rls + koff0), qrf0, zero, 0, 0, 0);
        br = __builtin_amdgcn_mfma_f32_16x16x32_bf16(ld_bf16x8(rls + koff1), qrf1, br, 0, 0, 0);
        *reinterpret_cast<f32x4*>(&brawW[fr * 84 + pp * 16 + 4 * fq]) = br;
      }
      __builtin_amdgcn_s_setprio(0);
      // ---- scores + in-register online softmax (q = fr) ----
      // Mask is provably inactive for kt < nk-1 (thr >= 64 > koff_max=63).
      const float* brd = &brawW[fr * 84 + 15 - fr];
      float mx = -INFINITY;
      if (kt < nk - 1) {
#pragma unroll
        for (int n = 0; n < 4; ++n) {
#pragma unroll
          for (int j = 0; j < 4; ++j) {
            const int koff = 16 * n + 4 * fq + j;
            const float s = (st[n][j] + brd[koff]) * 0.125f;
            st[n][j] = s;
            mx = fmaxf(mx, s);
          }
        }
      } else {
#pragma unroll
        for (int n = 0; n < 4; ++n) {
#pragma unroll
          for (int j = 0; j < 4; ++j) {
            const int koff = 16 * n + 4 * fq + j;
            const float s = (koff > thr) ? -INFINITY : (st[n][j] + brd[koff]) * 0.125f;
            st[n][j] = s;
            mx = fmaxf(mx, s);
          }
        }
      }
      mx = fmaxf(mx, __shfl_xor(mx, 16));
      mx = fmaxf(mx, __shfl_xor(mx, 32));
      const float mn = fmaxf(mrow, mx);
      const float al = __expf(mrow - mn);
      mrow = mn;
      float rsum = 0.f;
#pragma unroll
      for (int n = 0; n < 4; ++n)
#pragma unroll
        for (int j = 0; j < 4; ++j) {
          const float pv = __expf(st[n][j] - mn);
          st[n][j] = pv;
          rsum += pv;
        }
      rsum += __shfl_xor(rsum, 16);
      rsum += __shfl_xor(rsum, 32);
      lrow = lrow * al + rsum;
#pragma unroll
      for (int nd = 0; nd < 4; ++nd) o[nd] *= al;
      // ---- P store (overlay; braw fully consumed) ----
#pragma unroll
      for (int n = 0; n < 4; ++n) {
        B4 pk;
        pk.a = __float2bfloat16(st[n][0]);
        pk.b = __float2bfloat16(st[n][1]);
        pk.c = __float2bfloat16(st[n][2]);
        pk.d = __float2bfloat16(st[n][3]);
        *reinterpret_cast<B4*>(&plqW[fr * 88 + 16 * n + 4 * fq]) = pk;
      }
      // ---- O^T += V^T . P^T from Vsm[cur] ----
      const char* vls = (const char*)Vsm + curOff + fr * 128;
      __builtin_amdgcn_s_setprio(1);
#pragma unroll
      for (int c = 0; c < 2; ++c) {
        const bf16x8 pf = ld_bf16x8(&plqW[fr * 88 + 8 * fq + 32 * c]);
#pragma unroll
        for (int nd = 0; nd < 4; ++nd)
          o[nd] = __builtin_amdgcn_mfma_f32_16x16x32_bf16(
              ld_bf16x8(vls + nd * 2048 + (c ? koff1 : koff0)), pf, o[nd], 0, 0, 0);
      }
      __builtin_amdgcn_s_setprio(0);
      // ---- advance ----
      rbase += 64;
      rm = rm >= 128 ? 0 : rm + 64;
      thr -= 64;
    }
    // ---- epilogue: per-lane 1/l, packed 8B stores; row i = iw0+fr ----
    const float linv = 1.f / lrow;
    const int i = iw0 + fr;
#pragma unroll
    for (int nd = 0; nd < 4; ++nd) {
      B4 pack;
      pack.a = __float2bfloat16(o[nd][0] * linv);
      pack.b = __float2bfloat16(o[nd][1] * linv);
      pack.c = __float2bfloat16(o[nd][2] * linv);
      pack.d = __float2bfloat16(o[nd][3] * linv);
      *reinterpret_cast<B4*>(av + ((size_t)i * NB + bb) * DM + h * DHD + 16 * nd + 4 * fq) = pack;
    }
  }
}

extern "C" void kernel_launch(void* const* d_in, const int* in_sizes, int n_in,
                              void* d_out, int out_size, void* d_ws, size_t ws_size,
                              hipStream_t stream) {
  (void)in_sizes; (void)n_in; (void)out_size; (void)ws_size;
  const float* x    = (const float*)d_in[0];
  const float* pos  = (const float*)d_in[1];
  const float* ln_g = (const float*)d_in[2];
  const float* ln_b = (const float*)d_in[3];
  const float* Wqkv = (const float*)d_in[4];
  const float* Wr   = (const float*)d_in[5];
  const float* Wo   = (const float*)d_in[6];
  const float* rwb  = (const float*)d_in[7];
  const float* rrb  = (const float*)d_in[8];
  float* out = (float*)d_out;

  char* ws = (char*)d_ws;
  size_t off = 0;
  auto alloc = [&](size_t n) {
    char* p = ws + off; off += (n + 255) & ~(size_t)255; return p;
  };
  __hip_bfloat16* wqkvT = (__hip_bfloat16*)alloc((size_t)3072 * 1024 * 2);
  __hip_bfloat16* wrT   = (__hip_bfloat16*)alloc((size_t)1024 * 1024 * 2);
  __hip_bfloat16* woT   = (__hip_bfloat16*)alloc((size_t)1024 * 1024 * 2);
  __hip_bfloat16* posb  = (__hip_bfloat16*)alloc((size_t)2048 * 1024 * 2);
  __hip_bfloat16* xn    = (__hip_bfloat16*)alloc((size_t)4096 * 1024 * 2);
  __hip_bfloat16* qwb   = (__hip_bfloat16*)alloc((size_t)NB * NH * TSEQ * DHD * 2);
  __hip_bfloat16* kbb   = (__hip_bfloat16*)alloc((size_t)NB * NH * TSEQ * DHD * 2);
  __hip_bfloat16* vTb   = (__hip_bfloat16*)alloc((size_t)NB * NH * TSEQ * DHD * 2);
  __hip_bfloat16* rTb   = (__hip_bfloat16*)alloc((size_t)NH * TSEQ * DHD * 2);
  __hip_bfloat16* avb   = (__hip_bfloat16*)alloc((size_t)4096 * 1024 * 2);
  (void)alloc(64 * 1024);  // guard region

  k_prep<<<11264, 256, 0, stream>>>(Wqkv, Wr, Wo, wqkvT, wrT, woT,
                                    pos, posb, x, ln_g, ln_b, xn);
  k_gemm01<<<896, 256, 0, stream>>>(xn, wqkvT, posb, wrT,
                                    qwb, kbb, vTb, rwb, rTb);
  k_attn<<<512, 256, 0, stream>>>(qwb, kbb, vTb, rTb, rwb, rrb, avb);
  k_gemm2<<<512, 256, 0, stream>>>(avb, woT, out);
}

// Round 22
// 150.234 us; speedup vs baseline: 1.3835x; 1.0117x over previous
//
#include <hip/hip_runtime.h>
#include <hip/hip_bf16.h>
#include <math.h>

#define TSEQ 2048
#define NB 2
#define DM 1024
#define NH 16
#define DHD 64

typedef __attribute__((ext_vector_type(8))) __bf16 bf16x8;
typedef __attribute__((ext_vector_type(8))) short s16x8;
typedef __attribute__((ext_vector_type(4))) float f32x4;

__device__ __forceinline__ bf16x8 ld_bf16x8(const void* p) {
  s16x8 v = *reinterpret_cast<const s16x8*>(p);
  return __builtin_bit_cast(bf16x8, v);
}

#define GLL16(g, l) __builtin_amdgcn_global_load_lds( \
    (const __attribute__((address_space(1))) void*)(g), \
    (__attribute__((address_space(3))) void*)(l), 16, 0, 0)

// ---------- fused prep: weight transposes + pos cast + LayerNorm ----------
__global__ __launch_bounds__(256) void k_prep(
    const float* __restrict__ Wqkv, const float* __restrict__ Wr,
    const float* __restrict__ Wo, __hip_bfloat16* __restrict__ wqkvT,
    __hip_bfloat16* __restrict__ wrT, __hip_bfloat16* __restrict__ woT,
    const float* __restrict__ pos, __hip_bfloat16* __restrict__ posb,
    const float* __restrict__ x, const float* __restrict__ g,
    const float* __restrict__ b, __hip_bfloat16* __restrict__ xn) {
  __shared__ float t[32][33];
  __shared__ float r1[4], r2[4];
  const int blk = blockIdx.x, tid = threadIdx.x;
  struct B4 { __hip_bfloat16 a, b, c, d; };
  if (blk < 5120) {
    const int tx = tid & 31, ty = tid >> 5;
    const float* in; __hip_bfloat16* out; int C, bx, by;
    if (blk < 3072)      { in = Wqkv; out = wqkvT; C = 3072; bx = blk % 96;  by = blk / 96; }
    else if (blk < 4096) { in = Wr;   out = wrT;   C = 1024; bx = (blk - 3072) % 32; by = (blk - 3072) / 32; }
    else                 { in = Wo;   out = woT;   C = 1024; bx = (blk - 4096) % 32; by = (blk - 4096) / 32; }
    const int c0 = bx * 32, r0 = by * 32;
#pragma unroll
    for (int j = 0; j < 4; ++j)
      t[ty + j * 8][tx] = in[(size_t)(r0 + ty + j * 8) * C + c0 + tx];
    __syncthreads();
#pragma unroll
    for (int j = 0; j < 4; ++j) {
      const int oc = ty + j * 8;
      out[(size_t)(c0 + oc) * 1024 + r0 + tx] = __float2bfloat16(t[tx][oc]);
    }
  } else if (blk < 7168) {
    const int i = ((blk - 5120) * 256 + tid) * 4;
    const float4 v = *reinterpret_cast<const float4*>(pos + i);
    B4 o;
    o.a = __float2bfloat16(v.x); o.b = __float2bfloat16(v.y);
    o.c = __float2bfloat16(v.z); o.d = __float2bfloat16(v.w);
    *reinterpret_cast<B4*>(posb + i) = o;
  } else {
    const int row = blk - 7168;
    const float4 v = reinterpret_cast<const float4*>(x + (size_t)row * DM)[tid];
    float s = v.x + v.y + v.z + v.w;
#pragma unroll
    for (int off = 32; off; off >>= 1) s += __shfl_xor(s, off);
    if ((tid & 63) == 0) r1[tid >> 6] = s;
    __syncthreads();
    const float mu = (r1[0] + r1[1] + r1[2] + r1[3]) * (1.f / DM);
    const float dx = v.x - mu, dy = v.y - mu, dz = v.z - mu, dw = v.w - mu;
    float q = dx * dx + dy * dy + dz * dz + dw * dw;
#pragma unroll
    for (int off = 32; off; off >>= 1) q += __shfl_xor(q, off);
    if ((tid & 63) == 0) r2[tid >> 6] = q;
    __syncthreads();
    const float rs = rsqrtf((r2[0] + r2[1] + r2[2] + r2[3]) * (1.f / DM) + 1e-5f);
    const float4 gv = reinterpret_cast<const float4*>(g)[tid];
    const float4 bv = reinterpret_cast<const float4*>(b)[tid];
    B4 o;
    o.a = __float2bfloat16(dx * rs * gv.x + bv.x);
    o.b = __float2bfloat16(dy * rs * gv.y + bv.y);
    o.c = __float2bfloat16(dz * rs * gv.z + bv.z);
    o.d = __float2bfloat16(dw * rs * gv.w + bv.w);
    reinterpret_cast<B4*>(xn + (size_t)row * DM)[tid] = o;
  }
}

// ---------- merged QKV + R GEMM, split-phase pipelined (R18-proven) ----------
__global__ __launch_bounds__(256) void k_gemm01(
    const __hip_bfloat16* __restrict__ xn, const __hip_bfloat16* __restrict__ wqkvT,
    const __hip_bfloat16* __restrict__ posb, const __hip_bfloat16* __restrict__ wrT,
    __hip_bfloat16* __restrict__ o_qw, __hip_bfloat16* __restrict__ o_k,
    __hip_bfloat16* __restrict__ o_vT, const float* __restrict__ rwb,
    __hip_bfloat16* __restrict__ o_rT) {
  __shared__ __align__(16) __hip_bfloat16 As[128 * 64];
  __shared__ __align__(16) __hip_bfloat16 Bs[128 * 64];
  const int tid = threadIdx.x, lane = tid & 63;
  const int tile = (blockIdx.x & 7) * 112 + (blockIdx.x >> 3);
  const bool q0 = tile < 768;
  const int t0 = q0 ? tile : tile - 768;
  const int ntn = q0 ? 24 : 8;
  const __hip_bfloat16* A  = q0 ? xn : posb;
  const __hip_bfloat16* BT = q0 ? wqkvT : wrT;
  const int K = 1024;
  const int m0 = (t0 / ntn) * 128, n0 = (t0 % ntn) * 128;
  const int wid = tid >> 6;
  const int wr = (wid >> 1) * 64, wc = (wid & 1) * 64;
  const int fr = lane & 15, fq = lane >> 4;
  const int srow8 = tid >> 3;
  const int ssb = ((tid & 7) << 4) ^ ((srow8 & 7) << 4);
  const char* aS = (const char*)(A + (size_t)(m0 + srow8) * K) + ssb;
  const char* bS = (const char*)(BT + (size_t)(n0 + srow8) * K) + ssb;
  char* aD = (char*)As + tid * 16;
  char* bD = (char*)Bs + tid * 16;
  const int rk0 = (fq << 4) ^ ((fr & 7) << 4);
  const int rk1 = ((fq << 4) + 64) ^ ((fr & 7) << 4);
  f32x4 acc[4][4] = {};

  // prologue: stage tile 0
#pragma unroll
  for (int gg = 0; gg < 4; ++gg)
    GLL16(aS + (size_t)(gg * 32) * K * 2, aD + gg * 4096);
#pragma unroll
  for (int gg = 0; gg < 4; ++gg)
    GLL16(bS + (size_t)(gg * 32) * K * 2, bD + gg * 4096);

  for (int k0 = 0; k0 < K; k0 += 64) {
    asm volatile("s_waitcnt vmcnt(0)" ::: "memory");   // prefetched tile landed
    __builtin_amdgcn_s_barrier();
    // ---- read phase: all fragments -> regs ----
    bf16x8 af[4][2], bfr[4][2];
#pragma unroll
    for (int mi = 0; mi < 4; ++mi) {
      const char* p = (char*)As + (wr + mi * 16 + fr) * 128;
      af[mi][0] = ld_bf16x8(p + rk0);
      af[mi][1] = ld_bf16x8(p + rk1);
    }
#pragma unroll
    for (int ni = 0; ni < 4; ++ni) {
      const char* p = (char*)Bs + (wc + ni * 16 + fr) * 128;
      bfr[ni][0] = ld_bf16x8(p + rk0);
      bfr[ni][1] = ld_bf16x8(p + rk1);
    }
    asm volatile("s_waitcnt lgkmcnt(0)" ::: "memory");
    __builtin_amdgcn_sched_barrier(0);
    __builtin_amdgcn_s_barrier();   // all waves' LDS reads drained
    // ---- prefetch next tile into the same buffers ----
    if (k0 + 64 < K) {
      const size_t kb = (size_t)(k0 + 64) * 2;
#pragma unroll
      for (int gg = 0; gg < 4; ++gg)
        GLL16(aS + (size_t)(gg * 32) * K * 2 + kb, aD + gg * 4096);
#pragma unroll
      for (int gg = 0; gg < 4; ++gg)
        GLL16(bS + (size_t)(gg * 32) * K * 2 + kb, bD + gg * 4096);
    }
    // ---- compute (reg-fed) under GLL flight ----
    __builtin_amdgcn_s_setprio(1);
#pragma unroll
    for (int mi = 0; mi < 4; ++mi)
#pragma unroll
      for (int ni = 0; ni < 4; ++ni) {
        acc[mi][ni] = __builtin_amdgcn_mfma_f32_16x16x32_bf16(
            af[mi][0], bfr[ni][0], acc[mi][ni], 0, 0, 0);
        acc[mi][ni] = __builtin_amdgcn_mfma_f32_16x16x32_bf16(
            af[mi][1], bfr[ni][1], acc[mi][ni], 0, 0, 0);
      }
    __builtin_amdgcn_s_setprio(0);
  }
#pragma unroll
  for (int mi = 0; mi < 4; ++mi) {
#pragma unroll
    for (int ni = 0; ni < 4; ++ni) {
#pragma unroll
      for (int j = 0; j < 4; ++j) {
        const int r = m0 + wr + mi * 16 + fq * 4 + j;
        const int c = n0 + wc + ni * 16 + fr;
        const float v = acc[mi][ni][j];
        if (q0) {
          const int t = r >> 1, bb = r & 1;
          if (c < 1024) {
            const int h = c >> 6, d = c & 63;
            o_qw[(((size_t)(bb * NH + h)) * TSEQ + t) * DHD + d] = __float2bfloat16(v + rwb[c]);
          } else if (c < 2048) {
            const int e = c - 1024, h = e >> 6, d = e & 63;
            o_k[(((size_t)(bb * NH + h)) * TSEQ + t) * DHD + d] = __float2bfloat16(v);
          } else {
            const int e = c - 2048, h = e >> 6, d = e & 63;
            o_vT[(((size_t)(bb * NH + h)) * DHD + d) * TSEQ + t] = __float2bfloat16(v);
          }
        } else {
          const int h = c >> 6, d = c & 63;
          o_rT[((size_t)h * TSEQ + r) * DHD + d] = __float2bfloat16(v);
        }
      }
    }
  }
}

// ---------- out GEMM: BM=128 x BN=64, 512 blocks, split-phase pipelined ----------
__global__ __launch_bounds__(256) void k_gemm2(
    const __hip_bfloat16* __restrict__ A, const __hip_bfloat16* __restrict__ BT,
    float* __restrict__ outF) {
  __shared__ __align__(16) __hip_bfloat16 As[128 * 64];   // 16 KB
  __shared__ __align__(16) __hip_bfloat16 Bs[64 * 64];    // 8 KB
  const int tid = threadIdx.x, lane = tid & 63;
  const int K = 1024, N = 1024, ntn = 16;
  const int tile = (blockIdx.x & 7) * 64 + (blockIdx.x >> 3);   // 512 = 8*64
  const int m0 = (tile / ntn) * 128, n0 = (tile % ntn) * 64;
  const int wid = tid >> 6;
  const int wr = (wid >> 1) * 64, wc = (wid & 1) * 32;
  const int fr = lane & 15, fq = lane >> 4;
  const int srow8 = tid >> 3;
  const int ssb = ((tid & 7) << 4) ^ ((srow8 & 7) << 4);
  const char* aS = (const char*)(A + (size_t)(m0 + srow8) * K) + ssb;
  const char* bS = (const char*)(BT + (size_t)(n0 + srow8) * K) + ssb;
  char* aD = (char*)As + tid * 16;
  char* bD = (char*)Bs + tid * 16;
  const int rk0 = (fq << 4) ^ ((fr & 7) << 4);
  const int rk1 = ((fq << 4) + 64) ^ ((fr & 7) << 4);
  f32x4 acc[4][2] = {};

  // prologue: stage tile 0
#pragma unroll
  for (int gg = 0; gg < 4; ++gg)
    GLL16(aS + (size_t)(gg * 32) * K * 2, aD + gg * 4096);
#pragma unroll
  for (int gg = 0; gg < 2; ++gg)
    GLL16(bS + (size_t)(gg * 32) * K * 2, bD + gg * 4096);

  for (int k0 = 0; k0 < K; k0 += 64) {
    asm volatile("s_waitcnt vmcnt(0)" ::: "memory");
    __builtin_amdgcn_s_barrier();
    // ---- read phase ----
    bf16x8 af[4][2], bfr[2][2];
#pragma unroll
    for (int mi = 0; mi < 4; ++mi) {
      const char* p = (char*)As + (wr + mi * 16 + fr) * 128;
      af[mi][0] = ld_bf16x8(p + rk0);
      af[mi][1] = ld_bf16x8(p + rk1);
    }
#pragma unroll
    for (int ni = 0; ni < 2; ++ni) {
      const char* p = (char*)Bs + (wc + ni * 16 + fr) * 128;
      bfr[ni][0] = ld_bf16x8(p + rk0);
      bfr[ni][1] = ld_bf16x8(p + rk1);
    }
    asm volatile("s_waitcnt lgkmcnt(0)" ::: "memory");
    __builtin_amdgcn_sched_barrier(0);
    __builtin_amdgcn_s_barrier();
    // ---- prefetch next tile ----
    if (k0 + 64 < K) {
      const size_t kb = (size_t)(k0 + 64) * 2;
#pragma unroll
      for (int gg = 0; gg < 4; ++gg)
        GLL16(aS + (size_t)(gg * 32) * K * 2 + kb, aD + gg * 4096);
#pragma unroll
      for (int gg = 0; gg < 2; ++gg)
        GLL16(bS + (size_t)(gg * 32) * K * 2 + kb, bD + gg * 4096);
    }
    // ---- compute ----
    __builtin_amdgcn_s_setprio(1);
#pragma unroll
    for (int mi = 0; mi < 4; ++mi)
#pragma unroll
      for (int ni = 0; ni < 2; ++ni) {
        acc[mi][ni] = __builtin_amdgcn_mfma_f32_16x16x32_bf16(
            af[mi][0], bfr[ni][0], acc[mi][ni], 0, 0, 0);
        acc[mi][ni] = __builtin_amdgcn_mfma_f32_16x16x32_bf16(
            af[mi][1], bfr[ni][1], acc[mi][ni], 0, 0, 0);
      }
    __builtin_amdgcn_s_setprio(0);
  }
#pragma unroll
  for (int mi = 0; mi < 4; ++mi)
#pragma unroll
    for (int ni = 0; ni < 2; ++ni)
#pragma unroll
      for (int j = 0; j < 4; ++j) {
        const int r = m0 + wr + mi * 16 + fq * 4 + j;
        const int c = n0 + wc + ni * 16 + fr;
        outF[(size_t)r * N + c] = acc[mi][ni][j];
      }
}

// ---------- fused causal rel-attention: R21 + pre-scaled Q fragments ----------
// Only change vs R21: qwf/qrf scaled by 0.125 at part start (bf16 * 2^-3 is
// an EXACT exponent shift) -> scores emerge pre-scaled, the per-iteration
// *0.125f (16 serial v_mul on the softmax critical chain) is eliminated.
__global__ __launch_bounds__(256, 2) void k_attn(
    const __hip_bfloat16* __restrict__ qw,
    const __hip_bfloat16* __restrict__ kb, const __hip_bfloat16* __restrict__ vT,
    const __hip_bfloat16* __restrict__ rT,
    const float* __restrict__ rwb, const float* __restrict__ rrb,
    __hip_bfloat16* __restrict__ av) {
  const int tid = threadIdx.x, lane = tid & 63;
  const int w = __builtin_amdgcn_readfirstlane(tid >> 6);
  const int fr = lane & 15, fq = lane >> 4;
  const int l8 = lane >> 3, lb = lane & 7;
  const int bid = blockIdx.x;
  const int xcd = bid & 7, idx = bid >> 3;     // idx 0..63
  const int bh = xcd * 4 + (idx & 3);          // 4 heads per XCD
  const int pr = idx >> 2;                     // pair 0..15
  const int bb = bh >> 4, h = bh & 15;
  const char* Kp = (const char*)(kb + (size_t)bh * TSEQ * DHD);   // row t:128B
  const char* Vp = (const char*)(vT + (size_t)bh * DHD * TSEQ);   // row d:4096B
  const char* Rp = (const char*)(rT + (size_t)h * TSEQ * DHD);    // row t:128B

  __shared__ __align__(16) __hip_bfloat16 Ksm[2][64][64];   // 16 KB
  __shared__ __align__(16) __hip_bfloat16 Vsm[2][64][64];   // 16 KB
  __shared__ __align__(16) __hip_bfloat16 Rsm[192][64];     // 24 KB circular
  __shared__ __align__(16) char scratch[4][5632];           // braw/plq overlay

  const int swz = (lb << 4) ^ (l8 << 4);                 // staging src byte
  const int koff0 = (fq << 4) ^ ((fr & 7) << 4);         // swizzled read c=0
  const int koff1 = ((fq << 4) + 64) ^ ((fr & 7) << 4);  // swizzled read c=1
  const int rowA = w * 16 + l8;                          // K/V stage rows
  const int kOff0 = rowA * 128 + swz, kOff1 = (rowA + 8) * 128 + swz;
  const int vOff0 = rowA * 4096 + swz, vOff1 = (rowA + 8) * 4096 + swz;
  char* kDstB = (char*)Ksm + w * 2048 + lane * 16;   // + buf*8192
  char* vDstB = (char*)Vsm + w * 2048 + lane * 16;
  char* RsmC = (char*)Rsm;
  float* brawW = (float*)scratch[w];                       // [16][84] f32
  __hip_bfloat16* plqW = (__hip_bfloat16*)scratch[w];      // [16][88] bf16 overlay
  const f32x4 zero = {0.f, 0.f, 0.f, 0.f};
  struct B4 { __hip_bfloat16 a, b, c, d; };

  const float* rwbh = rwb + h * 64;
  const float* rrbh = rrb + h * 64;

#pragma unroll
  for (int part = 0; part < 2; ++part) {
    const int p4 = part ? 31 - pr : pr;
    const int nk = p4 + 1;
    const int iw0 = p4 * 64 + w * 16;
    const int rbase0 = 1984 - 64 * p4;
    int rm = (((1 - p4) % 3) + 3) % 3 * 64;    // rbase0 mod 192
    const __hip_bfloat16* qwp = qw + ((size_t)bh * TSEQ + iw0 + fr) * DHD + fq * 8;
    const bf16x8 qwl0 = ld_bf16x8(qwp), qwl1 = ld_bf16x8(qwp + 32);
    // pre-scaled fragments: *0.125 is an exact bf16 exponent shift
    bf16x8 qwf0, qwf1, qrf0, qrf1;
#pragma unroll
    for (int e = 0; e < 8; ++e) {
      const float q0v = (float)qwl0[e], q1v = (float)qwl1[e];
      qwf0[e] = (__bf16)(q0v * 0.125f);
      qwf1[e] = (__bf16)(q1v * 0.125f);
      qrf0[e] = (__bf16)((q0v + rrbh[fq * 8 + e] - rwbh[fq * 8 + e]) * 0.125f);
      qrf1[e] = (__bf16)((q1v + rrbh[32 + fq * 8 + e] - rwbh[32 + fq * 8 + e]) * 0.125f);
    }
    f32x4 o[4] = {};
    float mrow = -INFINITY, lrow = 0.f;

    asm volatile("s_waitcnt lgkmcnt(0)" ::: "memory");  // harden: all LDS ops done
    __builtin_amdgcn_s_barrier();   // protect previous part's reads

    // ---- prologue: K(0),V(0) -> buf0; R rows [rbase0, rbase0+128) ----
    GLL16(Kp + kOff0, kDstB);
    GLL16(Kp + kOff1, kDstB + 1024);
    GLL16(Vp + vOff0, vDstB);
    GLL16(Vp + vOff1, vDstB + 1024);
#pragma unroll
    for (int s = 0; s < 4; ++s) {
      int pb = rm + w * 32 + s * 8;
      if (pb >= 192) pb -= 192;
      int g = rbase0 + w * 32 + s * 8 + l8;
      g = g > 2047 ? 2047 : g;
      GLL16(Rp + g * 128 + swz, RsmC + pb * 128 + (lb << 4));
    }

    int rbase = rbase0;
    int thr = iw0 + fr;
    const char* kTile = Kp + 8192;    // src for K(kt+1)
    const char* vTile = Vp + 128;     // src for V(kt+1)
    for (int kt = 0; kt < nk; ++kt) {
      asm volatile("s_waitcnt vmcnt(0)" ::: "memory");
      __builtin_amdgcn_s_barrier();
      // ---- prefetch tile kt+1 (skip on last) ----
      if (kt + 1 < nk) {
        const int nxtOff = ((kt + 1) & 1) << 13;
        GLL16(kTile + kOff0, kDstB + nxtOff);
        GLL16(kTile + kOff1, kDstB + nxtOff + 1024);
        GLL16(vTile + vOff0, vDstB + nxtOff);
        GLL16(vTile + vOff1, vDstB + nxtOff + 1024);
        const int rm2 = rm >= 64 ? rm - 64 : rm + 128;   // (rbase+128) mod 192
#pragma unroll
        for (int s = 0; s < 2; ++s) {
          int g = rbase + 128 + w * 16 + s * 8 + l8;
          g = g > 2047 ? 2047 : g;
          GLL16(Rp + g * 128 + swz,
                RsmC + (rm2 + w * 16 + s * 8) * 128 + (lb << 4));
        }
        kTile += 8192;
        vTile += 128;
      }
      // ---- S^T from Ksm[cur] (staged last iter; ready) ----
      const int curOff = (kt & 1) << 13;
      const char* kls = (const char*)Ksm + curOff + fr * 128;
      f32x4 st[4];
      __builtin_amdgcn_s_setprio(1);
#pragma unroll
      for (int n = 0; n < 4; ++n) {
        st[n] = __builtin_amdgcn_mfma_f32_16x16x32_bf16(ld_bf16x8(kls + n * 2048 + koff0), qwf0, zero, 0, 0, 0);
        st[n] = __builtin_amdgcn_mfma_f32_16x16x32_bf16(ld_bf16x8(kls + n * 2048 + koff1), qwf1, st[n], 0, 0, 0);
      }
      __builtin_amdgcn_s_setprio(0);
      // ---- band from circular Rsm: D[m][q=fr] -> b128 braw write ----
      const int base_l = rm + 48 - 16 * w + fr;   // <= 191; == fr (mod 8)
      __builtin_amdgcn_s_setprio(1);
#pragma unroll
      for (int pp = 0; pp < 5; ++pp) {
        int rrow = base_l + 16 * pp;
        if (rrow >= 192) rrow -= 192;
        const char* rls = RsmC + rrow * 128;
        f32x4 br = __builtin_amdgcn_mfma_f32_16x16x32_bf16(ld_bf16x8(rls + koff0), qrf0, zero, 0, 0, 0);
        br = __builtin_amdgcn_mfma_f32_16x16x32_bf16(ld_bf16x8(rls + koff1), qrf1, br, 0, 0, 0);
        *reinterpret_cast<f32x4*>(&brawW[fr * 84 + pp * 16 + 4 * fq]) = br;
      }
      __builtin_amdgcn_s_setprio(0);
      // ---- scores (pre-scaled) + in-register online softmax (q = fr) ----
      const float* brd = &brawW[fr * 84 + 15 - fr];
      float mx = -INFINITY;
      if (kt < nk - 1) {
#pragma unroll
        for (int n = 0; n < 4; ++n) {
#pragma unroll
          for (int j = 0; j < 4; ++j) {
            const int koff = 16 * n + 4 * fq + j;
            const float s = st[n][j] + brd[koff];
            st[n][j] = s;
            mx = fmaxf(mx, s);
          }
        }
      } else {
#pragma unroll
        for (int n = 0; n < 4; ++n) {
#pragma unroll
          for (int j = 0; j < 4; ++j) {
            const int koff = 16 * n + 4 * fq + j;
            const float s = (koff > thr) ? -INFINITY : st[n][j] + brd[koff];
            st[n][j] = s;
            mx = fmaxf(mx, s);
          }
        }
      }
      mx = fmaxf(mx, __shfl_xor(mx, 16));
      mx = fmaxf(mx, __shfl_xor(mx, 32));
      const float mn = fmaxf(mrow, mx);
      const float al = __expf(mrow - mn);
      mrow = mn;
      float rsum = 0.f;
#pragma unroll
      for (int n = 0; n < 4; ++n)
#pragma unroll
        for (int j = 0; j < 4; ++j) {
          const float pv = __expf(st[n][j] - mn);
          st[n][j] = pv;
          rsum += pv;
        }
      rsum += __shfl_xor(rsum, 16);
      rsum += __shfl_xor(rsum, 32);
      lrow = lrow * al + rsum;
#pragma unroll
      for (int nd = 0; nd < 4; ++nd) o[nd] *= al;
      // ---- P store (overlay; braw fully consumed) ----
#pragma unroll
      for (int n = 0; n < 4; ++n) {
        B4 pk;
        pk.a = __float2bfloat16(st[n][0]);
        pk.b = __float2bfloat16(st[n][1]);
        pk.c = __float2bfloat16(st[n][2]);
        pk.d = __float2bfloat16(st[n][3]);
        *reinterpret_cast<B4*>(&plqW[fr * 88 + 16 * n + 4 * fq]) = pk;
      }
      // ---- O^T += V^T . P^T from Vsm[cur] ----
      const char* vls = (const char*)Vsm + curOff + fr * 128;
      __builtin_amdgcn_s_setprio(1);
#pragma unroll
      for (int c = 0; c < 2; ++c) {
        const bf16x8 pf = ld_bf16x8(&plqW[fr * 88 + 8 * fq + 32 * c]);
#pragma unroll
        for (int nd = 0; nd < 4; ++nd)
          o[nd] = __builtin_amdgcn_mfma_f32_16x16x32_bf16(
              ld_bf16x8(vls + nd * 2048 + (c ? koff1 : koff0)), pf, o[nd], 0, 0, 0);
      }
      __builtin_amdgcn_s_setprio(0);
      // ---- advance ----
      rbase += 64;
      rm = rm >= 128 ? 0 : rm + 64;
      thr -= 64;
    }
    // ---- epilogue: per-lane 1/l, packed 8B stores; row i = iw0+fr ----
    const float linv = 1.f / lrow;
    const int i = iw0 + fr;
#pragma unroll
    for (int nd = 0; nd < 4; ++nd) {
      B4 pack;
      pack.a = __float2bfloat16(o[nd][0] * linv);
      pack.b = __float2bfloat16(o[nd][1] * linv);
      pack.c = __float2bfloat16(o[nd][2] * linv);
      pack.d = __float2bfloat16(o[nd][3] * linv);
      *reinterpret_cast<B4*>(av + ((size_t)i * NB + bb) * DM + h * DHD + 16 * nd + 4 * fq) = pack;
    }
  }
}

extern "C" void kernel_launch(void* const* d_in, const int* in_sizes, int n_in,
                              void* d_out, int out_size, void* d_ws, size_t ws_size,
                              hipStream_t stream) {
  (void)in_sizes; (void)n_in; (void)out_size; (void)ws_size;
  const float* x    = (const float*)d_in[0];
  const float* pos  = (const float*)d_in[1];
  const float* ln_g = (const float*)d_in[2];
  const float* ln_b = (const float*)d_in[3];
  const float* Wqkv = (const float*)d_in[4];
  const float* Wr   = (const float*)d_in[5];
  const float* Wo   = (const float*)d_in[6];
  const float* rwb  = (const float*)d_in[7];
  const float* rrb  = (const float*)d_in[8];
  float* out = (float*)d_out;

  char* ws = (char*)d_ws;
  size_t off = 0;
  auto alloc = [&](size_t n) {
    char* p = ws + off; off += (n + 255) & ~(size_t)255; return p;
  };
  __hip_bfloat16* wqkvT = (__hip_bfloat16*)alloc((size_t)3072 * 1024 * 2);
  __hip_bfloat16* wrT   = (__hip_bfloat16*)alloc((size_t)1024 * 1024 * 2);
  __hip_bfloat16* woT   = (__hip_bfloat16*)alloc((size_t)1024 * 1024 * 2);
  __hip_bfloat16* posb  = (__hip_bfloat16*)alloc((size_t)2048 * 1024 * 2);
  __hip_bfloat16* xn    = (__hip_bfloat16*)alloc((size_t)4096 * 1024 * 2);
  __hip_bfloat16* qwb   = (__hip_bfloat16*)alloc((size_t)NB * NH * TSEQ * DHD * 2);
  __hip_bfloat16* kbb   = (__hip_bfloat16*)alloc((size_t)NB * NH * TSEQ * DHD * 2);
  __hip_bfloat16* vTb   = (__hip_bfloat16*)alloc((size_t)NB * NH * TSEQ * DHD * 2);
  __hip_bfloat16* rTb   = (__hip_bfloat16*)alloc((size_t)NH * TSEQ * DHD * 2);
  __hip_bfloat16* avb   = (__hip_bfloat16*)alloc((size_t)4096 * 1024 * 2);
  (void)alloc(64 * 1024);  // guard region

  k_prep<<<11264, 256, 0, stream>>>(Wqkv, Wr, Wo, wqkvT, wrT, woT,
                                    pos, posb, x, ln_g, ln_b, xn);
  k_gemm01<<<896, 256, 0, stream>>>(xn, wqkvT, posb, wrT,
                                    qwb, kbb, vTb, rwb, rTb);
  k_attn<<<512, 256, 0, stream>>>(qwb, kbb, vTb, rTb, rwb, rrb, avb);
  k_gemm2<<<512, 256, 0, stream>>>(avb, woT, out);
}